// Round 1
// baseline (2331.732 us; speedup 1.0000x reference)
//
#include <hip/hip_runtime.h>
#include <hip/hip_bf16.h>

// ---------------------------------------------------------------------------
// GAT 2-layer forward (PyG GATConv semantics, eval mode), fp32 throughout.
// N=50000 nodes, E=600000 edges (+N self-loops), L1: 500 -> 8 heads x 64,
// L2: 512 -> 1 head x 64, final linear 64 -> 500.
// ---------------------------------------------------------------------------

#define N_NODES 50000
#define F_IN    500
#define H1      8
#define C_DIM   64
#define E_RAW   600000
#define E_TOT   (E_RAW + N_NODES)
#define NEG_SLOPE 0.2f

// ---------------- fill kernels ----------------
__global__ void fill_f32(float* __restrict__ p, float v, long n) {
    long i = blockIdx.x * (long)blockDim.x + threadIdx.x;
    long stride = (long)gridDim.x * blockDim.x;
    for (; i < n; i += stride) p[i] = v;
}

__global__ void fill_i32(int* __restrict__ p, int v, long n) {
    long i = blockIdx.x * (long)blockDim.x + threadIdx.x;
    long stride = (long)gridDim.x * blockDim.x;
    for (; i < n; i += stride) p[i] = v;
}

// ---------------- simple tiled fp32 GEMM: C = A[MxK] * B[KxN] (+bias) -------
template<bool ADD_BIAS>
__global__ void gemm_kernel(const float* __restrict__ A, const float* __restrict__ B,
                            const float* __restrict__ bias, float* __restrict__ C,
                            int M, int N, int K) {
    __shared__ float As[16][65];   // [k][m], padded
    __shared__ float Bs[16][64];   // [k][n]
    int tid = threadIdx.x;         // 256 threads
    int tx = tid & 15, ty = tid >> 4;
    int row0 = blockIdx.y * 64, col0 = blockIdx.x * 64;
    float acc[4][4] = {};
    for (int k0 = 0; k0 < K; k0 += 16) {
        #pragma unroll
        for (int i = 0; i < 4; ++i) {
            int idx = tid + i * 256;          // 0..1023 = 64 rows x 16 k
            int m = idx >> 4, kk = idx & 15;
            int gr = row0 + m, gk = k0 + kk;
            float v = 0.f;
            if (gr < M && gk < K) v = A[(long)gr * K + gk];
            As[kk][m] = v;
        }
        #pragma unroll
        for (int i = 0; i < 4; ++i) {
            int idx = tid + i * 256;          // 16 k x 64 n
            int kk = idx >> 6, n = idx & 63;
            int gk = k0 + kk, gc = col0 + n;
            float v = 0.f;
            if (gk < K && gc < N) v = B[(long)gk * N + gc];
            Bs[kk][n] = v;
        }
        __syncthreads();
        #pragma unroll
        for (int kk = 0; kk < 16; ++kk) {
            float a[4], b[4];
            #pragma unroll
            for (int i = 0; i < 4; ++i) a[i] = As[kk][ty * 4 + i];
            #pragma unroll
            for (int j = 0; j < 4; ++j) b[j] = Bs[kk][tx * 4 + j];
            #pragma unroll
            for (int i = 0; i < 4; ++i)
                #pragma unroll
                for (int j = 0; j < 4; ++j)
                    acc[i][j] += a[i] * b[j];
        }
        __syncthreads();
    }
    #pragma unroll
    for (int i = 0; i < 4; ++i) {
        int r = row0 + ty * 4 + i;
        if (r >= M) continue;
        #pragma unroll
        for (int j = 0; j < 4; ++j) {
            int c = col0 + tx * 4 + j;
            if (c >= N) continue;
            float v = acc[i][j];
            if (ADD_BIAS) v += bias[c];
            C[(long)r * N + c] = v;
        }
    }
}

// ---------------- per-node attention dots: a_s[n,h], a_d[n,h] (C=64) --------
__global__ void attn_dots(const float* __restrict__ h, const float* __restrict__ att_src,
                          const float* __restrict__ att_dst, float* __restrict__ a_s,
                          float* __restrict__ a_d, int N, int H) {
    long wid = (blockIdx.x * (long)blockDim.x + threadIdx.x) >> 6;
    int lane = threadIdx.x & 63;
    long total = (long)N * H;
    if (wid >= total) return;
    int n = (int)(wid / H), hh = (int)(wid % H);
    float v = h[(long)n * H * 64 + hh * 64 + lane];
    float s = v * att_src[hh * 64 + lane];
    float d = v * att_dst[hh * 64 + lane];
    #pragma unroll
    for (int m = 32; m >= 1; m >>= 1) { s += __shfl_xor(s, m); d += __shfl_xor(d, m); }
    if (lane == 0) { a_s[wid] = s; a_d[wid] = d; }
}

__device__ __forceinline__ int f32_order_key(float x) {
    int b = __float_as_int(x);
    return b ^ ((b >> 31) & 0x7fffffff);   // monotone float->int, self-inverse
}

// ---------------- edge pass 1: e = leakyrelu(a_s[src]+a_d[dst]); seg-max ----
__global__ void edge_pass1(const int* __restrict__ ei, const float* __restrict__ a_s,
                           const float* __restrict__ a_d, float* __restrict__ ebuf,
                           int* __restrict__ m_int, int H) {
    long gid = blockIdx.x * (long)blockDim.x + threadIdx.x;
    long total = (long)E_TOT * H;
    long stride = (long)gridDim.x * blockDim.x;
    for (; gid < total; gid += stride) {
        int e = (int)(gid / H), hh = (int)(gid % H);
        int s, d;
        if (e < E_RAW) { s = ei[e]; d = ei[E_RAW + e]; } else { s = d = e - E_RAW; }
        float x = a_s[(long)s * H + hh] + a_d[(long)d * H + hh];
        x = x > 0.f ? x : NEG_SLOPE * x;
        ebuf[gid] = x;
        atomicMax(&m_int[(long)d * H + hh], f32_order_key(x));
    }
}

// ---------------- edge pass 2: p = exp(e - m[dst]); seg-sum -----------------
__global__ void edge_pass2(const int* __restrict__ ei, const int* __restrict__ m_int,
                           float* __restrict__ ebuf, float* __restrict__ denom, int H) {
    long gid = blockIdx.x * (long)blockDim.x + threadIdx.x;
    long total = (long)E_TOT * H;
    long stride = (long)gridDim.x * blockDim.x;
    for (; gid < total; gid += stride) {
        int e = (int)(gid / H), hh = (int)(gid % H);
        int d = (e < E_RAW) ? ei[E_RAW + e] : e - E_RAW;
        int key = m_int[(long)d * H + hh];
        key ^= (key >> 31) & 0x7fffffff;
        float m = __int_as_float(key);
        float p = expf(ebuf[gid] - m);
        ebuf[gid] = p;
        atomicAdd(&denom[(long)d * H + hh], p);
    }
}

// ---------------- edge pass 3: out[dst,h,:] += h[src,h,:] * alpha -----------
__global__ void edge_agg(const int* __restrict__ ei, const float* __restrict__ ebuf,
                         const float* __restrict__ denom, const float* __restrict__ h,
                         float* __restrict__ out, int H) {
    long wid = (blockIdx.x * (long)blockDim.x + threadIdx.x) >> 6;
    int lane = threadIdx.x & 63;
    long total = (long)E_TOT * H;
    if (wid >= total) return;
    int e = (int)(wid / H), hh = (int)(wid % H);
    int s, d;
    if (e < E_RAW) { s = ei[e]; d = ei[E_RAW + e]; } else { s = d = e - E_RAW; }
    float alpha = ebuf[wid] / (denom[(long)d * H + hh] + 1e-16f);
    float v = h[(long)s * H * 64 + hh * 64 + lane] * alpha;
    atomicAdd(&out[(long)d * H * 64 + hh * 64 + lane], v);
}

// ---------------- bias + ELU (in place) -------------------------------------
__global__ void bias_elu(float* __restrict__ y, const float* __restrict__ b,
                         long n, int ncols) {
    long i = blockIdx.x * (long)blockDim.x + threadIdx.x;
    long stride = (long)gridDim.x * blockDim.x;
    for (; i < n; i += stride) {
        float v = y[i] + b[(int)(i % ncols)];
        y[i] = v > 0.f ? v : (expf(v) - 1.f);
    }
}

// ---------------------------------------------------------------------------
extern "C" void kernel_launch(void* const* d_in, const int* in_sizes, int n_in,
                              void* d_out, int out_size, void* d_ws, size_t ws_size,
                              hipStream_t stream) {
    const float* x        = (const float*)d_in[0];
    const int*   ei       = (const int*)d_in[1];
    const float* W1       = (const float*)d_in[2];
    const float* att_src1 = (const float*)d_in[3];
    const float* att_dst1 = (const float*)d_in[4];
    const float* b1       = (const float*)d_in[5];
    const float* W2       = (const float*)d_in[6];
    const float* att_src2 = (const float*)d_in[7];
    const float* att_dst2 = (const float*)d_in[8];
    const float* b2       = (const float*)d_in[9];
    const float* Wl       = (const float*)d_in[10];
    const float* bl       = (const float*)d_in[11];
    float* out = (float*)d_out;

    // workspace layout (floats)
    float* ws   = (float*)d_ws;
    float* h1   = ws;                              // 50000*512 = 25.6M
    float* out1 = h1 + (long)N_NODES * 512;        // 25.6M
    float* ebuf = out1 + (long)N_NODES * 512;      // 650000*8 = 5.2M
    float* as1  = ebuf + (long)E_TOT * H1;         // 400000
    float* ad1  = as1 + (long)N_NODES * H1;        // 400000
    int*   m1   = (int*)(ad1 + (long)N_NODES * H1);// 400000
    float* den1 = (float*)(m1 + (long)N_NODES * H1);// 400000
    // layer-2 reuse: h1 region is dead after layer-1 aggregation
    float* h2   = h1;                              // 50000*64 = 3.2M
    float* out2 = h1 + (long)N_NODES * 64;         // 3.2M

    const int BT = 256;
    dim3 blk(BT);

    // ---------------- layer 1 ----------------
    fill_f32<<<2048, blk, 0, stream>>>(out1, 0.f, (long)N_NODES * 512);
    fill_f32<<<512, blk, 0, stream>>>(den1, 0.f, (long)N_NODES * H1);
    fill_i32<<<512, blk, 0, stream>>>(m1, (int)0x80000000, (long)N_NODES * H1);

    {   // h1 = x @ W1   [50000 x 512, K=500]
        dim3 grid(512 / 64, (N_NODES + 63) / 64);
        gemm_kernel<false><<<grid, blk, 0, stream>>>(x, W1, nullptr, h1, N_NODES, 512, F_IN);
    }
    {   // attention dots
        long waves = (long)N_NODES * H1;
        attn_dots<<<(waves * 64 + BT - 1) / BT, blk, 0, stream>>>(h1, att_src1, att_dst1,
                                                                  as1, ad1, N_NODES, H1);
    }
    {
        long total = (long)E_TOT * H1;
        int blocks = (int)((total + BT - 1) / BT);
        edge_pass1<<<blocks, blk, 0, stream>>>(ei, as1, ad1, ebuf, m1, H1);
        edge_pass2<<<blocks, blk, 0, stream>>>(ei, m1, ebuf, den1, H1);
        long aggblocks = (total * 64 + BT - 1) / BT;
        edge_agg<<<aggblocks, blk, 0, stream>>>(ei, ebuf, den1, h1, out1, H1);
    }
    bias_elu<<<2048, blk, 0, stream>>>(out1, b1, (long)N_NODES * 512, 512);

    // ---------------- layer 2 (H=1) ----------------
    {   // h2 = y1 @ W2   [50000 x 64, K=512]
        dim3 grid(64 / 64, (N_NODES + 63) / 64);
        gemm_kernel<false><<<grid, blk, 0, stream>>>(out1, W2, nullptr, h2, N_NODES, 64, 512);
    }
    fill_f32<<<512, blk, 0, stream>>>(out2, 0.f, (long)N_NODES * 64);
    fill_f32<<<128, blk, 0, stream>>>(den1, 0.f, N_NODES);
    fill_i32<<<128, blk, 0, stream>>>(m1, (int)0x80000000, N_NODES);
    {
        long waves = (long)N_NODES;
        attn_dots<<<(waves * 64 + BT - 1) / BT, blk, 0, stream>>>(h2, att_src2, att_dst2,
                                                                  as1, ad1, N_NODES, 1);
    }
    {
        long total = (long)E_TOT;
        int blocks = (int)((total + BT - 1) / BT);
        edge_pass1<<<blocks, blk, 0, stream>>>(ei, as1, ad1, ebuf, m1, 1);
        edge_pass2<<<blocks, blk, 0, stream>>>(ei, m1, ebuf, den1, 1);
        long aggblocks = (total * 64 + BT - 1) / BT;
        edge_agg<<<aggblocks, blk, 0, stream>>>(ei, ebuf, den1, h2, out2, 1);
    }
    bias_elu<<<2048, blk, 0, stream>>>(out2, b2, (long)N_NODES * 64, 64);

    // ---------------- final linear: out = y2 @ Wl + bl ----------------
    {
        dim3 grid((F_IN + 63) / 64, (N_NODES + 63) / 64);
        gemm_kernel<true><<<grid, blk, 0, stream>>>(out2, Wl, bl, out, N_NODES, F_IN, 64);
    }
}

// Round 2
// 1860.210 us; speedup vs baseline: 1.2535x; 1.2535x over previous
//
#include <hip/hip_runtime.h>
#include <hip/hip_bf16.h>

// ---------------------------------------------------------------------------
// GAT 2-layer forward (PyG GATConv semantics, eval mode), fp32.
// R2: CSR-based pull aggregation (no atomics in the hot path), fused bias+ELU.
// ---------------------------------------------------------------------------

#define N_NODES 50000
#define F_IN    500
#define H1      8
#define C_DIM   64
#define E_RAW   600000
#define E_TOT   (E_RAW + N_NODES)
#define NEG_SLOPE 0.2f

__device__ __forceinline__ int edge_src(const int* ei, int e) {
    return (e < E_RAW) ? ei[e] : e - E_RAW;
}
__device__ __forceinline__ int edge_dst(const int* ei, int e) {
    return (e < E_RAW) ? ei[E_RAW + e] : e - E_RAW;
}

// ---------------- fills ----------------
__global__ void fill_i32(int* __restrict__ p, int v, long n) {
    long i = blockIdx.x * (long)blockDim.x + threadIdx.x;
    long stride = (long)gridDim.x * blockDim.x;
    for (; i < n; i += stride) p[i] = v;
}

// ---------------- CSR build ----------------
__global__ void count_deg(const int* __restrict__ ei, int* __restrict__ deg) {
    long i = blockIdx.x * (long)blockDim.x + threadIdx.x;
    long stride = (long)gridDim.x * blockDim.x;
    for (; i < E_TOT; i += stride) atomicAdd(&deg[edge_dst(ei, (int)i)], 1);
}

// single-block exclusive scan over n<=50176 ints
__global__ void scan_deg(const int* __restrict__ deg, int* __restrict__ off, int n) {
    __shared__ int part[1024];
    int t = threadIdx.x;
    int chunk = (n + 1023) >> 10;
    int b = t * chunk, e = min(b + chunk, n);
    int s = 0;
    for (int i = b; i < e; ++i) s += deg[i];
    part[t] = s;
    __syncthreads();
    for (int d = 1; d < 1024; d <<= 1) {
        int v = (t >= d) ? part[t - d] : 0;
        __syncthreads();
        part[t] += v;
        __syncthreads();
    }
    int excl = (t == 0) ? 0 : part[t - 1];
    for (int i = b; i < e; ++i) { int dv = deg[i]; off[i] = excl; excl += dv; }
    if (t == 1023) off[n] = part[1023];
}

__global__ void scatter_edges(const int* __restrict__ ei, const int* __restrict__ off,
                              int* __restrict__ cnt, int* __restrict__ eid) {
    long i = blockIdx.x * (long)blockDim.x + threadIdx.x;
    long stride = (long)gridDim.x * blockDim.x;
    for (; i < E_TOT; i += stride) {
        int d = edge_dst(ei, (int)i);
        int p = atomicAdd(&cnt[d], 1);
        eid[off[d] + p] = (int)i;
    }
}

// ---------------- simple tiled fp32 GEMM: C = A[MxK] * B[KxN] (+bias) -------
template<bool ADD_BIAS>
__global__ void gemm_kernel(const float* __restrict__ A, const float* __restrict__ B,
                            const float* __restrict__ bias, float* __restrict__ C,
                            int M, int N, int K) {
    __shared__ float As[16][65];
    __shared__ float Bs[16][64];
    int tid = threadIdx.x;
    int tx = tid & 15, ty = tid >> 4;
    int row0 = blockIdx.y * 64, col0 = blockIdx.x * 64;
    float acc[4][4] = {};
    for (int k0 = 0; k0 < K; k0 += 16) {
        #pragma unroll
        for (int i = 0; i < 4; ++i) {
            int idx = tid + i * 256;
            int m = idx >> 4, kk = idx & 15;
            int gr = row0 + m, gk = k0 + kk;
            float v = 0.f;
            if (gr < M && gk < K) v = A[(long)gr * K + gk];
            As[kk][m] = v;
        }
        #pragma unroll
        for (int i = 0; i < 4; ++i) {
            int idx = tid + i * 256;
            int kk = idx >> 6, n = idx & 63;
            int gk = k0 + kk, gc = col0 + n;
            float v = 0.f;
            if (gk < K && gc < N) v = B[(long)gk * N + gc];
            Bs[kk][n] = v;
        }
        __syncthreads();
        #pragma unroll
        for (int kk = 0; kk < 16; ++kk) {
            float a[4], b[4];
            #pragma unroll
            for (int i = 0; i < 4; ++i) a[i] = As[kk][ty * 4 + i];
            #pragma unroll
            for (int j = 0; j < 4; ++j) b[j] = Bs[kk][tx * 4 + j];
            #pragma unroll
            for (int i = 0; i < 4; ++i)
                #pragma unroll
                for (int j = 0; j < 4; ++j)
                    acc[i][j] += a[i] * b[j];
        }
        __syncthreads();
    }
    #pragma unroll
    for (int i = 0; i < 4; ++i) {
        int r = row0 + ty * 4 + i;
        if (r >= M) continue;
        #pragma unroll
        for (int j = 0; j < 4; ++j) {
            int c = col0 + tx * 4 + j;
            if (c >= N) continue;
            float v = acc[i][j];
            if (ADD_BIAS) v += bias[c];
            C[(long)r * N + c] = v;
        }
    }
}

// ---------------- per-node attention dots ----------------
__global__ void attn_dots(const float* __restrict__ h, const float* __restrict__ att_src,
                          const float* __restrict__ att_dst, float* __restrict__ a_s,
                          float* __restrict__ a_d, int N, int H) {
    long wid = (blockIdx.x * (long)blockDim.x + threadIdx.x) >> 6;
    int lane = threadIdx.x & 63;
    long total = (long)N * H;
    if (wid >= total) return;
    int n = (int)(wid / H), hh = (int)(wid % H);
    float v = h[(long)n * H * 64 + hh * 64 + lane];
    float s = v * att_src[hh * 64 + lane];
    float d = v * att_dst[hh * 64 + lane];
    #pragma unroll
    for (int m = 32; m >= 1; m >>= 1) { s += __shfl_xor(s, m); d += __shfl_xor(d, m); }
    if (lane == 0) { a_s[wid] = s; a_d[wid] = d; }
}

// ---------------- CSR aggregation: one wave per (dst, head) -----------------
// softmax over incoming edges + weighted gather of h[src], fused bias+ELU.
template<int H>
__global__ void csr_agg(const int* __restrict__ ei, const int* __restrict__ off,
                        const int* __restrict__ eid, const float* __restrict__ a_s,
                        const float* __restrict__ a_d, const float* __restrict__ h,
                        const float* __restrict__ bias, float* __restrict__ out) {
    long wid = (blockIdx.x * (long)blockDim.x + threadIdx.x) >> 6;
    int lane = threadIdx.x & 63;
    long total = (long)N_NODES * H;
    if (wid >= total) return;
    int dst = (int)(wid / H), hh = (int)(wid % H);
    int b = off[dst], e2 = off[dst + 1];
    float ad = a_d[(long)dst * H + hh];

    // pass A: max (lanes parallel over edges)
    float m = -1e30f;
    for (int i = b + lane; i < e2; i += 64) {
        int ed = eid[i];
        int s = edge_src(ei, ed);
        float x = a_s[(long)s * H + hh] + ad;
        x = x > 0.f ? x : NEG_SLOPE * x;
        m = fmaxf(m, x);
    }
    #pragma unroll
    for (int mm = 32; mm >= 1; mm >>= 1) m = fmaxf(m, __shfl_xor(m, mm));

    // pass B: sum of exp
    float sum = 0.f;
    for (int i = b + lane; i < e2; i += 64) {
        int ed = eid[i];
        int s = edge_src(ei, ed);
        float x = a_s[(long)s * H + hh] + ad;
        x = x > 0.f ? x : NEG_SLOPE * x;
        sum += __expf(x - m);
    }
    #pragma unroll
    for (int mm = 32; mm >= 1; mm >>= 1) sum += __shfl_xor(sum, mm);
    float inv = 1.f / (sum + 1e-16f);

    // pass C: weighted gather, lanes = channels
    float acc = 0.f;
    for (int i = b; i < e2; ++i) {
        int ed = eid[i];
        int s = edge_src(ei, ed);
        float x = a_s[(long)s * H + hh] + ad;
        x = x > 0.f ? x : NEG_SLOPE * x;
        float alpha = __expf(x - m) * inv;
        acc += alpha * h[((long)s * H + hh) * 64 + lane];
    }
    float v = acc + bias[hh * 64 + lane];
    out[((long)dst * H + hh) * 64 + lane] = v > 0.f ? v : (__expf(v) - 1.f);
}

// ---------------------------------------------------------------------------
extern "C" void kernel_launch(void* const* d_in, const int* in_sizes, int n_in,
                              void* d_out, int out_size, void* d_ws, size_t ws_size,
                              hipStream_t stream) {
    const float* x        = (const float*)d_in[0];
    const int*   ei       = (const int*)d_in[1];
    const float* W1       = (const float*)d_in[2];
    const float* att_src1 = (const float*)d_in[3];
    const float* att_dst1 = (const float*)d_in[4];
    const float* b1       = (const float*)d_in[5];
    const float* W2       = (const float*)d_in[6];
    const float* att_src2 = (const float*)d_in[7];
    const float* att_dst2 = (const float*)d_in[8];
    const float* b2       = (const float*)d_in[9];
    const float* Wl       = (const float*)d_in[10];
    const float* bl       = (const float*)d_in[11];
    float* out = (float*)d_out;

    // workspace layout (floats)
    float* ws   = (float*)d_ws;
    float* h1   = ws;                                  // 50000*512
    float* out1 = h1 + (long)N_NODES * 512;            // 50000*512
    float* as1  = out1 + (long)N_NODES * 512;          // 50000*8
    float* ad1  = as1 + (long)N_NODES * H1;            // 50000*8
    int* csr_off = (int*)(ad1 + (long)N_NODES * H1);   // N+1
    int* csr_cnt = csr_off + (N_NODES + 1);            // N
    int* csr_eid = csr_cnt + N_NODES;                  // E_TOT
    // layer-2 reuse of dead h1 region
    float* h2   = h1;
    float* out2 = h1 + (long)N_NODES * 64;

    const int BT = 256;
    dim3 blk(BT);

    // ---------------- CSR build (shared by both layers) ----------------
    fill_i32<<<256, blk, 0, stream>>>(csr_cnt, 0, N_NODES);
    count_deg<<<1024, blk, 0, stream>>>(ei, csr_cnt);
    scan_deg<<<1, 1024, 0, stream>>>(csr_cnt, csr_off, N_NODES);
    fill_i32<<<256, blk, 0, stream>>>(csr_cnt, 0, N_NODES);
    scatter_edges<<<1024, blk, 0, stream>>>(ei, csr_off, csr_cnt, csr_eid);

    // ---------------- layer 1 ----------------
    {   // h1 = x @ W1   [50000 x 512, K=500]
        dim3 grid(512 / 64, (N_NODES + 63) / 64);
        gemm_kernel<false><<<grid, blk, 0, stream>>>(x, W1, nullptr, h1, N_NODES, 512, F_IN);
    }
    {
        long waves = (long)N_NODES * H1;
        attn_dots<<<(waves * 64 + BT - 1) / BT, blk, 0, stream>>>(h1, att_src1, att_dst1,
                                                                  as1, ad1, N_NODES, H1);
    }
    {
        long waves = (long)N_NODES * H1;
        csr_agg<H1><<<(waves * 64 + BT - 1) / BT, blk, 0, stream>>>(
            ei, csr_off, csr_eid, as1, ad1, h1, b1, out1);
    }

    // ---------------- layer 2 (H=1) ----------------
    {   // h2 = out1 @ W2   [50000 x 64, K=512]
        dim3 grid(64 / 64, (N_NODES + 63) / 64);
        gemm_kernel<false><<<grid, blk, 0, stream>>>(out1, W2, nullptr, h2, N_NODES, 64, 512);
    }
    {
        long waves = (long)N_NODES;
        attn_dots<<<(waves * 64 + BT - 1) / BT, blk, 0, stream>>>(h2, att_src2, att_dst2,
                                                                  as1, ad1, N_NODES, 1);
    }
    {
        long waves = (long)N_NODES;
        csr_agg<1><<<(waves * 64 + BT - 1) / BT, blk, 0, stream>>>(
            ei, csr_off, csr_eid, as1, ad1, h2, b2, out2);
    }

    // ---------------- final linear: out = out2 @ Wl + bl ----------------
    {
        dim3 grid((F_IN + 63) / 64, (N_NODES + 63) / 64);
        gemm_kernel<true><<<grid, blk, 0, stream>>>(out2, Wl, bl, out, N_NODES, F_IN, 64);
    }
}

// Round 3
// 1312.763 us; speedup vs baseline: 1.7762x; 1.4170x over previous
//
#include <hip/hip_runtime.h>
#include <hip/hip_bf16.h>

// ---------------------------------------------------------------------------
// GAT 2-layer forward (PyG GATConv semantics, eval mode), fp32.
// R3: one-wave-per-dst CSR aggregation — all heads per wave, lane=edge
//     softmax, register-broadcast weighted gather (no atomics, no redundant
//     edge-list walks).
// ---------------------------------------------------------------------------

#define N_NODES 50000
#define F_IN    500
#define H1      8
#define C_DIM   64
#define E_RAW   600000
#define E_TOT   (E_RAW + N_NODES)
#define NEG_SLOPE 0.2f

__device__ __forceinline__ int edge_src(const int* ei, int e) {
    return (e < E_RAW) ? ei[e] : e - E_RAW;
}
__device__ __forceinline__ int edge_dst(const int* ei, int e) {
    return (e < E_RAW) ? ei[E_RAW + e] : e - E_RAW;
}

// ---------------- fills ----------------
__global__ void fill_i32(int* __restrict__ p, int v, long n) {
    long i = blockIdx.x * (long)blockDim.x + threadIdx.x;
    long stride = (long)gridDim.x * blockDim.x;
    for (; i < n; i += stride) p[i] = v;
}

// ---------------- CSR build ----------------
__global__ void count_deg(const int* __restrict__ ei, int* __restrict__ deg) {
    long i = blockIdx.x * (long)blockDim.x + threadIdx.x;
    long stride = (long)gridDim.x * blockDim.x;
    for (; i < E_TOT; i += stride) atomicAdd(&deg[edge_dst(ei, (int)i)], 1);
}

__global__ void scan_deg(const int* __restrict__ deg, int* __restrict__ off, int n) {
    __shared__ int part[1024];
    int t = threadIdx.x;
    int chunk = (n + 1023) >> 10;
    int b = t * chunk, e = min(b + chunk, n);
    int s = 0;
    for (int i = b; i < e; ++i) s += deg[i];
    part[t] = s;
    __syncthreads();
    for (int d = 1; d < 1024; d <<= 1) {
        int v = (t >= d) ? part[t - d] : 0;
        __syncthreads();
        part[t] += v;
        __syncthreads();
    }
    int excl = (t == 0) ? 0 : part[t - 1];
    for (int i = b; i < e; ++i) { int dv = deg[i]; off[i] = excl; excl += dv; }
    if (t == 1023) off[n] = part[1023];
}

__global__ void scatter_edges(const int* __restrict__ ei, const int* __restrict__ off,
                              int* __restrict__ cnt, int* __restrict__ eid) {
    long i = blockIdx.x * (long)blockDim.x + threadIdx.x;
    long stride = (long)gridDim.x * blockDim.x;
    for (; i < E_TOT; i += stride) {
        int d = edge_dst(ei, (int)i);
        int p = atomicAdd(&cnt[d], 1);
        eid[off[d] + p] = (int)i;
    }
}

// ---------------- simple tiled fp32 GEMM: C = A[MxK] * B[KxN] (+bias) -------
template<bool ADD_BIAS>
__global__ void gemm_kernel(const float* __restrict__ A, const float* __restrict__ B,
                            const float* __restrict__ bias, float* __restrict__ C,
                            int M, int N, int K) {
    __shared__ float As[16][65];
    __shared__ float Bs[16][64];
    int tid = threadIdx.x;
    int tx = tid & 15, ty = tid >> 4;
    int row0 = blockIdx.y * 64, col0 = blockIdx.x * 64;
    float acc[4][4] = {};
    for (int k0 = 0; k0 < K; k0 += 16) {
        #pragma unroll
        for (int i = 0; i < 4; ++i) {
            int idx = tid + i * 256;
            int m = idx >> 4, kk = idx & 15;
            int gr = row0 + m, gk = k0 + kk;
            float v = 0.f;
            if (gr < M && gk < K) v = A[(long)gr * K + gk];
            As[kk][m] = v;
        }
        #pragma unroll
        for (int i = 0; i < 4; ++i) {
            int idx = tid + i * 256;
            int kk = idx >> 6, n = idx & 63;
            int gk = k0 + kk, gc = col0 + n;
            float v = 0.f;
            if (gk < K && gc < N) v = B[(long)gk * N + gc];
            Bs[kk][n] = v;
        }
        __syncthreads();
        #pragma unroll
        for (int kk = 0; kk < 16; ++kk) {
            float a[4], b[4];
            #pragma unroll
            for (int i = 0; i < 4; ++i) a[i] = As[kk][ty * 4 + i];
            #pragma unroll
            for (int j = 0; j < 4; ++j) b[j] = Bs[kk][tx * 4 + j];
            #pragma unroll
            for (int i = 0; i < 4; ++i)
                #pragma unroll
                for (int j = 0; j < 4; ++j)
                    acc[i][j] += a[i] * b[j];
        }
        __syncthreads();
    }
    #pragma unroll
    for (int i = 0; i < 4; ++i) {
        int r = row0 + ty * 4 + i;
        if (r >= M) continue;
        #pragma unroll
        for (int j = 0; j < 4; ++j) {
            int c = col0 + tx * 4 + j;
            if (c >= N) continue;
            float v = acc[i][j];
            if (ADD_BIAS) v += bias[c];
            C[(long)r * N + c] = v;
        }
    }
}

// ---------------- per-node attention dots ----------------
__global__ void attn_dots(const float* __restrict__ h, const float* __restrict__ att_src,
                          const float* __restrict__ att_dst, float* __restrict__ a_s,
                          float* __restrict__ a_d, int N, int H) {
    long wid = (blockIdx.x * (long)blockDim.x + threadIdx.x) >> 6;
    int lane = threadIdx.x & 63;
    long total = (long)N * H;
    if (wid >= total) return;
    int n = (int)(wid / H), hh = (int)(wid % H);
    float v = h[(long)n * H * 64 + hh * 64 + lane];
    float s = v * att_src[hh * 64 + lane];
    float d = v * att_dst[hh * 64 + lane];
    #pragma unroll
    for (int m = 32; m >= 1; m >>= 1) { s += __shfl_xor(s, m); d += __shfl_xor(d, m); }
    if (lane == 0) { a_s[wid] = s; a_d[wid] = d; }
}

// ---------------- CSR aggregation: one wave per dst, all H heads ------------
// lane = edge for softmax (shfl-reduced per head); register-broadcast gather.
template<int H>
__global__ void csr_agg(const int* __restrict__ ei, const int* __restrict__ off,
                        const int* __restrict__ eid, const float* __restrict__ a_s,
                        const float* __restrict__ a_d, const float* __restrict__ h,
                        const float* __restrict__ bias, float* __restrict__ out) {
    long wid = (blockIdx.x * (long)blockDim.x + threadIdx.x) >> 6;
    int lane = threadIdx.x & 63;
    if (wid >= N_NODES) return;
    int dst = (int)wid;
    int b = off[dst], e2 = off[dst + 1];

    float ad[H];
    #pragma unroll
    for (int hh = 0; hh < H; ++hh) ad[hh] = a_d[(long)dst * H + hh];

    // ---- pass 1: per-head online softmax stats (lane = edge, chunked) ----
    float m[H], ssum[H];
    #pragma unroll
    for (int hh = 0; hh < H; ++hh) { m[hh] = -1e30f; ssum[hh] = 0.f; }

    for (int c = b; c < e2; c += 64) {
        int i = c + lane;
        bool act = i < e2;
        int src = 0;
        if (act) src = edge_src(ei, eid[i]);
        float x[H];
        #pragma unroll
        for (int hh = 0; hh < H; ++hh) {
            float v = act ? (a_s[(long)src * H + hh] + ad[hh]) : -1e30f;
            x[hh] = v > 0.f ? v : NEG_SLOPE * v;
        }
        #pragma unroll
        for (int hh = 0; hh < H; ++hh) {
            float cm = x[hh];
            #pragma unroll
            for (int d2 = 32; d2 >= 1; d2 >>= 1) cm = fmaxf(cm, __shfl_xor(cm, d2));
            float nm = fmaxf(m[hh], cm);
            float ce = act ? __expf(x[hh] - nm) : 0.f;
            #pragma unroll
            for (int d2 = 32; d2 >= 1; d2 >>= 1) ce += __shfl_xor(ce, d2);
            ssum[hh] = ssum[hh] * __expf(m[hh] - nm) + ce;
            m[hh] = nm;
        }
    }
    float inv[H];
    #pragma unroll
    for (int hh = 0; hh < H; ++hh) inv[hh] = 1.f / (ssum[hh] + 1e-16f);

    // ---- pass 2: weighted gather (broadcast alpha+src from lane j) ----
    float acc[H];
    #pragma unroll
    for (int hh = 0; hh < H; ++hh) acc[hh] = 0.f;

    for (int c = b; c < e2; c += 64) {
        int i = c + lane;
        bool act = i < e2;
        int src = 0;
        float alpha[H];
        if (act) {
            src = edge_src(ei, eid[i]);
            #pragma unroll
            for (int hh = 0; hh < H; ++hh) {
                float v = a_s[(long)src * H + hh] + ad[hh];
                v = v > 0.f ? v : NEG_SLOPE * v;
                alpha[hh] = __expf(v - m[hh]) * inv[hh];
            }
        } else {
            #pragma unroll
            for (int hh = 0; hh < H; ++hh) alpha[hh] = 0.f;
        }
        int cnt = min(64, e2 - c);
        for (int j = 0; j < cnt; ++j) {
            int sj = __shfl(src, j);
            const float* hrow = h + (long)sj * (H * 64);
            #pragma unroll
            for (int hh = 0; hh < H; ++hh) {
                float al = __shfl(alpha[hh], j);
                acc[hh] += al * hrow[hh * 64 + lane];
            }
        }
    }
    #pragma unroll
    for (int hh = 0; hh < H; ++hh) {
        float v = acc[hh] + bias[hh * 64 + lane];
        out[((long)dst * H + hh) * 64 + lane] = v > 0.f ? v : (__expf(v) - 1.f);
    }
}

// ---------------------------------------------------------------------------
extern "C" void kernel_launch(void* const* d_in, const int* in_sizes, int n_in,
                              void* d_out, int out_size, void* d_ws, size_t ws_size,
                              hipStream_t stream) {
    const float* x        = (const float*)d_in[0];
    const int*   ei       = (const int*)d_in[1];
    const float* W1       = (const float*)d_in[2];
    const float* att_src1 = (const float*)d_in[3];
    const float* att_dst1 = (const float*)d_in[4];
    const float* b1       = (const float*)d_in[5];
    const float* W2       = (const float*)d_in[6];
    const float* att_src2 = (const float*)d_in[7];
    const float* att_dst2 = (const float*)d_in[8];
    const float* b2       = (const float*)d_in[9];
    const float* Wl       = (const float*)d_in[10];
    const float* bl       = (const float*)d_in[11];
    float* out = (float*)d_out;

    // workspace layout (floats)
    float* ws   = (float*)d_ws;
    float* h1   = ws;                                  // 50000*512
    float* out1 = h1 + (long)N_NODES * 512;            // 50000*512
    float* as1  = out1 + (long)N_NODES * 512;          // 50000*8
    float* ad1  = as1 + (long)N_NODES * H1;            // 50000*8
    int* csr_off = (int*)(ad1 + (long)N_NODES * H1);   // N+1
    int* csr_cnt = csr_off + (N_NODES + 1);            // N
    int* csr_eid = csr_cnt + N_NODES;                  // E_TOT
    // layer-2 reuse of dead h1 region
    float* h2   = h1;
    float* out2 = h1 + (long)N_NODES * 64;

    const int BT = 256;
    dim3 blk(BT);

    // ---------------- CSR build (shared by both layers) ----------------
    fill_i32<<<256, blk, 0, stream>>>(csr_cnt, 0, N_NODES);
    count_deg<<<1024, blk, 0, stream>>>(ei, csr_cnt);
    scan_deg<<<1, 1024, 0, stream>>>(csr_cnt, csr_off, N_NODES);
    fill_i32<<<256, blk, 0, stream>>>(csr_cnt, 0, N_NODES);
    scatter_edges<<<1024, blk, 0, stream>>>(ei, csr_off, csr_cnt, csr_eid);

    // ---------------- layer 1 ----------------
    {   // h1 = x @ W1   [50000 x 512, K=500]
        dim3 grid(512 / 64, (N_NODES + 63) / 64);
        gemm_kernel<false><<<grid, blk, 0, stream>>>(x, W1, nullptr, h1, N_NODES, 512, F_IN);
    }
    {
        long waves = (long)N_NODES * H1;
        attn_dots<<<(waves * 64 + BT - 1) / BT, blk, 0, stream>>>(h1, att_src1, att_dst1,
                                                                  as1, ad1, N_NODES, H1);
    }
    {
        long waves = (long)N_NODES;
        csr_agg<H1><<<(waves * 64 + BT - 1) / BT, blk, 0, stream>>>(
            ei, csr_off, csr_eid, as1, ad1, h1, b1, out1);
    }

    // ---------------- layer 2 (H=1) ----------------
    {   // h2 = out1 @ W2   [50000 x 64, K=512]
        dim3 grid(64 / 64, (N_NODES + 63) / 64);
        gemm_kernel<false><<<grid, blk, 0, stream>>>(out1, W2, nullptr, h2, N_NODES, 64, 512);
    }
    {
        long waves = (long)N_NODES;
        attn_dots<<<(waves * 64 + BT - 1) / BT, blk, 0, stream>>>(h2, att_src2, att_dst2,
                                                                  as1, ad1, N_NODES, 1);
    }
    {
        long waves = (long)N_NODES;
        csr_agg<1><<<(waves * 64 + BT - 1) / BT, blk, 0, stream>>>(
            ei, csr_off, csr_eid, as1, ad1, h2, b2, out2);
    }

    // ---------------- final linear: out = out2 @ Wl + bl ----------------
    {
        dim3 grid((F_IN + 63) / 64, (N_NODES + 63) / 64);
        gemm_kernel<true><<<grid, blk, 0, stream>>>(out2, Wl, bl, out, N_NODES, F_IN, 64);
    }
}

// Round 4
// 786.131 us; speedup vs baseline: 2.9661x; 1.6699x over previous
//
#include <hip/hip_runtime.h>
#include <hip/hip_bf16.h>

// ---------------------------------------------------------------------------
// GAT 2-layer forward (PyG GATConv semantics, eval mode).
// R4: GEMM1 (50000x512x500) via bf16 MFMA (16x16x32), inputs converted to
//     bf16 (x zero-padded, W1 transposed). Rest unchanged from R3.
// ---------------------------------------------------------------------------

#define N_NODES 50000
#define F_IN    500
#define H1      8
#define C_DIM   64
#define E_RAW   600000
#define E_TOT   (E_RAW + N_NODES)
#define NEG_SLOPE 0.2f

#define MP      50048      // N_NODES padded to multiple of 128
#define KP      512        // F_IN padded to multiple of 64

typedef __attribute__((ext_vector_type(8))) short bf16x8;
typedef __attribute__((ext_vector_type(4))) float f32x4;

__device__ __forceinline__ int edge_src(const int* ei, int e) {
    return (e < E_RAW) ? ei[e] : e - E_RAW;
}
__device__ __forceinline__ int edge_dst(const int* ei, int e) {
    return (e < E_RAW) ? ei[E_RAW + e] : e - E_RAW;
}

__device__ __forceinline__ unsigned short f32_to_bf16(float f) {
    unsigned int u = __float_as_uint(f);
    u += 0x7fffu + ((u >> 16) & 1u);       // RNE
    return (unsigned short)(u >> 16);
}

// ---------------- fills ----------------
__global__ void fill_i32(int* __restrict__ p, int v, long n) {
    long i = blockIdx.x * (long)blockDim.x + threadIdx.x;
    long stride = (long)gridDim.x * blockDim.x;
    for (; i < n; i += stride) p[i] = v;
}

// ---------------- CSR build ----------------
__global__ void count_deg(const int* __restrict__ ei, int* __restrict__ deg) {
    long i = blockIdx.x * (long)blockDim.x + threadIdx.x;
    long stride = (long)gridDim.x * blockDim.x;
    for (; i < E_TOT; i += stride) atomicAdd(&deg[edge_dst(ei, (int)i)], 1);
}

__global__ void scan_deg(const int* __restrict__ deg, int* __restrict__ off, int n) {
    __shared__ int part[1024];
    int t = threadIdx.x;
    int chunk = (n + 1023) >> 10;
    int b = t * chunk, e = min(b + chunk, n);
    int s = 0;
    for (int i = b; i < e; ++i) s += deg[i];
    part[t] = s;
    __syncthreads();
    for (int d = 1; d < 1024; d <<= 1) {
        int v = (t >= d) ? part[t - d] : 0;
        __syncthreads();
        part[t] += v;
        __syncthreads();
    }
    int excl = (t == 0) ? 0 : part[t - 1];
    for (int i = b; i < e; ++i) { int dv = deg[i]; off[i] = excl; excl += dv; }
    if (t == 1023) off[n] = part[1023];
}

__global__ void scatter_edges(const int* __restrict__ ei, const int* __restrict__ off,
                              int* __restrict__ cnt, int* __restrict__ eid) {
    long i = blockIdx.x * (long)blockDim.x + threadIdx.x;
    long stride = (long)gridDim.x * blockDim.x;
    for (; i < E_TOT; i += stride) {
        int d = edge_dst(ei, (int)i);
        int p = atomicAdd(&cnt[d], 1);
        eid[off[d] + p] = (int)i;
    }
}

// ---------------- bf16 conversion kernels ----------------
__global__ void cvt_x_bf16(const float* __restrict__ x, unsigned short* __restrict__ xb) {
    // xb: [MP][KP] bf16, zero-padded; one thread per bf16 pair
    long idx = blockIdx.x * (long)blockDim.x + threadIdx.x;
    long total = (long)MP * (KP / 2);
    long stride = (long)gridDim.x * blockDim.x;
    for (; idx < total; idx += stride) {
        int r = (int)(idx >> 8);           // KP/2 = 256
        int c0 = ((int)idx & 255) * 2;
        float v0 = (r < N_NODES && c0 < F_IN) ? x[(long)r * F_IN + c0] : 0.f;
        float v1 = (r < N_NODES && c0 + 1 < F_IN) ? x[(long)r * F_IN + c0 + 1] : 0.f;
        unsigned int packed = (unsigned int)f32_to_bf16(v0) |
                              ((unsigned int)f32_to_bf16(v1) << 16);
        ((unsigned int*)xb)[idx] = packed;
    }
}

__global__ void cvt_w1t_bf16(const float* __restrict__ W1, unsigned short* __restrict__ w1t) {
    // w1t: [512 n][KP k] bf16 (transposed, k-contiguous, k>=F_IN zero)
    int idx = blockIdx.x * blockDim.x + threadIdx.x;   // n*256 + k2
    if (idx >= 512 * (KP / 2)) return;
    int n = idx >> 8, k0 = (idx & 255) * 2;
    float v0 = (k0 < F_IN) ? W1[(long)k0 * 512 + n] : 0.f;
    float v1 = (k0 + 1 < F_IN) ? W1[(long)(k0 + 1) * 512 + n] : 0.f;
    unsigned int packed = (unsigned int)f32_to_bf16(v0) |
                          ((unsigned int)f32_to_bf16(v1) << 16);
    ((unsigned int*)w1t)[idx] = packed;
}

// ---------------- bf16 MFMA GEMM: C[M][512] = A[MP][512]bf16 * Bt[512][512]bf16^T
#define LDP 72   // padded LDS row stride (elements)

__global__ __launch_bounds__(256) void gemm1_mfma(
        const unsigned short* __restrict__ A,   // [MP][KP] bf16 row-major
        const unsigned short* __restrict__ Bt,  // [512][KP] bf16 [n][k]
        float* __restrict__ C) {                // [N_NODES][512] f32
    __shared__ unsigned short As[128 * LDP];
    __shared__ unsigned short Bs[128 * LDP];
    int tid = threadIdx.x;
    int lane = tid & 63, wid = tid >> 6;
    int wrow = wid >> 1, wcol = wid & 1;
    int brow = blockIdx.y, bcol = blockIdx.x;

    f32x4 acc[4][4];
    const f32x4 zero = {0.f, 0.f, 0.f, 0.f};
    #pragma unroll
    for (int mi = 0; mi < 4; ++mi)
        #pragma unroll
        for (int ni = 0; ni < 4; ++ni) acc[mi][ni] = zero;

    int lrow = lane & 15, lkb = lane >> 4;

    for (int k0 = 0; k0 < KP; k0 += 64) {
        #pragma unroll
        for (int it = 0; it < 4; ++it) {
            int slot = tid + it * 256;         // 0..1023: 128 rows x 8 segs
            int row = slot >> 3, seg = slot & 7;
            *(int4*)(As + row * LDP + seg * 8) =
                *(const int4*)(A + ((long)(brow * 128 + row)) * KP + k0 + seg * 8);
            *(int4*)(Bs + row * LDP + seg * 8) =
                *(const int4*)(Bt + ((long)(bcol * 128 + row)) * KP + k0 + seg * 8);
        }
        __syncthreads();
        #pragma unroll
        for (int ks = 0; ks < 2; ++ks) {
            bf16x8 af[4], bfr[4];
            #pragma unroll
            for (int mi = 0; mi < 4; ++mi)
                af[mi] = *(const bf16x8*)(As + (wrow * 64 + mi * 16 + lrow) * LDP +
                                          ks * 32 + lkb * 8);
            #pragma unroll
            for (int ni = 0; ni < 4; ++ni)
                bfr[ni] = *(const bf16x8*)(Bs + (wcol * 64 + ni * 16 + lrow) * LDP +
                                           ks * 32 + lkb * 8);
            #pragma unroll
            for (int mi = 0; mi < 4; ++mi)
                #pragma unroll
                for (int ni = 0; ni < 4; ++ni)
                    acc[mi][ni] = __builtin_amdgcn_mfma_f32_16x16x32_bf16(
                        af[mi], bfr[ni], acc[mi][ni], 0, 0, 0);
        }
        __syncthreads();
    }

    // C/D layout: col = lane&15, row = (lane>>4)*4 + reg   [m89]
    #pragma unroll
    for (int mi = 0; mi < 4; ++mi) {
        #pragma unroll
        for (int reg = 0; reg < 4; ++reg) {
            int r = brow * 128 + wrow * 64 + mi * 16 + lkb * 4 + reg;
            if (r >= N_NODES) continue;
            #pragma unroll
            for (int ni = 0; ni < 4; ++ni) {
                int c = bcol * 128 + wcol * 64 + ni * 16 + lrow;
                C[(long)r * 512 + c] = acc[mi][ni][reg];
            }
        }
    }
}

// ---------------- simple tiled fp32 GEMM (layers 2/3) ----------------
template<bool ADD_BIAS>
__global__ void gemm_kernel(const float* __restrict__ A, const float* __restrict__ B,
                            const float* __restrict__ bias, float* __restrict__ C,
                            int M, int N, int K) {
    __shared__ float As[16][65];
    __shared__ float Bs[16][64];
    int tid = threadIdx.x;
    int tx = tid & 15, ty = tid >> 4;
    int row0 = blockIdx.y * 64, col0 = blockIdx.x * 64;
    float acc[4][4] = {};
    for (int k0 = 0; k0 < K; k0 += 16) {
        #pragma unroll
        for (int i = 0; i < 4; ++i) {
            int idx = tid + i * 256;
            int m = idx >> 4, kk = idx & 15;
            int gr = row0 + m, gk = k0 + kk;
            float v = 0.f;
            if (gr < M && gk < K) v = A[(long)gr * K + gk];
            As[kk][m] = v;
        }
        #pragma unroll
        for (int i = 0; i < 4; ++i) {
            int idx = tid + i * 256;
            int kk = idx >> 6, n = idx & 63;
            int gk = k0 + kk, gc = col0 + n;
            float v = 0.f;
            if (gk < K && gc < N) v = B[(long)gk * N + gc];
            Bs[kk][n] = v;
        }
        __syncthreads();
        #pragma unroll
        for (int kk = 0; kk < 16; ++kk) {
            float a[4], b[4];
            #pragma unroll
            for (int i = 0; i < 4; ++i) a[i] = As[kk][ty * 4 + i];
            #pragma unroll
            for (int j = 0; j < 4; ++j) b[j] = Bs[kk][tx * 4 + j];
            #pragma unroll
            for (int i = 0; i < 4; ++i)
                #pragma unroll
                for (int j = 0; j < 4; ++j)
                    acc[i][j] += a[i] * b[j];
        }
        __syncthreads();
    }
    #pragma unroll
    for (int i = 0; i < 4; ++i) {
        int r = row0 + ty * 4 + i;
        if (r >= M) continue;
        #pragma unroll
        for (int j = 0; j < 4; ++j) {
            int c = col0 + tx * 4 + j;
            if (c >= N) continue;
            float v = acc[i][j];
            if (ADD_BIAS) v += bias[c];
            C[(long)r * N + c] = v;
        }
    }
}

// ---------------- per-node attention dots ----------------
__global__ void attn_dots(const float* __restrict__ h, const float* __restrict__ att_src,
                          const float* __restrict__ att_dst, float* __restrict__ a_s,
                          float* __restrict__ a_d, int N, int H) {
    long wid = (blockIdx.x * (long)blockDim.x + threadIdx.x) >> 6;
    int lane = threadIdx.x & 63;
    long total = (long)N * H;
    if (wid >= total) return;
    int n = (int)(wid / H), hh = (int)(wid % H);
    float v = h[(long)n * H * 64 + hh * 64 + lane];
    float s = v * att_src[hh * 64 + lane];
    float d = v * att_dst[hh * 64 + lane];
    #pragma unroll
    for (int m = 32; m >= 1; m >>= 1) { s += __shfl_xor(s, m); d += __shfl_xor(d, m); }
    if (lane == 0) { a_s[wid] = s; a_d[wid] = d; }
}

// ---------------- CSR aggregation: one wave per dst, all H heads ------------
template<int H>
__global__ void csr_agg(const int* __restrict__ ei, const int* __restrict__ off,
                        const int* __restrict__ eid, const float* __restrict__ a_s,
                        const float* __restrict__ a_d, const float* __restrict__ h,
                        const float* __restrict__ bias, float* __restrict__ out) {
    long wid = (blockIdx.x * (long)blockDim.x + threadIdx.x) >> 6;
    int lane = threadIdx.x & 63;
    if (wid >= N_NODES) return;
    int dst = (int)wid;
    int b = off[dst], e2 = off[dst + 1];

    float ad[H];
    #pragma unroll
    for (int hh = 0; hh < H; ++hh) ad[hh] = a_d[(long)dst * H + hh];

    float m[H], ssum[H];
    #pragma unroll
    for (int hh = 0; hh < H; ++hh) { m[hh] = -1e30f; ssum[hh] = 0.f; }

    for (int c = b; c < e2; c += 64) {
        int i = c + lane;
        bool act = i < e2;
        int src = 0;
        if (act) src = edge_src(ei, eid[i]);
        float x[H];
        #pragma unroll
        for (int hh = 0; hh < H; ++hh) {
            float v = act ? (a_s[(long)src * H + hh] + ad[hh]) : -1e30f;
            x[hh] = v > 0.f ? v : NEG_SLOPE * v;
        }
        #pragma unroll
        for (int hh = 0; hh < H; ++hh) {
            float cm = x[hh];
            #pragma unroll
            for (int d2 = 32; d2 >= 1; d2 >>= 1) cm = fmaxf(cm, __shfl_xor(cm, d2));
            float nm = fmaxf(m[hh], cm);
            float ce = act ? __expf(x[hh] - nm) : 0.f;
            #pragma unroll
            for (int d2 = 32; d2 >= 1; d2 >>= 1) ce += __shfl_xor(ce, d2);
            ssum[hh] = ssum[hh] * __expf(m[hh] - nm) + ce;
            m[hh] = nm;
        }
    }
    float inv[H];
    #pragma unroll
    for (int hh = 0; hh < H; ++hh) inv[hh] = 1.f / (ssum[hh] + 1e-16f);

    float acc[H];
    #pragma unroll
    for (int hh = 0; hh < H; ++hh) acc[hh] = 0.f;

    for (int c = b; c < e2; c += 64) {
        int i = c + lane;
        bool act = i < e2;
        int src = 0;
        float alpha[H];
        if (act) {
            src = edge_src(ei, eid[i]);
            #pragma unroll
            for (int hh = 0; hh < H; ++hh) {
                float v = a_s[(long)src * H + hh] + ad[hh];
                v = v > 0.f ? v : NEG_SLOPE * v;
                alpha[hh] = __expf(v - m[hh]) * inv[hh];
            }
        } else {
            #pragma unroll
            for (int hh = 0; hh < H; ++hh) alpha[hh] = 0.f;
        }
        int cnt = min(64, e2 - c);
        for (int j = 0; j < cnt; ++j) {
            int sj = __shfl(src, j);
            const float* hrow = h + (long)sj * (H * 64);
            #pragma unroll
            for (int hh = 0; hh < H; ++hh) {
                float al = __shfl(alpha[hh], j);
                acc[hh] += al * hrow[hh * 64 + lane];
            }
        }
    }
    #pragma unroll
    for (int hh = 0; hh < H; ++hh) {
        float v = acc[hh] + bias[hh * 64 + lane];
        out[((long)dst * H + hh) * 64 + lane] = v > 0.f ? v : (__expf(v) - 1.f);
    }
}

// ---------------------------------------------------------------------------
extern "C" void kernel_launch(void* const* d_in, const int* in_sizes, int n_in,
                              void* d_out, int out_size, void* d_ws, size_t ws_size,
                              hipStream_t stream) {
    const float* x        = (const float*)d_in[0];
    const int*   ei       = (const int*)d_in[1];
    const float* W1       = (const float*)d_in[2];
    const float* att_src1 = (const float*)d_in[3];
    const float* att_dst1 = (const float*)d_in[4];
    const float* b1       = (const float*)d_in[5];
    const float* W2       = (const float*)d_in[6];
    const float* att_src2 = (const float*)d_in[7];
    const float* att_dst2 = (const float*)d_in[8];
    const float* b2       = (const float*)d_in[9];
    const float* Wl       = (const float*)d_in[10];
    const float* bl       = (const float*)d_in[11];
    float* out = (float*)d_out;

    // workspace layout (floats)
    float* ws   = (float*)d_ws;
    float* h1   = ws;                                  // 50000*512
    float* out1 = h1 + (long)N_NODES * 512;            // 50000*512
    float* as1  = out1 + (long)N_NODES * 512;          // 50000*8
    float* ad1  = as1 + (long)N_NODES * H1;            // 50000*8
    int* csr_off = (int*)(ad1 + (long)N_NODES * H1);   // N+1
    int* csr_cnt = csr_off + (N_NODES + 1);            // N
    int* csr_eid = csr_cnt + N_NODES;                  // E_TOT
    unsigned short* w1t = (unsigned short*)(csr_eid + E_TOT);  // 512*512 bf16
    // xb aliases out1 (dead until csr_agg L1 writes it; xb consumed by gemm1)
    unsigned short* xb = (unsigned short*)out1;        // MP*KP bf16 = 51.25MB
    // layer-2 reuse of dead h1 region
    float* h2   = h1;
    float* out2 = h1 + (long)N_NODES * 64;

    const int BT = 256;
    dim3 blk(BT);

    // ---------------- CSR build (shared by both layers) ----------------
    fill_i32<<<256, blk, 0, stream>>>(csr_cnt, 0, N_NODES);
    count_deg<<<1024, blk, 0, stream>>>(ei, csr_cnt);
    scan_deg<<<1, 1024, 0, stream>>>(csr_cnt, csr_off, N_NODES);
    fill_i32<<<256, blk, 0, stream>>>(csr_cnt, 0, N_NODES);
    scatter_edges<<<1024, blk, 0, stream>>>(ei, csr_off, csr_cnt, csr_eid);

    // ---------------- layer 1 ----------------
    cvt_x_bf16<<<2048, blk, 0, stream>>>(x, xb);
    cvt_w1t_bf16<<<512, blk, 0, stream>>>(W1, w1t);
    {   // h1 = xb @ w1t^T  [MP x 512, K=KP] via MFMA
        dim3 grid(512 / 128, MP / 128);
        gemm1_mfma<<<grid, blk, 0, stream>>>(xb, w1t, h1);
    }
    {
        long waves = (long)N_NODES * H1;
        attn_dots<<<(waves * 64 + BT - 1) / BT, blk, 0, stream>>>(h1, att_src1, att_dst1,
                                                                  as1, ad1, N_NODES, H1);
    }
    {
        long waves = (long)N_NODES;
        csr_agg<H1><<<(waves * 64 + BT - 1) / BT, blk, 0, stream>>>(
            ei, csr_off, csr_eid, as1, ad1, h1, b1, out1);
    }

    // ---------------- layer 2 (H=1) ----------------
    {   // h2 = out1 @ W2   [50000 x 64, K=512]
        dim3 grid(64 / 64, (N_NODES + 63) / 64);
        gemm_kernel<false><<<grid, blk, 0, stream>>>(out1, W2, nullptr, h2, N_NODES, 64, 512);
    }
    {
        long waves = (long)N_NODES;
        attn_dots<<<(waves * 64 + BT - 1) / BT, blk, 0, stream>>>(h2, att_src2, att_dst2,
                                                                  as1, ad1, N_NODES, 1);
    }
    {
        long waves = (long)N_NODES;
        csr_agg<1><<<(waves * 64 + BT - 1) / BT, blk, 0, stream>>>(
            ei, csr_off, csr_eid, as1, ad1, h2, b2, out2);
    }

    // ---------------- final linear: out = out2 @ Wl + bl ----------------
    {
        dim3 grid((F_IN + 63) / 64, (N_NODES + 63) / 64);
        gemm_kernel<true><<<grid, blk, 0, stream>>>(out2, Wl, bl, out, N_NODES, F_IN, 64);
    }
}

// Round 5
// 495.380 us; speedup vs baseline: 4.7070x; 1.5869x over previous
//
#include <hip/hip_runtime.h>
#include <hip/hip_bf16.h>

// ---------------------------------------------------------------------------
// GAT 2-layer forward (PyG GATConv semantics, eval mode).
// R5: full bf16 dataflow. All three GEMMs bf16-MFMA (f32 accumulate);
//     h1/out1/h2/out2 stored bf16 (halves gather bytes); csr_agg8 gathers
//     one int4 (8 bf16) per lane per edge with LDS-staged alphas.
// ---------------------------------------------------------------------------

#define N_NODES 50000
#define F_IN    500
#define H1      8
#define E_RAW   600000
#define E_TOT   (E_RAW + N_NODES)
#define NEG_SLOPE 0.2f

#define MP      50048      // N_NODES padded to multiple of 128
#define KP      512        // F_IN padded

typedef __attribute__((ext_vector_type(8))) short bf16x8;
typedef __attribute__((ext_vector_type(4))) float f32x4;
typedef unsigned short ushort_t;

__device__ __forceinline__ int edge_src(const int* ei, int e) {
    return (e < E_RAW) ? ei[e] : e - E_RAW;
}
__device__ __forceinline__ int edge_dst(const int* ei, int e) {
    return (e < E_RAW) ? ei[E_RAW + e] : e - E_RAW;
}

__device__ __forceinline__ unsigned short f32_to_bf16(float f) {
    unsigned int u = __float_as_uint(f);
    u += 0x7fffu + ((u >> 16) & 1u);       // RNE
    return (unsigned short)(u >> 16);
}
__device__ __forceinline__ float bf16_lo(unsigned int u) {
    return __uint_as_float(u << 16);
}
__device__ __forceinline__ float bf16_hi(unsigned int u) {
    return __uint_as_float(u & 0xffff0000u);
}

// ---------------- fills ----------------
__global__ void fill_i32(int* __restrict__ p, int v, long n) {
    long i = blockIdx.x * (long)blockDim.x + threadIdx.x;
    long stride = (long)gridDim.x * blockDim.x;
    for (; i < n; i += stride) p[i] = v;
}

// ---------------- CSR build ----------------
__global__ void count_deg(const int* __restrict__ ei, int* __restrict__ deg) {
    long i = blockIdx.x * (long)blockDim.x + threadIdx.x;
    long stride = (long)gridDim.x * blockDim.x;
    for (; i < E_TOT; i += stride) atomicAdd(&deg[edge_dst(ei, (int)i)], 1);
}

__global__ void scan_deg(const int* __restrict__ deg, int* __restrict__ off, int n) {
    __shared__ int part[1024];
    int t = threadIdx.x;
    int chunk = (n + 1023) >> 10;
    int b = t * chunk, e = min(b + chunk, n);
    int s = 0;
    for (int i = b; i < e; ++i) s += deg[i];
    part[t] = s;
    __syncthreads();
    for (int d = 1; d < 1024; d <<= 1) {
        int v = (t >= d) ? part[t - d] : 0;
        __syncthreads();
        part[t] += v;
        __syncthreads();
    }
    int excl = (t == 0) ? 0 : part[t - 1];
    for (int i = b; i < e; ++i) { int dv = deg[i]; off[i] = excl; excl += dv; }
    if (t == 1023) off[n] = part[1023];
}

__global__ void scatter_edges(const int* __restrict__ ei, const int* __restrict__ off,
                              int* __restrict__ cnt, int* __restrict__ eid) {
    long i = blockIdx.x * (long)blockDim.x + threadIdx.x;
    long stride = (long)gridDim.x * blockDim.x;
    for (; i < E_TOT; i += stride) {
        int d = edge_dst(ei, (int)i);
        int p = atomicAdd(&cnt[d], 1);
        eid[off[d] + p] = (int)i;
    }
}

// ---------------- bf16 conversion kernels ----------------
__global__ void cvt_x_bf16(const float* __restrict__ x, ushort_t* __restrict__ xb) {
    long idx = blockIdx.x * (long)blockDim.x + threadIdx.x;
    long total = (long)MP * (KP / 2);
    long stride = (long)gridDim.x * blockDim.x;
    for (; idx < total; idx += stride) {
        int r = (int)(idx >> 8);
        int c0 = ((int)idx & 255) * 2;
        float v0 = (r < N_NODES && c0 < F_IN) ? x[(long)r * F_IN + c0] : 0.f;
        float v1 = (r < N_NODES && c0 + 1 < F_IN) ? x[(long)r * F_IN + c0 + 1] : 0.f;
        ((unsigned int*)xb)[idx] = (unsigned int)f32_to_bf16(v0) |
                                   ((unsigned int)f32_to_bf16(v1) << 16);
    }
}

__global__ void cvt_w1t_bf16(const float* __restrict__ W1, ushort_t* __restrict__ w1t) {
    // w1t[n][k], n<512, k<KP; W1 is [F_IN][512]
    int idx = blockIdx.x * blockDim.x + threadIdx.x;
    if (idx >= 512 * (KP / 2)) return;
    int n = idx >> 8, k0 = (idx & 255) * 2;
    float v0 = (k0 < F_IN) ? W1[(long)k0 * 512 + n] : 0.f;
    float v1 = (k0 + 1 < F_IN) ? W1[(long)(k0 + 1) * 512 + n] : 0.f;
    ((unsigned int*)w1t)[idx] = (unsigned int)f32_to_bf16(v0) |
                                ((unsigned int)f32_to_bf16(v1) << 16);
}

__global__ void cvt_w2t_bf16(const float* __restrict__ W2, ushort_t* __restrict__ w2t) {
    // w2t[n][k], n<64, k<512; W2 is [512][64]
    int idx = blockIdx.x * blockDim.x + threadIdx.x;
    if (idx >= 64 * 256) return;
    int n = idx >> 8, k0 = (idx & 255) * 2;
    float v0 = W2[(long)k0 * 64 + n];
    float v1 = W2[(long)(k0 + 1) * 64 + n];
    ((unsigned int*)w2t)[idx] = (unsigned int)f32_to_bf16(v0) |
                                ((unsigned int)f32_to_bf16(v1) << 16);
}

__global__ void cvt_wlt_bf16(const float* __restrict__ Wl, ushort_t* __restrict__ wlt) {
    // wlt[n][k], n<512 (pad from 500), k<64; Wl is [64][500]
    int idx = blockIdx.x * blockDim.x + threadIdx.x;
    if (idx >= 512 * 32) return;
    int n = idx >> 5, k0 = (idx & 31) * 2;
    float v0 = (n < F_IN) ? Wl[(long)k0 * F_IN + n] : 0.f;
    float v1 = (n < F_IN) ? Wl[(long)(k0 + 1) * F_IN + n] : 0.f;
    ((unsigned int*)wlt)[idx] = (unsigned int)f32_to_bf16(v0) |
                                ((unsigned int)f32_to_bf16(v1) << 16);
}

// ---------------- GEMM1: h1b[MP][512] = xb[MP][KP] @ w1t[512][KP]^T --------
#define LDP 72

__global__ __launch_bounds__(256) void gemm1_mfma(
        const ushort_t* __restrict__ A, const ushort_t* __restrict__ Bt,
        ushort_t* __restrict__ C) {
    __shared__ ushort_t As[128 * LDP];
    __shared__ ushort_t Bs[128 * LDP];
    int tid = threadIdx.x;
    int lane = tid & 63, wid = tid >> 6;
    int wrow = wid >> 1, wcol = wid & 1;
    int brow = blockIdx.y, bcol = blockIdx.x;

    f32x4 acc[4][4];
    const f32x4 zero = {0.f, 0.f, 0.f, 0.f};
    #pragma unroll
    for (int mi = 0; mi < 4; ++mi)
        #pragma unroll
        for (int ni = 0; ni < 4; ++ni) acc[mi][ni] = zero;

    int lrow = lane & 15, lkb = lane >> 4;

    for (int k0 = 0; k0 < KP; k0 += 64) {
        #pragma unroll
        for (int it = 0; it < 4; ++it) {
            int slot = tid + it * 256;
            int row = slot >> 3, seg = slot & 7;
            *(int4*)(As + row * LDP + seg * 8) =
                *(const int4*)(A + ((long)(brow * 128 + row)) * KP + k0 + seg * 8);
            *(int4*)(Bs + row * LDP + seg * 8) =
                *(const int4*)(Bt + ((long)(bcol * 128 + row)) * KP + k0 + seg * 8);
        }
        __syncthreads();
        #pragma unroll
        for (int ks = 0; ks < 2; ++ks) {
            bf16x8 af[4], bfr[4];
            #pragma unroll
            for (int mi = 0; mi < 4; ++mi)
                af[mi] = *(const bf16x8*)(As + (wrow * 64 + mi * 16 + lrow) * LDP +
                                          ks * 32 + lkb * 8);
            #pragma unroll
            for (int ni = 0; ni < 4; ++ni)
                bfr[ni] = *(const bf16x8*)(Bs + (wcol * 64 + ni * 16 + lrow) * LDP +
                                           ks * 32 + lkb * 8);
            #pragma unroll
            for (int mi = 0; mi < 4; ++mi)
                #pragma unroll
                for (int ni = 0; ni < 4; ++ni)
                    acc[mi][ni] = __builtin_amdgcn_mfma_f32_16x16x32_bf16(
                        af[mi], bfr[ni], acc[mi][ni], 0, 0, 0);
        }
        __syncthreads();
    }

    #pragma unroll
    for (int mi = 0; mi < 4; ++mi)
        #pragma unroll
        for (int reg = 0; reg < 4; ++reg) {
            int r = brow * 128 + wrow * 64 + mi * 16 + lkb * 4 + reg;
            #pragma unroll
            for (int ni = 0; ni < 4; ++ni) {
                int c = bcol * 128 + wcol * 64 + ni * 16 + lrow;
                C[(long)r * 512 + c] = f32_to_bf16(acc[mi][ni][reg]);
            }
        }
}

// ---------------- GEMM2: h2b[MP][64] = out1b[MP][512] @ w2t[64][512]^T -----
__global__ __launch_bounds__(256) void gemm2_mfma(
        const ushort_t* __restrict__ A, const ushort_t* __restrict__ Bt,
        ushort_t* __restrict__ C) {
    __shared__ ushort_t As[128 * LDP];
    __shared__ ushort_t Bs[64 * LDP];
    int tid = threadIdx.x;
    int lane = tid & 63, wid = tid >> 6;
    int wrow = wid >> 1, wcol = wid & 1;
    int brow = blockIdx.x;

    f32x4 acc[4][2];
    const f32x4 zero = {0.f, 0.f, 0.f, 0.f};
    #pragma unroll
    for (int mi = 0; mi < 4; ++mi) { acc[mi][0] = zero; acc[mi][1] = zero; }

    int lrow = lane & 15, lkb = lane >> 4;

    for (int k0 = 0; k0 < 512; k0 += 64) {
        #pragma unroll
        for (int it = 0; it < 4; ++it) {
            int slot = tid + it * 256;
            int row = slot >> 3, seg = slot & 7;
            *(int4*)(As + row * LDP + seg * 8) =
                *(const int4*)(A + ((long)(brow * 128 + row)) * 512 + k0 + seg * 8);
        }
        #pragma unroll
        for (int it = 0; it < 2; ++it) {
            int slot = tid + it * 256;
            int row = slot >> 3, seg = slot & 7;
            *(int4*)(Bs + row * LDP + seg * 8) =
                *(const int4*)(Bt + (long)row * 512 + k0 + seg * 8);
        }
        __syncthreads();
        #pragma unroll
        for (int ks = 0; ks < 2; ++ks) {
            bf16x8 af[4], bfr[2];
            #pragma unroll
            for (int mi = 0; mi < 4; ++mi)
                af[mi] = *(const bf16x8*)(As + (wrow * 64 + mi * 16 + lrow) * LDP +
                                          ks * 32 + lkb * 8);
            #pragma unroll
            for (int ni = 0; ni < 2; ++ni)
                bfr[ni] = *(const bf16x8*)(Bs + (wcol * 32 + ni * 16 + lrow) * LDP +
                                           ks * 32 + lkb * 8);
            #pragma unroll
            for (int mi = 0; mi < 4; ++mi)
                #pragma unroll
                for (int ni = 0; ni < 2; ++ni)
                    acc[mi][ni] = __builtin_amdgcn_mfma_f32_16x16x32_bf16(
                        af[mi], bfr[ni], acc[mi][ni], 0, 0, 0);
        }
        __syncthreads();
    }

    #pragma unroll
    for (int mi = 0; mi < 4; ++mi)
        #pragma unroll
        for (int reg = 0; reg < 4; ++reg) {
            int r = brow * 128 + wrow * 64 + mi * 16 + lkb * 4 + reg;
            #pragma unroll
            for (int ni = 0; ni < 2; ++ni) {
                int c = wcol * 32 + ni * 16 + lrow;
                C[(long)r * 64 + c] = f32_to_bf16(acc[mi][ni][reg]);
            }
        }
}

// ---------------- GEMM3: out[N][500] = out2b[MP][64] @ wlt[512][64]^T + bl --
__global__ __launch_bounds__(256) void gemm3_mfma(
        const ushort_t* __restrict__ A, const ushort_t* __restrict__ Bt,
        const float* __restrict__ bias, float* __restrict__ C) {
    __shared__ ushort_t As[128 * LDP];
    __shared__ ushort_t Bs[128 * LDP];
    int tid = threadIdx.x;
    int lane = tid & 63, wid = tid >> 6;
    int wrow = wid >> 1, wcol = wid & 1;
    int brow = blockIdx.y, bcol = blockIdx.x;

    f32x4 acc[4][4];
    const f32x4 zero = {0.f, 0.f, 0.f, 0.f};
    #pragma unroll
    for (int mi = 0; mi < 4; ++mi)
        #pragma unroll
        for (int ni = 0; ni < 4; ++ni) acc[mi][ni] = zero;

    int lrow = lane & 15, lkb = lane >> 4;

    #pragma unroll
    for (int it = 0; it < 4; ++it) {
        int slot = tid + it * 256;
        int row = slot >> 3, seg = slot & 7;
        *(int4*)(As + row * LDP + seg * 8) =
            *(const int4*)(A + ((long)(brow * 128 + row)) * 64 + seg * 8);
        *(int4*)(Bs + row * LDP + seg * 8) =
            *(const int4*)(Bt + ((long)(bcol * 128 + row)) * 64 + seg * 8);
    }
    __syncthreads();
    #pragma unroll
    for (int ks = 0; ks < 2; ++ks) {
        bf16x8 af[4], bfr[4];
        #pragma unroll
        for (int mi = 0; mi < 4; ++mi)
            af[mi] = *(const bf16x8*)(As + (wrow * 64 + mi * 16 + lrow) * LDP +
                                      ks * 32 + lkb * 8);
        #pragma unroll
        for (int ni = 0; ni < 4; ++ni)
            bfr[ni] = *(const bf16x8*)(Bs + (wcol * 64 + ni * 16 + lrow) * LDP +
                                       ks * 32 + lkb * 8);
        #pragma unroll
        for (int mi = 0; mi < 4; ++mi)
            #pragma unroll
            for (int ni = 0; ni < 4; ++ni)
                acc[mi][ni] = __builtin_amdgcn_mfma_f32_16x16x32_bf16(
                    af[mi], bfr[ni], acc[mi][ni], 0, 0, 0);
    }

    #pragma unroll
    for (int mi = 0; mi < 4; ++mi)
        #pragma unroll
        for (int reg = 0; reg < 4; ++reg) {
            int r = brow * 128 + wrow * 64 + mi * 16 + lkb * 4 + reg;
            if (r >= N_NODES) continue;
            #pragma unroll
            for (int ni = 0; ni < 4; ++ni) {
                int c = bcol * 128 + wcol * 64 + ni * 16 + lrow;
                if (c < F_IN) C[(long)r * F_IN + c] = acc[mi][ni][reg] + bias[c];
            }
        }
}

// ---------------- attention dots L1: wave per node, bf16 h ----------------
__global__ void attn_dots8(const ushort_t* __restrict__ hb, const float* __restrict__ att_s,
                           const float* __restrict__ att_d, float* __restrict__ a_s,
                           float* __restrict__ a_d) {
    long wid = (blockIdx.x * (long)blockDim.x + threadIdx.x) >> 6;
    int lane = threadIdx.x & 63;
    if (wid >= N_NODES) return;
    int n = (int)wid;
    int4 hv = *(const int4*)(hb + (long)n * 512 + lane * 8);
    const float* asp = att_s + lane * 8;
    const float* adp = att_d + lane * 8;
    float s = 0.f, d = 0.f;
    #pragma unroll
    for (int q = 0; q < 4; ++q) {
        unsigned u = ((const unsigned*)&hv)[q];
        float f0 = bf16_lo(u), f1 = bf16_hi(u);
        s += f0 * asp[2 * q] + f1 * asp[2 * q + 1];
        d += f0 * adp[2 * q] + f1 * adp[2 * q + 1];
    }
    #pragma unroll
    for (int m = 4; m >= 1; m >>= 1) { s += __shfl_xor(s, m); d += __shfl_xor(d, m); }
    if ((lane & 7) == 0) {
        a_s[(long)n * 8 + (lane >> 3)] = s;
        a_d[(long)n * 8 + (lane >> 3)] = d;
    }
}

// ---------------- attention dots L2 (H=1): wave per node ----------------
__global__ void attn_dots1(const ushort_t* __restrict__ hb, const float* __restrict__ att_s,
                           const float* __restrict__ att_d, float* __restrict__ a_s,
                           float* __restrict__ a_d) {
    long wid = (blockIdx.x * (long)blockDim.x + threadIdx.x) >> 6;
    int lane = threadIdx.x & 63;
    if (wid >= N_NODES) return;
    int n = (int)wid;
    float f = __uint_as_float(((unsigned)hb[(long)n * 64 + lane]) << 16);
    float s = f * att_s[lane], d = f * att_d[lane];
    #pragma unroll
    for (int m = 32; m >= 1; m >>= 1) { s += __shfl_xor(s, m); d += __shfl_xor(d, m); }
    if (lane == 0) { a_s[n] = s; a_d[n] = d; }
}

// ---------------- csr_agg8: wave per dst, 8 heads, bf16 gather --------------
// lane = (head = lane>>3, ch-block = (lane&7)*8); per-edge gather = 1 int4.
__global__ void csr_agg8(const int* __restrict__ ei, const int* __restrict__ off,
                         const int* __restrict__ eid, const float* __restrict__ a_s,
                         const float* __restrict__ a_d, const ushort_t* __restrict__ hb,
                         const float* __restrict__ bias, ushort_t* __restrict__ outb) {
    __shared__ float alds[4 * 512];          // per-wave [64 edges][8 heads]
    long wid = (blockIdx.x * (long)blockDim.x + threadIdx.x) >> 6;
    int lane = threadIdx.x & 63;
    if (wid >= N_NODES) return;
    int dst = (int)wid;
    float* aw = alds + ((threadIdx.x >> 6) << 9);
    int b = off[dst], e2 = off[dst + 1];
    int myh = lane >> 3;

    float ad[8];
    {
        const float* adp = a_d + (long)dst * 8;
        #pragma unroll
        for (int hh = 0; hh < 8; ++hh) ad[hh] = adp[hh];
    }

    // ---- pass 1: per-head online softmax stats ----
    float m[8], ssum[8];
    #pragma unroll
    for (int hh = 0; hh < 8; ++hh) { m[hh] = -1e30f; ssum[hh] = 0.f; }

    for (int c = b; c < e2; c += 64) {
        int i = c + lane;
        bool act = i < e2;
        int src = act ? edge_src(ei, eid[i]) : 0;
        float x[8];
        {
            const float* asp = a_s + (long)src * 8;
            #pragma unroll
            for (int hh = 0; hh < 8; ++hh) {
                float v = act ? (asp[hh] + ad[hh]) : -1e30f;
                x[hh] = v > 0.f ? v : NEG_SLOPE * v;
            }
        }
        #pragma unroll
        for (int hh = 0; hh < 8; ++hh) {
            float cm = x[hh];
            #pragma unroll
            for (int d2 = 32; d2 >= 1; d2 >>= 1) cm = fmaxf(cm, __shfl_xor(cm, d2));
            float nm = fmaxf(m[hh], cm);
            float ce = act ? __expf(x[hh] - nm) : 0.f;
            #pragma unroll
            for (int d2 = 32; d2 >= 1; d2 >>= 1) ce += __shfl_xor(ce, d2);
            ssum[hh] = ssum[hh] * __expf(m[hh] - nm) + ce;
            m[hh] = nm;
        }
    }
    float inv[8];
    #pragma unroll
    for (int hh = 0; hh < 8; ++hh) inv[hh] = 1.f / (ssum[hh] + 1e-16f);

    // ---- pass 2: gather with LDS-staged alphas ----
    float acc8[8];
    #pragma unroll
    for (int q = 0; q < 8; ++q) acc8[q] = 0.f;

    for (int c = b; c < e2; c += 64) {
        int i = c + lane;
        bool act = i < e2;
        int src = act ? edge_src(ei, eid[i]) : 0;
        {
            const float* asp = a_s + (long)src * 8;
            #pragma unroll
            for (int hh = 0; hh < 8; ++hh) {
                float v = act ? (asp[hh] + ad[hh]) : -1e30f;
                v = v > 0.f ? v : NEG_SLOPE * v;
                aw[lane * 8 + hh] = act ? __expf(v - m[hh]) * inv[hh] : 0.f;
            }
        }
        asm volatile("s_waitcnt lgkmcnt(0)" ::: "memory");
        int cnt = min(64, e2 - c);
        for (int j = 0; j < cnt; ++j) {
            int sj = __shfl(src, j);
            float aj = aw[j * 8 + myh];
            int4 hv = *(const int4*)(hb + (long)sj * 512 + lane * 8);
            #pragma unroll
            for (int q = 0; q < 4; ++q) {
                unsigned u = ((const unsigned*)&hv)[q];
                acc8[2 * q]     += aj * bf16_lo(u);
                acc8[2 * q + 1] += aj * bf16_hi(u);
            }
        }
        asm volatile("s_waitcnt lgkmcnt(0)" ::: "memory");
    }

    // epilogue: bias + ELU, pack bf16, one int4 store
    const float* bp = bias + lane * 8;
    int4 st;
    #pragma unroll
    for (int q = 0; q < 8; ++q) {
        float v = acc8[q] + bp[q];
        v = v > 0.f ? v : (__expf(v) - 1.f);
        ((ushort_t*)&st)[q] = f32_to_bf16(v);
    }
    *(int4*)(outb + (long)dst * 512 + lane * 8) = st;
}

// ---------------- csr_agg1: wave per dst, H=1, bf16 gather ------------------
__global__ void csr_agg1(const int* __restrict__ ei, const int* __restrict__ off,
                         const int* __restrict__ eid, const float* __restrict__ a_s,
                         const float* __restrict__ a_d, const ushort_t* __restrict__ hb,
                         const float* __restrict__ bias, ushort_t* __restrict__ outb) {
    long wid = (blockIdx.x * (long)blockDim.x + threadIdx.x) >> 6;
    int lane = threadIdx.x & 63;
    if (wid >= N_NODES) return;
    int dst = (int)wid;
    int b = off[dst], e2 = off[dst + 1];
    float ad = a_d[dst];

    float m = -1e30f, ssum = 0.f;
    for (int c = b; c < e2; c += 64) {
        int i = c + lane;
        bool act = i < e2;
        int src = act ? edge_src(ei, eid[i]) : 0;
        float v = act ? (a_s[src] + ad) : -1e30f;
        float x = v > 0.f ? v : NEG_SLOPE * v;
        float cm = x;
        #pragma unroll
        for (int d2 = 32; d2 >= 1; d2 >>= 1) cm = fmaxf(cm, __shfl_xor(cm, d2));
        float nm = fmaxf(m, cm);
        float ce = act ? __expf(x - nm) : 0.f;
        #pragma unroll
        for (int d2 = 32; d2 >= 1; d2 >>= 1) ce += __shfl_xor(ce, d2);
        ssum = ssum * __expf(m - nm) + ce;
        m = nm;
    }
    float inv = 1.f / (ssum + 1e-16f);

    float acc = 0.f;
    for (int c = b; c < e2; c += 64) {
        int i = c + lane;
        bool act = i < e2;
        int src = act ? edge_src(ei, eid[i]) : 0;
        float alpha = 0.f;
        if (act) {
            float v = a_s[src] + ad;
            v = v > 0.f ? v : NEG_SLOPE * v;
            alpha = __expf(v - m) * inv;
        }
        int cnt = min(64, e2 - c);
        for (int j = 0; j < cnt; ++j) {
            int sj = __shfl(src, j);
            float aj = __shfl(alpha, j);
            float f = __uint_as_float(((unsigned)hb[(long)sj * 64 + lane]) << 16);
            acc += aj * f;
        }
    }
    float v = acc + bias[lane];
    v = v > 0.f ? v : (__expf(v) - 1.f);
    outb[(long)dst * 64 + lane] = f32_to_bf16(v);
}

// ---------------------------------------------------------------------------
extern "C" void kernel_launch(void* const* d_in, const int* in_sizes, int n_in,
                              void* d_out, int out_size, void* d_ws, size_t ws_size,
                              hipStream_t stream) {
    const float* x        = (const float*)d_in[0];
    const int*   ei       = (const int*)d_in[1];
    const float* W1       = (const float*)d_in[2];
    const float* att_src1 = (const float*)d_in[3];
    const float* att_dst1 = (const float*)d_in[4];
    const float* b1       = (const float*)d_in[5];
    const float* W2       = (const float*)d_in[6];
    const float* att_src2 = (const float*)d_in[7];
    const float* att_dst2 = (const float*)d_in[8];
    const float* b2       = (const float*)d_in[9];
    const float* Wl       = (const float*)d_in[10];
    const float* bl       = (const float*)d_in[11];
    float* out = (float*)d_out;

    // workspace layout (bf16 buffers first, all 16B-aligned)
    char* p = (char*)d_ws;
    ushort_t* h1b   = (ushort_t*)p; p += (long)MP * 512 * 2;   // 51.25 MB
    ushort_t* out1b = (ushort_t*)p; p += (long)MP * 512 * 2;   // 51.25 MB
    ushort_t* xb    = (ushort_t*)p; p += (long)MP * 512 * 2;   // 51.25 MB
    ushort_t* h2b   = (ushort_t*)p; p += (long)MP * 64 * 2;    // 6.4 MB
    ushort_t* out2b = (ushort_t*)p; p += (long)MP * 64 * 2;    // 6.4 MB
    float* as1 = (float*)p; p += (long)N_NODES * 8 * 4;        // 1.6 MB
    float* ad1 = (float*)p; p += (long)N_NODES * 8 * 4;        // 1.6 MB
    ushort_t* w1t = (ushort_t*)p; p += 512 * 512 * 2;
    ushort_t* w2t = (ushort_t*)p; p += 64 * 512 * 2;
    ushort_t* wlt = (ushort_t*)p; p += 512 * 64 * 2;
    int* csr_off = (int*)p; p += (N_NODES + 4) * 4;
    int* csr_cnt = (int*)p; p += N_NODES * 4;
    int* csr_eid = (int*)p; p += (long)E_TOT * 4;

    const int BT = 256;
    dim3 blk(BT);

    // ---------------- CSR build ----------------
    fill_i32<<<256, blk, 0, stream>>>(csr_cnt, 0, N_NODES);
    count_deg<<<1024, blk, 0, stream>>>(ei, csr_cnt);
    scan_deg<<<1, 1024, 0, stream>>>(csr_cnt, csr_off, N_NODES);
    fill_i32<<<256, blk, 0, stream>>>(csr_cnt, 0, N_NODES);
    scatter_edges<<<1024, blk, 0, stream>>>(ei, csr_off, csr_cnt, csr_eid);

    // ---------------- conversions + pad-row zero fills ----------------
    cvt_x_bf16<<<2048, blk, 0, stream>>>(x, xb);
    cvt_w1t_bf16<<<512, blk, 0, stream>>>(W1, w1t);
    cvt_w2t_bf16<<<64, blk, 0, stream>>>(W2, w2t);
    cvt_wlt_bf16<<<64, blk, 0, stream>>>(Wl, wlt);
    fill_i32<<<12, blk, 0, stream>>>((int*)(out1b + (long)N_NODES * 512), 0,
                                     (MP - N_NODES) * 512 / 2);
    fill_i32<<<2, blk, 0, stream>>>((int*)(out2b + (long)N_NODES * 64), 0,
                                    (MP - N_NODES) * 64 / 2);

    // ---------------- layer 1 ----------------
    {
        dim3 grid(512 / 128, MP / 128);
        gemm1_mfma<<<grid, blk, 0, stream>>>(xb, w1t, h1b);
    }
    attn_dots8<<<(N_NODES * 64 + BT - 1) / BT, blk, 0, stream>>>(h1b, att_src1, att_dst1,
                                                                 as1, ad1);
    csr_agg8<<<(N_NODES * 64 + BT - 1) / BT, blk, 0, stream>>>(
        ei, csr_off, csr_eid, as1, ad1, h1b, b1, out1b);

    // ---------------- layer 2 (H=1) ----------------
    gemm2_mfma<<<MP / 128, blk, 0, stream>>>(out1b, w2t, h2b);
    attn_dots1<<<(N_NODES * 64 + BT - 1) / BT, blk, 0, stream>>>(h2b, att_src2, att_dst2,
                                                                 as1, ad1);
    csr_agg1<<<(N_NODES * 64 + BT - 1) / BT, blk, 0, stream>>>(
        ei, csr_off, csr_eid, as1, ad1, h2b, b2, out2b);

    // ---------------- final linear ----------------
    {
        dim3 grid(512 / 128, MP / 128);
        gemm3_mfma<<<grid, blk, 0, stream>>>(out2b, wlt, bl, out);
    }
}

// Round 6
// 485.580 us; speedup vs baseline: 4.8020x; 1.0202x over previous
//
#include <hip/hip_runtime.h>
#include <hip/hip_bf16.h>

// ---------------------------------------------------------------------------
// GAT 2-layer forward (PyG GATConv semantics, eval mode).
// R6: gemm1 -> m97-style global_load_lds MFMA GEMM (linear LDS, 2-barrier
//     K-loop); csr_agg8 -> conflict-free alpha LDS (stride 9) + one-pass
//     fast path for deg<=64. Rest unchanged from R5.
// ---------------------------------------------------------------------------

#define N_NODES 50000
#define F_IN    500
#define H1      8
#define E_RAW   600000
#define E_TOT   (E_RAW + N_NODES)
#define NEG_SLOPE 0.2f

#define MP      50048      // N_NODES padded to multiple of 128
#define KP      512        // F_IN padded

typedef __attribute__((ext_vector_type(8))) short bf16x8;
typedef __attribute__((ext_vector_type(4))) float f32x4;
typedef unsigned short ushort_t;

__device__ __forceinline__ int edge_src(const int* ei, int e) {
    return (e < E_RAW) ? ei[e] : e - E_RAW;
}
__device__ __forceinline__ int edge_dst(const int* ei, int e) {
    return (e < E_RAW) ? ei[E_RAW + e] : e - E_RAW;
}

__device__ __forceinline__ unsigned short f32_to_bf16(float f) {
    unsigned int u = __float_as_uint(f);
    u += 0x7fffu + ((u >> 16) & 1u);       // RNE
    return (unsigned short)(u >> 16);
}
__device__ __forceinline__ float bf16_lo(unsigned int u) {
    return __uint_as_float(u << 16);
}
__device__ __forceinline__ float bf16_hi(unsigned int u) {
    return __uint_as_float(u & 0xffff0000u);
}

// ---------------- fills ----------------
__global__ void fill_i32(int* __restrict__ p, int v, long n) {
    long i = blockIdx.x * (long)blockDim.x + threadIdx.x;
    long stride = (long)gridDim.x * blockDim.x;
    for (; i < n; i += stride) p[i] = v;
}

// ---------------- CSR build ----------------
__global__ void count_deg(const int* __restrict__ ei, int* __restrict__ deg) {
    long i = blockIdx.x * (long)blockDim.x + threadIdx.x;
    long stride = (long)gridDim.x * blockDim.x;
    for (; i < E_TOT; i += stride) atomicAdd(&deg[edge_dst(ei, (int)i)], 1);
}

__global__ void scan_deg(const int* __restrict__ deg, int* __restrict__ off, int n) {
    __shared__ int part[1024];
    int t = threadIdx.x;
    int chunk = (n + 1023) >> 10;
    int b = t * chunk, e = min(b + chunk, n);
    int s = 0;
    for (int i = b; i < e; ++i) s += deg[i];
    part[t] = s;
    __syncthreads();
    for (int d = 1; d < 1024; d <<= 1) {
        int v = (t >= d) ? part[t - d] : 0;
        __syncthreads();
        part[t] += v;
        __syncthreads();
    }
    int excl = (t == 0) ? 0 : part[t - 1];
    for (int i = b; i < e; ++i) { int dv = deg[i]; off[i] = excl; excl += dv; }
    if (t == 1023) off[n] = part[1023];
}

__global__ void scatter_edges(const int* __restrict__ ei, const int* __restrict__ off,
                              int* __restrict__ cnt, int* __restrict__ eid) {
    long i = blockIdx.x * (long)blockDim.x + threadIdx.x;
    long stride = (long)gridDim.x * blockDim.x;
    for (; i < E_TOT; i += stride) {
        int d = edge_dst(ei, (int)i);
        int p = atomicAdd(&cnt[d], 1);
        eid[off[d] + p] = (int)i;
    }
}

// ---------------- bf16 conversion kernels ----------------
__global__ void cvt_x_bf16(const float* __restrict__ x, ushort_t* __restrict__ xb) {
    long idx = blockIdx.x * (long)blockDim.x + threadIdx.x;
    long total = (long)MP * (KP / 2);
    long stride = (long)gridDim.x * blockDim.x;
    for (; idx < total; idx += stride) {
        int r = (int)(idx >> 8);
        int c0 = ((int)idx & 255) * 2;
        float v0 = (r < N_NODES && c0 < F_IN) ? x[(long)r * F_IN + c0] : 0.f;
        float v1 = (r < N_NODES && c0 + 1 < F_IN) ? x[(long)r * F_IN + c0 + 1] : 0.f;
        ((unsigned int*)xb)[idx] = (unsigned int)f32_to_bf16(v0) |
                                   ((unsigned int)f32_to_bf16(v1) << 16);
    }
}

__global__ void cvt_w1t_bf16(const float* __restrict__ W1, ushort_t* __restrict__ w1t) {
    int idx = blockIdx.x * blockDim.x + threadIdx.x;
    if (idx >= 512 * (KP / 2)) return;
    int n = idx >> 8, k0 = (idx & 255) * 2;
    float v0 = (k0 < F_IN) ? W1[(long)k0 * 512 + n] : 0.f;
    float v1 = (k0 + 1 < F_IN) ? W1[(long)(k0 + 1) * 512 + n] : 0.f;
    ((unsigned int*)w1t)[idx] = (unsigned int)f32_to_bf16(v0) |
                                ((unsigned int)f32_to_bf16(v1) << 16);
}

__global__ void cvt_w2t_bf16(const float* __restrict__ W2, ushort_t* __restrict__ w2t) {
    int idx = blockIdx.x * blockDim.x + threadIdx.x;
    if (idx >= 64 * 256) return;
    int n = idx >> 8, k0 = (idx & 255) * 2;
    float v0 = W2[(long)k0 * 64 + n];
    float v1 = W2[(long)(k0 + 1) * 64 + n];
    ((unsigned int*)w2t)[idx] = (unsigned int)f32_to_bf16(v0) |
                                ((unsigned int)f32_to_bf16(v1) << 16);
}

__global__ void cvt_wlt_bf16(const float* __restrict__ Wl, ushort_t* __restrict__ wlt) {
    int idx = blockIdx.x * blockDim.x + threadIdx.x;
    if (idx >= 512 * 32) return;
    int n = idx >> 5, k0 = (idx & 31) * 2;
    float v0 = (n < F_IN) ? Wl[(long)k0 * F_IN + n] : 0.f;
    float v1 = (n < F_IN) ? Wl[(long)(k0 + 1) * F_IN + n] : 0.f;
    ((unsigned int*)wlt)[idx] = (unsigned int)f32_to_bf16(v0) |
                                ((unsigned int)f32_to_bf16(v1) << 16);
}

// ---------------- GEMM1: h1b[MP][512] = xb[MP][KP] @ w1t[512][KP]^T --------
// m97-structure: 128x128 tile, BK=64, linear LDS, global_load_lds width=16.
__global__ __launch_bounds__(256) void gemm1_mfma(
        const ushort_t* __restrict__ A, const ushort_t* __restrict__ Bt,
        ushort_t* __restrict__ C) {
    __shared__ ushort_t As[128 * 64];
    __shared__ ushort_t Bs[128 * 64];
    int tid = threadIdx.x;
    int lane = tid & 63, wid = tid >> 6;
    int wrow = wid >> 1, wcol = wid & 1;
    int brow = blockIdx.y, bcol = blockIdx.x;
    int lrow = lane & 15, lkb = lane >> 4;

    f32x4 acc[4][4];
    const f32x4 zero = {0.f, 0.f, 0.f, 0.f};
    #pragma unroll
    for (int mi = 0; mi < 4; ++mi)
        #pragma unroll
        for (int ni = 0; ni < 4; ++ni) acc[mi][ni] = zero;

    // staging: each wave covers rows [wid*32, wid*32+32); call t covers 8 rows.
    // lane -> row +(lane>>3), col elems (lane&7)*8  (16B per lane, linear LDS)
    const ushort_t* aG = A + ((long)(brow * 128 + wid * 32 + (lane >> 3))) * KP + (lane & 7) * 8;
    const ushort_t* bG = Bt + ((long)(bcol * 128 + wid * 32 + (lane >> 3))) * KP + (lane & 7) * 8;
    ushort_t* aL = As + wid * 32 * 64;
    ushort_t* bL = Bs + wid * 32 * 64;

    for (int k0 = 0; k0 < KP; k0 += 64) {
        #pragma unroll
        for (int t = 0; t < 4; ++t)
            __builtin_amdgcn_global_load_lds(
                (const __attribute__((address_space(1))) void*)(aG + (long)t * 8 * KP + k0),
                (__attribute__((address_space(3))) void*)(aL + t * 8 * 64), 16, 0, 0);
        #pragma unroll
        for (int t = 0; t < 4; ++t)
            __builtin_amdgcn_global_load_lds(
                (const __attribute__((address_space(1))) void*)(bG + (long)t * 8 * KP + k0),
                (__attribute__((address_space(3))) void*)(bL + t * 8 * 64), 16, 0, 0);
        __syncthreads();
        #pragma unroll
        for (int ks = 0; ks < 2; ++ks) {
            bf16x8 af[4], bfr[4];
            #pragma unroll
            for (int mi = 0; mi < 4; ++mi)
                af[mi] = *(const bf16x8*)(As + (wrow * 64 + mi * 16 + lrow) * 64 +
                                          ks * 32 + lkb * 8);
            #pragma unroll
            for (int ni = 0; ni < 4; ++ni)
                bfr[ni] = *(const bf16x8*)(Bs + (wcol * 64 + ni * 16 + lrow) * 64 +
                                           ks * 32 + lkb * 8);
            #pragma unroll
            for (int mi = 0; mi < 4; ++mi)
                #pragma unroll
                for (int ni = 0; ni < 4; ++ni)
                    acc[mi][ni] = __builtin_amdgcn_mfma_f32_16x16x32_bf16(
                        af[mi], bfr[ni], acc[mi][ni], 0, 0, 0);
        }
        __syncthreads();
    }

    #pragma unroll
    for (int mi = 0; mi < 4; ++mi)
        #pragma unroll
        for (int reg = 0; reg < 4; ++reg) {
            int r = brow * 128 + wrow * 64 + mi * 16 + lkb * 4 + reg;
            #pragma unroll
            for (int ni = 0; ni < 4; ++ni) {
                int c = bcol * 128 + wcol * 64 + ni * 16 + lrow;
                C[(long)r * 512 + c] = f32_to_bf16(acc[mi][ni][reg]);
            }
        }
}

// ---------------- GEMM2: h2b[MP][64] = out1b[MP][512] @ w2t[64][512]^T -----
#define LDP 72

__global__ __launch_bounds__(256) void gemm2_mfma(
        const ushort_t* __restrict__ A, const ushort_t* __restrict__ Bt,
        ushort_t* __restrict__ C) {
    __shared__ ushort_t As[128 * LDP];
    __shared__ ushort_t Bs[64 * LDP];
    int tid = threadIdx.x;
    int lane = tid & 63, wid = tid >> 6;
    int wrow = wid >> 1, wcol = wid & 1;
    int brow = blockIdx.x;

    f32x4 acc[4][2];
    const f32x4 zero = {0.f, 0.f, 0.f, 0.f};
    #pragma unroll
    for (int mi = 0; mi < 4; ++mi) { acc[mi][0] = zero; acc[mi][1] = zero; }

    int lrow = lane & 15, lkb = lane >> 4;

    for (int k0 = 0; k0 < 512; k0 += 64) {
        #pragma unroll
        for (int it = 0; it < 4; ++it) {
            int slot = tid + it * 256;
            int row = slot >> 3, seg = slot & 7;
            *(int4*)(As + row * LDP + seg * 8) =
                *(const int4*)(A + ((long)(brow * 128 + row)) * 512 + k0 + seg * 8);
        }
        #pragma unroll
        for (int it = 0; it < 2; ++it) {
            int slot = tid + it * 256;
            int row = slot >> 3, seg = slot & 7;
            *(int4*)(Bs + row * LDP + seg * 8) =
                *(const int4*)(Bt + (long)row * 512 + k0 + seg * 8);
        }
        __syncthreads();
        #pragma unroll
        for (int ks = 0; ks < 2; ++ks) {
            bf16x8 af[4], bfr[2];
            #pragma unroll
            for (int mi = 0; mi < 4; ++mi)
                af[mi] = *(const bf16x8*)(As + (wrow * 64 + mi * 16 + lrow) * LDP +
                                          ks * 32 + lkb * 8);
            #pragma unroll
            for (int ni = 0; ni < 2; ++ni)
                bfr[ni] = *(const bf16x8*)(Bs + (wcol * 32 + ni * 16 + lrow) * LDP +
                                           ks * 32 + lkb * 8);
            #pragma unroll
            for (int mi = 0; mi < 4; ++mi)
                #pragma unroll
                for (int ni = 0; ni < 2; ++ni)
                    acc[mi][ni] = __builtin_amdgcn_mfma_f32_16x16x32_bf16(
                        af[mi], bfr[ni], acc[mi][ni], 0, 0, 0);
        }
        __syncthreads();
    }

    #pragma unroll
    for (int mi = 0; mi < 4; ++mi)
        #pragma unroll
        for (int reg = 0; reg < 4; ++reg) {
            int r = brow * 128 + wrow * 64 + mi * 16 + lkb * 4 + reg;
            #pragma unroll
            for (int ni = 0; ni < 2; ++ni) {
                int c = wcol * 32 + ni * 16 + lrow;
                C[(long)r * 64 + c] = f32_to_bf16(acc[mi][ni][reg]);
            }
        }
}

// ---------------- GEMM3: out[N][500] = out2b[MP][64] @ wlt[512][64]^T + bl --
__global__ __launch_bounds__(256) void gemm3_mfma(
        const ushort_t* __restrict__ A, const ushort_t* __restrict__ Bt,
        const float* __restrict__ bias, float* __restrict__ C) {
    __shared__ ushort_t As[128 * LDP];
    __shared__ ushort_t Bs[128 * LDP];
    int tid = threadIdx.x;
    int lane = tid & 63, wid = tid >> 6;
    int wrow = wid >> 1, wcol = wid & 1;
    int brow = blockIdx.y, bcol = blockIdx.x;

    f32x4 acc[4][4];
    const f32x4 zero = {0.f, 0.f, 0.f, 0.f};
    #pragma unroll
    for (int mi = 0; mi < 4; ++mi)
        #pragma unroll
        for (int ni = 0; ni < 4; ++ni) acc[mi][ni] = zero;

    int lrow = lane & 15, lkb = lane >> 4;

    #pragma unroll
    for (int it = 0; it < 4; ++it) {
        int slot = tid + it * 256;
        int row = slot >> 3, seg = slot & 7;
        *(int4*)(As + row * LDP + seg * 8) =
            *(const int4*)(A + ((long)(brow * 128 + row)) * 64 + seg * 8);
        *(int4*)(Bs + row * LDP + seg * 8) =
            *(const int4*)(Bt + ((long)(bcol * 128 + row)) * 64 + seg * 8);
    }
    __syncthreads();
    #pragma unroll
    for (int ks = 0; ks < 2; ++ks) {
        bf16x8 af[4], bfr[4];
        #pragma unroll
        for (int mi = 0; mi < 4; ++mi)
            af[mi] = *(const bf16x8*)(As + (wrow * 64 + mi * 16 + lrow) * LDP +
                                      ks * 32 + lkb * 8);
        #pragma unroll
        for (int ni = 0; ni < 4; ++ni)
            bfr[ni] = *(const bf16x8*)(Bs + (wcol * 64 + ni * 16 + lrow) * LDP +
                                       ks * 32 + lkb * 8);
        #pragma unroll
        for (int mi = 0; mi < 4; ++mi)
            #pragma unroll
            for (int ni = 0; ni < 4; ++ni)
                acc[mi][ni] = __builtin_amdgcn_mfma_f32_16x16x32_bf16(
                    af[mi], bfr[ni], acc[mi][ni], 0, 0, 0);
    }

    #pragma unroll
    for (int mi = 0; mi < 4; ++mi)
        #pragma unroll
        for (int reg = 0; reg < 4; ++reg) {
            int r = brow * 128 + wrow * 64 + mi * 16 + lkb * 4 + reg;
            if (r >= N_NODES) continue;
            #pragma unroll
            for (int ni = 0; ni < 4; ++ni) {
                int c = bcol * 128 + wcol * 64 + ni * 16 + lrow;
                if (c < F_IN) C[(long)r * F_IN + c] = acc[mi][ni][reg] + bias[c];
            }
        }
}

// ---------------- attention dots L1: wave per node, bf16 h ----------------
__global__ void attn_dots8(const ushort_t* __restrict__ hb, const float* __restrict__ att_s,
                           const float* __restrict__ att_d, float* __restrict__ a_s,
                           float* __restrict__ a_d) {
    long wid = (blockIdx.x * (long)blockDim.x + threadIdx.x) >> 6;
    int lane = threadIdx.x & 63;
    if (wid >= N_NODES) return;
    int n = (int)wid;
    int4 hv = *(const int4*)(hb + (long)n * 512 + lane * 8);
    const float* asp = att_s + lane * 8;
    const float* adp = att_d + lane * 8;
    float s = 0.f, d = 0.f;
    #pragma unroll
    for (int q = 0; q < 4; ++q) {
        unsigned u = ((const unsigned*)&hv)[q];
        float f0 = bf16_lo(u), f1 = bf16_hi(u);
        s += f0 * asp[2 * q] + f1 * asp[2 * q + 1];
        d += f0 * adp[2 * q] + f1 * adp[2 * q + 1];
    }
    #pragma unroll
    for (int m = 4; m >= 1; m >>= 1) { s += __shfl_xor(s, m); d += __shfl_xor(d, m); }
    if ((lane & 7) == 0) {
        a_s[(long)n * 8 + (lane >> 3)] = s;
        a_d[(long)n * 8 + (lane >> 3)] = d;
    }
}

// ---------------- attention dots L2 (H=1): wave per node ----------------
__global__ void attn_dots1(const ushort_t* __restrict__ hb, const float* __restrict__ att_s,
                           const float* __restrict__ att_d, float* __restrict__ a_s,
                           float* __restrict__ a_d) {
    long wid = (blockIdx.x * (long)blockDim.x + threadIdx.x) >> 6;
    int lane = threadIdx.x & 63;
    if (wid >= N_NODES) return;
    int n = (int)wid;
    float f = __uint_as_float(((unsigned)hb[(long)n * 64 + lane]) << 16);
    float s = f * att_s[lane], d = f * att_d[lane];
    #pragma unroll
    for (int m = 32; m >= 1; m >>= 1) { s += __shfl_xor(s, m); d += __shfl_xor(d, m); }
    if (lane == 0) { a_s[n] = s; a_d[n] = d; }
}

// ---------------- csr_agg8: wave per dst, 8 heads, bf16 gather --------------
// lane = (head = lane>>3, ch-block = lane&7); per-edge gather = 1 int4.
// alpha LDS stride 9 -> conflict-free writes and reads.
__global__ void csr_agg8(const int* __restrict__ ei, const int* __restrict__ off,
                         const int* __restrict__ eid, const float* __restrict__ a_s,
                         const float* __restrict__ a_d, const ushort_t* __restrict__ hb,
                         const float* __restrict__ bias, ushort_t* __restrict__ outb) {
    __shared__ float alds[4 * 64 * 9];       // per-wave [64 edges][9]
    long wid = (blockIdx.x * (long)blockDim.x + threadIdx.x) >> 6;
    int lane = threadIdx.x & 63;
    if (wid >= N_NODES) return;
    int dst = (int)wid;
    float* aw = alds + (threadIdx.x >> 6) * (64 * 9);
    int b = off[dst], e2 = off[dst + 1];
    int deg = e2 - b;
    int myh = lane >> 3;

    float ad[8];
    {
        const float* adp = a_d + (long)dst * 8;
        #pragma unroll
        for (int hh = 0; hh < 8; ++hh) ad[hh] = adp[hh];
    }

    float acc8[8];
    #pragma unroll
    for (int q = 0; q < 8; ++q) acc8[q] = 0.f;

    if (deg <= 64) {
        // ---- one-pass fast path: scores live in registers ----
        bool act = lane < deg;
        int src = act ? edge_src(ei, eid[b + lane]) : 0;
        const float* asp = a_s + (long)src * 8;
        float x[8];
        #pragma unroll
        for (int hh = 0; hh < 8; ++hh) {
            float v = act ? (asp[hh] + ad[hh]) : -1e30f;
            x[hh] = v > 0.f ? v : NEG_SLOPE * v;
        }
        #pragma unroll
        for (int hh = 0; hh < 8; ++hh) {
            float cm = x[hh];
            #pragma unroll
            for (int d2 = 32; d2 >= 1; d2 >>= 1) cm = fmaxf(cm, __shfl_xor(cm, d2));
            float ce = act ? __expf(x[hh] - cm) : 0.f;
            float ss = ce;
            #pragma unroll
            for (int d2 = 32; d2 >= 1; d2 >>= 1) ss += __shfl_xor(ss, d2);
            aw[lane * 9 + hh] = ce * (1.f / (ss + 1e-16f));
        }
        asm volatile("s_waitcnt lgkmcnt(0)" ::: "memory");
        for (int j = 0; j < deg; ++j) {
            int sj = __shfl(src, j);
            float aj = aw[j * 9 + myh];
            int4 hv = *(const int4*)(hb + (long)sj * 512 + lane * 8);
            #pragma unroll
            for (int q = 0; q < 4; ++q) {
                unsigned u = ((const unsigned*)&hv)[q];
                acc8[2 * q]     += aj * bf16_lo(u);
                acc8[2 * q + 1] += aj * bf16_hi(u);
            }
        }
    } else {
        // ---- general chunked two-pass path ----
        float m[8], ssum[8];
        #pragma unroll
        for (int hh = 0; hh < 8; ++hh) { m[hh] = -1e30f; ssum[hh] = 0.f; }

        for (int c = b; c < e2; c += 64) {
            int i = c + lane;
            bool act = i < e2;
            int src = act ? edge_src(ei, eid[i]) : 0;
            float x[8];
            {
                const float* asp = a_s + (long)src * 8;
                #pragma unroll
                for (int hh = 0; hh < 8; ++hh) {
                    float v = act ? (asp[hh] + ad[hh]) : -1e30f;
                    x[hh] = v > 0.f ? v : NEG_SLOPE * v;
                }
            }
            #pragma unroll
            for (int hh = 0; hh < 8; ++hh) {
                float cm = x[hh];
                #pragma unroll
                for (int d2 = 32; d2 >= 1; d2 >>= 1) cm = fmaxf(cm, __shfl_xor(cm, d2));
                float nm = fmaxf(m[hh], cm);
                float ce = act ? __expf(x[hh] - nm) : 0.f;
                #pragma unroll
                for (int d2 = 32; d2 >= 1; d2 >>= 1) ce += __shfl_xor(ce, d2);
                ssum[hh] = ssum[hh] * __expf(m[hh] - nm) + ce;
                m[hh] = nm;
            }
        }
        float inv[8];
        #pragma unroll
        for (int hh = 0; hh < 8; ++hh) inv[hh] = 1.f / (ssum[hh] + 1e-16f);

        for (int c = b; c < e2; c += 64) {
            int i = c + lane;
            bool act = i < e2;
            int src = act ? edge_src(ei, eid[i]) : 0;
            {
                const float* asp = a_s + (long)src * 8;
                #pragma unroll
                for (int hh = 0; hh < 8; ++hh) {
                    float v = act ? (asp[hh] + ad[hh]) : -1e30f;
                    v = v > 0.f ? v : NEG_SLOPE * v;
                    aw[lane * 9 + hh] = act ? __expf(v - m[hh]) * inv[hh] : 0.f;
                }
            }
            asm volatile("s_waitcnt lgkmcnt(0)" ::: "memory");
            int cnt = min(64, e2 - c);
            for (int j = 0; j < cnt; ++j) {
                int sj = __shfl(src, j);
                float aj = aw[j * 9 + myh];
                int4 hv = *(const int4*)(hb + (long)sj * 512 + lane * 8);
                #pragma unroll
                for (int q = 0; q < 4; ++q) {
                    unsigned u = ((const unsigned*)&hv)[q];
                    acc8[2 * q]     += aj * bf16_lo(u);
                    acc8[2 * q + 1] += aj * bf16_hi(u);
                }
            }
            asm volatile("s_waitcnt lgkmcnt(0)" ::: "memory");
        }
    }

    // epilogue: bias + ELU, pack bf16, one int4 store
    const float* bp = bias + lane * 8;
    int4 st;
    #pragma unroll
    for (int q = 0; q < 8; ++q) {
        float v = acc8[q] + bp[q];
        v = v > 0.f ? v : (__expf(v) - 1.f);
        ((ushort_t*)&st)[q] = f32_to_bf16(v);
    }
    *(int4*)(outb + (long)dst * 512 + lane * 8) = st;
}

// ---------------- csr_agg1: wave per dst, H=1, bf16 gather ------------------
__global__ void csr_agg1(const int* __restrict__ ei, const int* __restrict__ off,
                         const int* __restrict__ eid, const float* __restrict__ a_s,
                         const float* __restrict__ a_d, const ushort_t* __restrict__ hb,
                         const float* __restrict__ bias, ushort_t* __restrict__ outb) {
    long wid = (blockIdx.x * (long)blockDim.x + threadIdx.x) >> 6;
    int lane = threadIdx.x & 63;
    if (wid >= N_NODES) return;
    int dst = (int)wid;
    int b = off[dst], e2 = off[dst + 1];
    float ad = a_d[dst];

    float m = -1e30f, ssum = 0.f;
    for (int c = b; c < e2; c += 64) {
        int i = c + lane;
        bool act = i < e2;
        int src = act ? edge_src(ei, eid[i]) : 0;
        float v = act ? (a_s[src] + ad) : -1e30f;
        float x = v > 0.f ? v : NEG_SLOPE * v;
        float cm = x;
        #pragma unroll
        for (int d2 = 32; d2 >= 1; d2 >>= 1) cm = fmaxf(cm, __shfl_xor(cm, d2));
        float nm = fmaxf(m, cm);
        float ce = act ? __expf(x - nm) : 0.f;
        #pragma unroll
        for (int d2 = 32; d2 >= 1; d2 >>= 1) ce += __shfl_xor(ce, d2);
        ssum = ssum * __expf(m - nm) + ce;
        m = nm;
    }
    float inv = 1.f / (ssum + 1e-16f);

    float acc = 0.f;
    for (int c = b; c < e2; c += 64) {
        int i = c + lane;
        bool act = i < e2;
        int src = act ? edge_src(ei, eid[i]) : 0;
        float alpha = 0.f;
        if (act) {
            float v = a_s[src] + ad;
            v = v > 0.f ? v : NEG_SLOPE * v;
            alpha = __expf(v - m) * inv;
        }
        int cnt = min(64, e2 - c);
        for (int j = 0; j < cnt; ++j) {
            int sj = __shfl(src, j);
            float aj = __shfl(alpha, j);
            float f = __uint_as_float(((unsigned)hb[(long)sj * 64 + lane]) << 16);
            acc += aj * f;
        }
    }
    float v = acc + bias[lane];
    v = v > 0.f ? v : (__expf(v) - 1.f);
    outb[(long)dst * 64 + lane] = f32_to_bf16(v);
}

// ---------------------------------------------------------------------------
extern "C" void kernel_launch(void* const* d_in, const int* in_sizes, int n_in,
                              void* d_out, int out_size, void* d_ws, size_t ws_size,
                              hipStream_t stream) {
    const float* x        = (const float*)d_in[0];
    const int*   ei       = (const int*)d_in[1];
    const float* W1       = (const float*)d_in[2];
    const float* att_src1 = (const float*)d_in[3];
    const float* att_dst1 = (const float*)d_in[4];
    const float* b1       = (const float*)d_in[5];
    const float* W2       = (const float*)d_in[6];
    const float* att_src2 = (const float*)d_in[7];
    const float* att_dst2 = (const float*)d_in[8];
    const float* b2       = (const float*)d_in[9];
    const float* Wl       = (const float*)d_in[10];
    const float* bl       = (const float*)d_in[11];
    float* out = (float*)d_out;

    // workspace layout
    char* p = (char*)d_ws;
    ushort_t* h1b   = (ushort_t*)p; p += (long)MP * 512 * 2;
    ushort_t* out1b = (ushort_t*)p; p += (long)MP * 512 * 2;
    ushort_t* xb    = (ushort_t*)p; p += (long)MP * 512 * 2;
    ushort_t* h2b   = (ushort_t*)p; p += (long)MP * 64 * 2;
    ushort_t* out2b = (ushort_t*)p; p += (long)MP * 64 * 2;
    float* as1 = (float*)p; p += (long)N_NODES * 8 * 4;
    float* ad1 = (float*)p; p += (long)N_NODES * 8 * 4;
    ushort_t* w1t = (ushort_t*)p; p += 512 * 512 * 2;
    ushort_t* w2t = (ushort_t*)p; p += 64 * 512 * 2;
    ushort_t* wlt = (ushort_t*)p; p += 512 * 64 * 2;
    int* csr_off = (int*)p; p += (N_NODES + 4) * 4;
    int* csr_cnt = (int*)p; p += N_NODES * 4;
    int* csr_eid = (int*)p; p += (long)E_TOT * 4;

    const int BT = 256;
    dim3 blk(BT);

    // ---------------- CSR build ----------------
    fill_i32<<<256, blk, 0, stream>>>(csr_cnt, 0, N_NODES);
    count_deg<<<1024, blk, 0, stream>>>(ei, csr_cnt);
    scan_deg<<<1, 1024, 0, stream>>>(csr_cnt, csr_off, N_NODES);
    fill_i32<<<256, blk, 0, stream>>>(csr_cnt, 0, N_NODES);
    scatter_edges<<<1024, blk, 0, stream>>>(ei, csr_off, csr_cnt, csr_eid);

    // ---------------- conversions + pad-row zero fills ----------------
    cvt_x_bf16<<<2048, blk, 0, stream>>>(x, xb);
    cvt_w1t_bf16<<<512, blk, 0, stream>>>(W1, w1t);
    cvt_w2t_bf16<<<64, blk, 0, stream>>>(W2, w2t);
    cvt_wlt_bf16<<<64, blk, 0, stream>>>(Wl, wlt);
    fill_i32<<<12, blk, 0, stream>>>((int*)(out1b + (long)N_NODES * 512), 0,
                                     (MP - N_NODES) * 512 / 2);
    fill_i32<<<2, blk, 0, stream>>>((int*)(out2b + (long)N_NODES * 64), 0,
                                    (MP - N_NODES) * 64 / 2);

    // ---------------- layer 1 ----------------
    {
        dim3 grid(512 / 128, MP / 128);
        gemm1_mfma<<<grid, blk, 0, stream>>>(xb, w1t, h1b);
    }
    attn_dots8<<<(N_NODES * 64 + BT - 1) / BT, blk, 0, stream>>>(h1b, att_src1, att_dst1,
                                                                 as1, ad1);
    csr_agg8<<<(N_NODES * 64 + BT - 1) / BT, blk, 0, stream>>>(
        ei, csr_off, csr_eid, as1, ad1, h1b, b1, out1b);

    // ---------------- layer 2 (H=1) ----------------
    gemm2_mfma<<<MP / 128, blk, 0, stream>>>(out1b, w2t, h2b);
    attn_dots1<<<(N_NODES * 64 + BT - 1) / BT, blk, 0, stream>>>(h2b, att_src2, att_dst2,
                                                                 as1, ad1);
    csr_agg1<<<(N_NODES * 64 + BT - 1) / BT, blk, 0, stream>>>(
        ei, csr_off, csr_eid, as1, ad1, h2b, b2, out2b);

    // ---------------- final linear ----------------
    {
        dim3 grid(512 / 128, MP / 128);
        gemm3_mfma<<<grid, blk, 0, stream>>>(out2b, wlt, bl, out);
    }
}

// Round 7
// 476.362 us; speedup vs baseline: 4.8949x; 1.0194x over previous
//
#include <hip/hip_runtime.h>
#include <hip/hip_bf16.h>

// ---------------------------------------------------------------------------
// GAT 2-layer forward (PyG GATConv semantics, eval mode).
// R7: gemm1 -> full-row-width block (128 rows x 512 cols, 8 waves, BK=32):
//     reads f32 x ONCE with in-reg cvt (kills cvt_x), computes a_s/a_d in the
//     epilogue (kills attn_dots8). B via global_load_lds with pre-swizzled
//     source. csr_agg8/csr_agg1/gemm2/gemm3 unchanged from R6.
// ---------------------------------------------------------------------------

#define N_NODES 50000
#define F_IN    500
#define H1      8
#define E_RAW   600000
#define E_TOT   (E_RAW + N_NODES)
#define NEG_SLOPE 0.2f

#define MP      50048      // N_NODES padded to multiple of 128
#define KP      512        // F_IN padded

typedef __attribute__((ext_vector_type(8))) short bf16x8;
typedef __attribute__((ext_vector_type(4))) float f32x4;
typedef unsigned short ushort_t;

__device__ __forceinline__ int edge_src(const int* ei, int e) {
    return (e < E_RAW) ? ei[e] : e - E_RAW;
}
__device__ __forceinline__ int edge_dst(const int* ei, int e) {
    return (e < E_RAW) ? ei[E_RAW + e] : e - E_RAW;
}

__device__ __forceinline__ unsigned short f32_to_bf16(float f) {
    unsigned int u = __float_as_uint(f);
    u += 0x7fffu + ((u >> 16) & 1u);       // RNE
    return (unsigned short)(u >> 16);
}
__device__ __forceinline__ float bf16_lo(unsigned int u) {
    return __uint_as_float(u << 16);
}
__device__ __forceinline__ float bf16_hi(unsigned int u) {
    return __uint_as_float(u & 0xffff0000u);
}

// ---------------- fills ----------------
__global__ void fill_i32(int* __restrict__ p, int v, long n) {
    long i = blockIdx.x * (long)blockDim.x + threadIdx.x;
    long stride = (long)gridDim.x * blockDim.x;
    for (; i < n; i += stride) p[i] = v;
}

// ---------------- CSR build ----------------
__global__ void count_deg(const int* __restrict__ ei, int* __restrict__ deg) {
    long i = blockIdx.x * (long)blockDim.x + threadIdx.x;
    long stride = (long)gridDim.x * blockDim.x;
    for (; i < E_TOT; i += stride) atomicAdd(&deg[edge_dst(ei, (int)i)], 1);
}

__global__ void scan_deg(const int* __restrict__ deg, int* __restrict__ off, int n) {
    __shared__ int part[1024];
    int t = threadIdx.x;
    int chunk = (n + 1023) >> 10;
    int b = t * chunk, e = min(b + chunk, n);
    int s = 0;
    for (int i = b; i < e; ++i) s += deg[i];
    part[t] = s;
    __syncthreads();
    for (int d = 1; d < 1024; d <<= 1) {
        int v = (t >= d) ? part[t - d] : 0;
        __syncthreads();
        part[t] += v;
        __syncthreads();
    }
    int excl = (t == 0) ? 0 : part[t - 1];
    for (int i = b; i < e; ++i) { int dv = deg[i]; off[i] = excl; excl += dv; }
    if (t == 1023) off[n] = part[1023];
}

__global__ void scatter_edges(const int* __restrict__ ei, const int* __restrict__ off,
                              int* __restrict__ cnt, int* __restrict__ eid) {
    long i = blockIdx.x * (long)blockDim.x + threadIdx.x;
    long stride = (long)gridDim.x * blockDim.x;
    for (; i < E_TOT; i += stride) {
        int d = edge_dst(ei, (int)i);
        int p = atomicAdd(&cnt[d], 1);
        eid[off[d] + p] = (int)i;
    }
}

// ---------------- bf16 weight conversion kernels ----------------
__global__ void cvt_w1t_bf16(const float* __restrict__ W1, ushort_t* __restrict__ w1t) {
    int idx = blockIdx.x * blockDim.x + threadIdx.x;
    if (idx >= 512 * (KP / 2)) return;
    int n = idx >> 8, k0 = (idx & 255) * 2;
    float v0 = (k0 < F_IN) ? W1[(long)k0 * 512 + n] : 0.f;
    float v1 = (k0 + 1 < F_IN) ? W1[(long)(k0 + 1) * 512 + n] : 0.f;
    ((unsigned int*)w1t)[idx] = (unsigned int)f32_to_bf16(v0) |
                                ((unsigned int)f32_to_bf16(v1) << 16);
}

__global__ void cvt_w2t_bf16(const float* __restrict__ W2, ushort_t* __restrict__ w2t) {
    int idx = blockIdx.x * blockDim.x + threadIdx.x;
    if (idx >= 64 * 256) return;
    int n = idx >> 8, k0 = (idx & 255) * 2;
    float v0 = W2[(long)k0 * 64 + n];
    float v1 = W2[(long)(k0 + 1) * 64 + n];
    ((unsigned int*)w2t)[idx] = (unsigned int)f32_to_bf16(v0) |
                                ((unsigned int)f32_to_bf16(v1) << 16);
}

__global__ void cvt_wlt_bf16(const float* __restrict__ Wl, ushort_t* __restrict__ wlt) {
    int idx = blockIdx.x * blockDim.x + threadIdx.x;
    if (idx >= 512 * 32) return;
    int n = idx >> 5, k0 = (idx & 31) * 2;
    float v0 = (n < F_IN) ? Wl[(long)k0 * F_IN + n] : 0.f;
    float v1 = (n < F_IN) ? Wl[(long)(k0 + 1) * F_IN + n] : 0.f;
    ((unsigned int*)wlt)[idx] = (unsigned int)f32_to_bf16(v0) |
                                ((unsigned int)f32_to_bf16(v1) << 16);
}

// ---------------- GEMM1 (fused): h1b = bf16(x) @ w1t^T; a_s/a_d epilogue ----
// Block: 128 rows x 512 cols, 8 waves (wrow 0..1, wcol 0..3), BK=32.
// A: f32 x, reg-staged with in-reg cvt; B: global_load_lds, pre-swizzled src.
// LDS swizzle: 16B-slot index ^= (row>>1)&3  (write & read sides match).
__global__ __launch_bounds__(512, 2) void gemm1_big(
        const float* __restrict__ X, const ushort_t* __restrict__ Bt,
        const float* __restrict__ att_s, const float* __restrict__ att_d,
        ushort_t* __restrict__ H, float* __restrict__ a_s, float* __restrict__ a_d) {
    __shared__ ushort_t As[128 * 32];    // 8 KB
    __shared__ ushort_t Bs[512 * 32];    // 32 KB
    int tid = threadIdx.x;
    int lane = tid & 63, wid = tid >> 6;
    int wrow = wid >> 2, wcol = wid & 3;
    int lrow = lane & 15, lkb = lane >> 4;
    int brow = blockIdx.x;

    f32x4 acc[4][8];
    const f32x4 zero = {0.f, 0.f, 0.f, 0.f};
    #pragma unroll
    for (int mi = 0; mi < 4; ++mi)
        #pragma unroll
        for (int ni = 0; ni < 8; ++ni) acc[mi][ni] = zero;

    // A staging mapping: thread -> (row = tid>>2, kseg = tid&3), 8 f32 each
    int arow = tid >> 2;
    int akseg = tid & 3;
    long arow_g = (long)brow * 128 + arow;
    bool arow_ok = arow_g < N_NODES;
    const float* aG = X + arow_g * F_IN;
    ushort_t* aL = As + arow * 32 + ((akseg ^ ((arow >> 1) & 3)) * 8);

    for (int k0 = 0; k0 < KP; k0 += 32) {
        // ---- stage A (reg cvt) ----
        float av[8];
        #pragma unroll
        for (int q = 0; q < 2; ++q) {
            int kk = k0 + akseg * 8 + q * 4;
            float4 v = {0.f, 0.f, 0.f, 0.f};
            if (arow_ok && kk + 4 <= F_IN) v = *(const float4*)(aG + kk);
            av[q * 4 + 0] = v.x; av[q * 4 + 1] = v.y;
            av[q * 4 + 2] = v.z; av[q * 4 + 3] = v.w;
        }
        int4 apk;
        #pragma unroll
        for (int q = 0; q < 4; ++q)
            ((unsigned*)&apk)[q] = (unsigned)f32_to_bf16(av[2 * q]) |
                                   ((unsigned)f32_to_bf16(av[2 * q + 1]) << 16);
        *(int4*)aL = apk;

        // ---- stage B via global_load_lds (pre-swizzled source) ----
        #pragma unroll
        for (int i = 0; i < 4; ++i) {
            int slot = i * 512 + tid;            // 0..2047
            int n = slot >> 2, ks8 = slot & 3;
            const ushort_t* g = Bt + (long)n * 512 + k0 + ((ks8 ^ ((n >> 1) & 3)) * 8);
            __builtin_amdgcn_global_load_lds(
                (const __attribute__((address_space(1))) void*)g,
                (__attribute__((address_space(3))) void*)(Bs + slot * 8), 16, 0, 0);
        }
        __syncthreads();

        // ---- MFMA ----
        bf16x8 af[4], bfr[8];
        #pragma unroll
        for (int mi = 0; mi < 4; ++mi) {
            int row = wrow * 64 + mi * 16 + lrow;
            af[mi] = *(const bf16x8*)(As + row * 32 + ((lkb ^ ((row >> 1) & 3)) * 8));
        }
        #pragma unroll
        for (int ni = 0; ni < 8; ++ni) {
            int n = wcol * 128 + ni * 16 + lrow;
            bfr[ni] = *(const bf16x8*)(Bs + n * 32 + ((lkb ^ ((n >> 1) & 3)) * 8));
        }
        #pragma unroll
        for (int mi = 0; mi < 4; ++mi)
            #pragma unroll
            for (int ni = 0; ni < 8; ++ni)
                acc[mi][ni] = __builtin_amdgcn_mfma_f32_16x16x32_bf16(
                    af[mi], bfr[ni], acc[mi][ni], 0, 0, 0);
        __syncthreads();
    }

    // ---- epilogue: h1b store + fused attention dots ----
    // C/D layout: col = lrow, row = lkb*4 + reg  [m89]
    int hA = wcol * 2, hB = wcol * 2 + 1;
    float asv[2][4], adv[2][4];
    #pragma unroll
    for (int j = 0; j < 4; ++j) {
        asv[0][j] = att_s[hA * 64 + j * 16 + lrow];
        asv[1][j] = att_s[hB * 64 + j * 16 + lrow];
        adv[0][j] = att_d[hA * 64 + j * 16 + lrow];
        adv[1][j] = att_d[hB * 64 + j * 16 + lrow];
    }

    #pragma unroll
    for (int mi = 0; mi < 4; ++mi) {
        #pragma unroll
        for (int reg = 0; reg < 4; ++reg) {
            long r = (long)brow * 128 + wrow * 64 + mi * 16 + lkb * 4 + reg;
            // store h1b row fragment
            #pragma unroll
            for (int ni = 0; ni < 8; ++ni) {
                int c = wcol * 128 + ni * 16 + lrow;
                H[r * 512 + c] = f32_to_bf16(acc[mi][ni][reg]);
            }
            // fused dots: head A = ni 0..3, head B = ni 4..7
            float sA = 0.f, dA = 0.f, sB = 0.f, dB = 0.f;
            #pragma unroll
            for (int j = 0; j < 4; ++j) {
                sA += acc[mi][j][reg] * asv[0][j];
                dA += acc[mi][j][reg] * adv[0][j];
                sB += acc[mi][j + 4][reg] * asv[1][j];
                dB += acc[mi][j + 4][reg] * adv[1][j];
            }
            #pragma unroll
            for (int mm = 8; mm >= 1; mm >>= 1) {
                sA += __shfl_xor(sA, mm);
                dA += __shfl_xor(dA, mm);
                sB += __shfl_xor(sB, mm);
                dB += __shfl_xor(dB, mm);
            }
            if (lrow == 0 && r < N_NODES) {
                a_s[r * 8 + hA] = sA;
                a_d[r * 8 + hA] = dA;
                a_s[r * 8 + hB] = sB;
                a_d[r * 8 + hB] = dB;
            }
        }
    }
}

// ---------------- GEMM2: h2b[MP][64] = out1b[MP][512] @ w2t[64][512]^T -----
#define LDP 72

__global__ __launch_bounds__(256) void gemm2_mfma(
        const ushort_t* __restrict__ A, const ushort_t* __restrict__ Bt,
        ushort_t* __restrict__ C) {
    __shared__ ushort_t As[128 * LDP];
    __shared__ ushort_t Bs[64 * LDP];
    int tid = threadIdx.x;
    int lane = tid & 63, wid = tid >> 6;
    int wrow = wid >> 1, wcol = wid & 1;
    int brow = blockIdx.x;

    f32x4 acc[4][2];
    const f32x4 zero = {0.f, 0.f, 0.f, 0.f};
    #pragma unroll
    for (int mi = 0; mi < 4; ++mi) { acc[mi][0] = zero; acc[mi][1] = zero; }

    int lrow = lane & 15, lkb = lane >> 4;

    for (int k0 = 0; k0 < 512; k0 += 64) {
        #pragma unroll
        for (int it = 0; it < 4; ++it) {
            int slot = tid + it * 256;
            int row = slot >> 3, seg = slot & 7;
            *(int4*)(As + row * LDP + seg * 8) =
                *(const int4*)(A + ((long)(brow * 128 + row)) * 512 + k0 + seg * 8);
        }
        #pragma unroll
        for (int it = 0; it < 2; ++it) {
            int slot = tid + it * 256;
            int row = slot >> 3, seg = slot & 7;
            *(int4*)(Bs + row * LDP + seg * 8) =
                *(const int4*)(Bt + (long)row * 512 + k0 + seg * 8);
        }
        __syncthreads();
        #pragma unroll
        for (int ks = 0; ks < 2; ++ks) {
            bf16x8 af[4], bfr[2];
            #pragma unroll
            for (int mi = 0; mi < 4; ++mi)
                af[mi] = *(const bf16x8*)(As + (wrow * 64 + mi * 16 + lrow) * LDP +
                                          ks * 32 + lkb * 8);
            #pragma unroll
            for (int ni = 0; ni < 2; ++ni)
                bfr[ni] = *(const bf16x8*)(Bs + (wcol * 32 + ni * 16 + lrow) * LDP +
                                           ks * 32 + lkb * 8);
            #pragma unroll
            for (int mi = 0; mi < 4; ++mi)
                #pragma unroll
                for (int ni = 0; ni < 2; ++ni)
                    acc[mi][ni] = __builtin_amdgcn_mfma_f32_16x16x32_bf16(
                        af[mi], bfr[ni], acc[mi][ni], 0, 0, 0);
        }
        __syncthreads();
    }

    #pragma unroll
    for (int mi = 0; mi < 4; ++mi)
        #pragma unroll
        for (int reg = 0; reg < 4; ++reg) {
            int r = brow * 128 + wrow * 64 + mi * 16 + lkb * 4 + reg;
            #pragma unroll
            for (int ni = 0; ni < 2; ++ni) {
                int c = wcol * 32 + ni * 16 + lrow;
                C[(long)r * 64 + c] = f32_to_bf16(acc[mi][ni][reg]);
            }
        }
}

// ---------------- GEMM3: out[N][500] = out2b[MP][64] @ wlt[512][64]^T + bl --
__global__ __launch_bounds__(256) void gemm3_mfma(
        const ushort_t* __restrict__ A, const ushort_t* __restrict__ Bt,
        const float* __restrict__ bias, float* __restrict__ C) {
    __shared__ ushort_t As[128 * LDP];
    __shared__ ushort_t Bs[128 * LDP];
    int tid = threadIdx.x;
    int lane = tid & 63, wid = tid >> 6;
    int wrow = wid >> 1, wcol = wid & 1;
    int brow = blockIdx.y, bcol = blockIdx.x;

    f32x4 acc[4][4];
    const f32x4 zero = {0.f, 0.f, 0.f, 0.f};
    #pragma unroll
    for (int mi = 0; mi < 4; ++mi)
        #pragma unroll
        for (int ni = 0; ni < 4; ++ni) acc[mi][ni] = zero;

    int lrow = lane & 15, lkb = lane >> 4;

    #pragma unroll
    for (int it = 0; it < 4; ++it) {
        int slot = tid + it * 256;
        int row = slot >> 3, seg = slot & 7;
        *(int4*)(As + row * LDP + seg * 8) =
            *(const int4*)(A + ((long)(brow * 128 + row)) * 64 + seg * 8);
        *(int4*)(Bs + row * LDP + seg * 8) =
            *(const int4*)(Bt + ((long)(bcol * 128 + row)) * 64 + seg * 8);
    }
    __syncthreads();
    #pragma unroll
    for (int ks = 0; ks < 2; ++ks) {
        bf16x8 af[4], bfr[4];
        #pragma unroll
        for (int mi = 0; mi < 4; ++mi)
            af[mi] = *(const bf16x8*)(As + (wrow * 64 + mi * 16 + lrow) * LDP +
                                      ks * 32 + lkb * 8);
        #pragma unroll
        for (int ni = 0; ni < 4; ++ni)
            bfr[ni] = *(const bf16x8*)(Bs + (wcol * 64 + ni * 16 + lrow) * LDP +
                                       ks * 32 + lkb * 8);
        #pragma unroll
        for (int mi = 0; mi < 4; ++mi)
            #pragma unroll
            for (int ni = 0; ni < 4; ++ni)
                acc[mi][ni] = __builtin_amdgcn_mfma_f32_16x16x32_bf16(
                    af[mi], bfr[ni], acc[mi][ni], 0, 0, 0);
    }

    #pragma unroll
    for (int mi = 0; mi < 4; ++mi)
        #pragma unroll
        for (int reg = 0; reg < 4; ++reg) {
            int r = brow * 128 + wrow * 64 + mi * 16 + lkb * 4 + reg;
            if (r >= N_NODES) continue;
            #pragma unroll
            for (int ni = 0; ni < 4; ++ni) {
                int c = bcol * 128 + wcol * 64 + ni * 16 + lrow;
                if (c < F_IN) C[(long)r * F_IN + c] = acc[mi][ni][reg] + bias[c];
            }
        }
}

// ---------------- attention dots L2 (H=1): wave per node ----------------
__global__ void attn_dots1(const ushort_t* __restrict__ hb, const float* __restrict__ att_s,
                           const float* __restrict__ att_d, float* __restrict__ a_s,
                           float* __restrict__ a_d) {
    long wid = (blockIdx.x * (long)blockDim.x + threadIdx.x) >> 6;
    int lane = threadIdx.x & 63;
    if (wid >= N_NODES) return;
    int n = (int)wid;
    float f = __uint_as_float(((unsigned)hb[(long)n * 64 + lane]) << 16);
    float s = f * att_s[lane], d = f * att_d[lane];
    #pragma unroll
    for (int m = 32; m >= 1; m >>= 1) { s += __shfl_xor(s, m); d += __shfl_xor(d, m); }
    if (lane == 0) { a_s[n] = s; a_d[n] = d; }
}

// ---------------- csr_agg8: wave per dst, 8 heads, bf16 gather --------------
__global__ void csr_agg8(const int* __restrict__ ei, const int* __restrict__ off,
                         const int* __restrict__ eid, const float* __restrict__ a_s,
                         const float* __restrict__ a_d, const ushort_t* __restrict__ hb,
                         const float* __restrict__ bias, ushort_t* __restrict__ outb) {
    __shared__ float alds[4 * 64 * 9];       // per-wave [64 edges][9]
    long wid = (blockIdx.x * (long)blockDim.x + threadIdx.x) >> 6;
    int lane = threadIdx.x & 63;
    if (wid >= N_NODES) return;
    int dst = (int)wid;
    float* aw = alds + (threadIdx.x >> 6) * (64 * 9);
    int b = off[dst], e2 = off[dst + 1];
    int deg = e2 - b;
    int myh = lane >> 3;

    float ad[8];
    {
        const float* adp = a_d + (long)dst * 8;
        #pragma unroll
        for (int hh = 0; hh < 8; ++hh) ad[hh] = adp[hh];
    }

    float acc8[8];
    #pragma unroll
    for (int q = 0; q < 8; ++q) acc8[q] = 0.f;

    if (deg <= 64) {
        bool act = lane < deg;
        int src = act ? edge_src(ei, eid[b + lane]) : 0;
        const float* asp = a_s + (long)src * 8;
        float x[8];
        #pragma unroll
        for (int hh = 0; hh < 8; ++hh) {
            float v = act ? (asp[hh] + ad[hh]) : -1e30f;
            x[hh] = v > 0.f ? v : NEG_SLOPE * v;
        }
        #pragma unroll
        for (int hh = 0; hh < 8; ++hh) {
            float cm = x[hh];
            #pragma unroll
            for (int d2 = 32; d2 >= 1; d2 >>= 1) cm = fmaxf(cm, __shfl_xor(cm, d2));
            float ce = act ? __expf(x[hh] - cm) : 0.f;
            float ss = ce;
            #pragma unroll
            for (int d2 = 32; d2 >= 1; d2 >>= 1) ss += __shfl_xor(ss, d2);
            aw[lane * 9 + hh] = ce * (1.f / (ss + 1e-16f));
        }
        asm volatile("s_waitcnt lgkmcnt(0)" ::: "memory");
        for (int j = 0; j < deg; ++j) {
            int sj = __shfl(src, j);
            float aj = aw[j * 9 + myh];
            int4 hv = *(const int4*)(hb + (long)sj * 512 + lane * 8);
            #pragma unroll
            for (int q = 0; q < 4; ++q) {
                unsigned u = ((const unsigned*)&hv)[q];
                acc8[2 * q]     += aj * bf16_lo(u);
                acc8[2 * q + 1] += aj * bf16_hi(u);
            }
        }
    } else {
        float m[8], ssum[8];
        #pragma unroll
        for (int hh = 0; hh < 8; ++hh) { m[hh] = -1e30f; ssum[hh] = 0.f; }

        for (int c = b; c < e2; c += 64) {
            int i = c + lane;
            bool act = i < e2;
            int src = act ? edge_src(ei, eid[i]) : 0;
            float x[8];
            {
                const float* asp = a_s + (long)src * 8;
                #pragma unroll
                for (int hh = 0; hh < 8; ++hh) {
                    float v = act ? (asp[hh] + ad[hh]) : -1e30f;
                    x[hh] = v > 0.f ? v : NEG_SLOPE * v;
                }
            }
            #pragma unroll
            for (int hh = 0; hh < 8; ++hh) {
                float cm = x[hh];
                #pragma unroll
                for (int d2 = 32; d2 >= 1; d2 >>= 1) cm = fmaxf(cm, __shfl_xor(cm, d2));
                float nm = fmaxf(m[hh], cm);
                float ce = act ? __expf(x[hh] - nm) : 0.f;
                #pragma unroll
                for (int d2 = 32; d2 >= 1; d2 >>= 1) ce += __shfl_xor(ce, d2);
                ssum[hh] = ssum[hh] * __expf(m[hh] - nm) + ce;
                m[hh] = nm;
            }
        }
        float inv[8];
        #pragma unroll
        for (int hh = 0; hh < 8; ++hh) inv[hh] = 1.f / (ssum[hh] + 1e-16f);

        for (int c = b; c < e2; c += 64) {
            int i = c + lane;
            bool act = i < e2;
            int src = act ? edge_src(ei, eid[i]) : 0;
            {
                const float* asp = a_s + (long)src * 8;
                #pragma unroll
                for (int hh = 0; hh < 8; ++hh) {
                    float v = act ? (asp[hh] + ad[hh]) : -1e30f;
                    v = v > 0.f ? v : NEG_SLOPE * v;
                    aw[lane * 9 + hh] = act ? __expf(v - m[hh]) * inv[hh] : 0.f;
                }
            }
            asm volatile("s_waitcnt lgkmcnt(0)" ::: "memory");
            int cnt = min(64, e2 - c);
            for (int j = 0; j < cnt; ++j) {
                int sj = __shfl(src, j);
                float aj = aw[j * 9 + myh];
                int4 hv = *(const int4*)(hb + (long)sj * 512 + lane * 8);
                #pragma unroll
                for (int q = 0; q < 4; ++q) {
                    unsigned u = ((const unsigned*)&hv)[q];
                    acc8[2 * q]     += aj * bf16_lo(u);
                    acc8[2 * q + 1] += aj * bf16_hi(u);
                }
            }
            asm volatile("s_waitcnt lgkmcnt(0)" ::: "memory");
        }
    }

    const float* bp = bias + lane * 8;
    int4 st;
    #pragma unroll
    for (int q = 0; q < 8; ++q) {
        float v = acc8[q] + bp[q];
        v = v > 0.f ? v : (__expf(v) - 1.f);
        ((ushort_t*)&st)[q] = f32_to_bf16(v);
    }
    *(int4*)(outb + (long)dst * 512 + lane * 8) = st;
}

// ---------------- csr_agg1: wave per dst, H=1, bf16 gather ------------------
__global__ void csr_agg1(const int* __restrict__ ei, const int* __restrict__ off,
                         const int* __restrict__ eid, const float* __restrict__ a_s,
                         const float* __restrict__ a_d, const ushort_t* __restrict__ hb,
                         const float* __restrict__ bias, ushort_t* __restrict__ outb) {
    long wid = (blockIdx.x * (long)blockDim.x + threadIdx.x) >> 6;
    int lane = threadIdx.x & 63;
    if (wid >= N_NODES) return;
    int dst = (int)wid;
    int b = off[dst], e2 = off[dst + 1];
    float ad = a_d[dst];

    float m = -1e30f, ssum = 0.f;
    for (int c = b; c < e2; c += 64) {
        int i = c + lane;
        bool act = i < e2;
        int src = act ? edge_src(ei, eid[i]) : 0;
        float v = act ? (a_s[src] + ad) : -1e30f;
        float x = v > 0.f ? v : NEG_SLOPE * v;
        float cm = x;
        #pragma unroll
        for (int d2 = 32; d2 >= 1; d2 >>= 1) cm = fmaxf(cm, __shfl_xor(cm, d2));
        float nm = fmaxf(m, cm);
        float ce = act ? __expf(x - nm) : 0.f;
        #pragma unroll
        for (int d2 = 32; d2 >= 1; d2 >>= 1) ce += __shfl_xor(ce, d2);
        ssum = ssum * __expf(m - nm) + ce;
        m = nm;
    }
    float inv = 1.f / (ssum + 1e-16f);

    float acc = 0.f;
    for (int c = b; c < e2; c += 64) {
        int i = c + lane;
        bool act = i < e2;
        int src = act ? edge_src(ei, eid[i]) : 0;
        float alpha = 0.f;
        if (act) {
            float v = a_s[src] + ad;
            v = v > 0.f ? v : NEG_SLOPE * v;
            alpha = __expf(v - m) * inv;
        }
        int cnt = min(64, e2 - c);
        for (int j = 0; j < cnt; ++j) {
            int sj = __shfl(src, j);
            float aj = __shfl(alpha, j);
            float f = __uint_as_float(((unsigned)hb[(long)sj * 64 + lane]) << 16);
            acc += aj * f;
        }
    }
    float v = acc + bias[lane];
    v = v > 0.f ? v : (__expf(v) - 1.f);
    outb[(long)dst * 64 + lane] = f32_to_bf16(v);
}

// ---------------------------------------------------------------------------
extern "C" void kernel_launch(void* const* d_in, const int* in_sizes, int n_in,
                              void* d_out, int out_size, void* d_ws, size_t ws_size,
                              hipStream_t stream) {
    const float* x        = (const float*)d_in[0];
    const int*   ei       = (const int*)d_in[1];
    const float* W1       = (const float*)d_in[2];
    const float* att_src1 = (const float*)d_in[3];
    const float* att_dst1 = (const float*)d_in[4];
    const float* b1       = (const float*)d_in[5];
    const float* W2       = (const float*)d_in[6];
    const float* att_src2 = (const float*)d_in[7];
    const float* att_dst2 = (const float*)d_in[8];
    const float* b2       = (const float*)d_in[9];
    const float* Wl       = (const float*)d_in[10];
    const float* bl       = (const float*)d_in[11];
    float* out = (float*)d_out;

    // workspace layout
    char* p = (char*)d_ws;
    ushort_t* h1b   = (ushort_t*)p; p += (long)MP * 512 * 2;
    ushort_t* out1b = (ushort_t*)p; p += (long)MP * 512 * 2;
    ushort_t* h2b   = (ushort_t*)p; p += (long)MP * 64 * 2;
    ushort_t* out2b = (ushort_t*)p; p += (long)MP * 64 * 2;
    float* as1 = (float*)p; p += (long)N_NODES * 8 * 4;
    float* ad1 = (float*)p; p += (long)N_NODES * 8 * 4;
    ushort_t* w1t = (ushort_t*)p; p += 512 * 512 * 2;
    ushort_t* w2t = (ushort_t*)p; p += 64 * 512 * 2;
    ushort_t* wlt = (ushort_t*)p; p += 512 * 64 * 2;
    int* csr_off = (int*)p; p += (N_NODES + 4) * 4;
    int* csr_cnt = (int*)p; p += N_NODES * 4;
    int* csr_eid = (int*)p; p += (long)E_TOT * 4;

    const int BT = 256;
    dim3 blk(BT);

    // ---------------- CSR build ----------------
    fill_i32<<<256, blk, 0, stream>>>(csr_cnt, 0, N_NODES);
    count_deg<<<1024, blk, 0, stream>>>(ei, csr_cnt);
    scan_deg<<<1, 1024, 0, stream>>>(csr_cnt, csr_off, N_NODES);
    fill_i32<<<256, blk, 0, stream>>>(csr_cnt, 0, N_NODES);
    scatter_edges<<<1024, blk, 0, stream>>>(ei, csr_off, csr_cnt, csr_eid);

    // ---------------- weight conversions + pad-row zero fills ----------------
    cvt_w1t_bf16<<<512, blk, 0, stream>>>(W1, w1t);
    cvt_w2t_bf16<<<64, blk, 0, stream>>>(W2, w2t);
    cvt_wlt_bf16<<<64, blk, 0, stream>>>(Wl, wlt);
    fill_i32<<<12, blk, 0, stream>>>((int*)(out1b + (long)N_NODES * 512), 0,
                                     (MP - N_NODES) * 512 / 2);
    fill_i32<<<2, blk, 0, stream>>>((int*)(out2b + (long)N_NODES * 64), 0,
                                    (MP - N_NODES) * 64 / 2);

    // ---------------- layer 1: fused GEMM + attn dots ----------------
    gemm1_big<<<MP / 128, dim3(512), 0, stream>>>(x, w1t, att_src1, att_dst1,
                                                  h1b, as1, ad1);
    csr_agg8<<<(N_NODES * 64 + BT - 1) / BT, blk, 0, stream>>>(
        ei, csr_off, csr_eid, as1, ad1, h1b, b1, out1b);

    // ---------------- layer 2 (H=1) ----------------
    gemm2_mfma<<<MP / 128, blk, 0, stream>>>(out1b, w2t, h2b);
    attn_dots1<<<(N_NODES * 64 + BT - 1) / BT, blk, 0, stream>>>(h2b, att_src2, att_dst2,
                                                                 as1, ad1);
    csr_agg1<<<(N_NODES * 64 + BT - 1) / BT, blk, 0, stream>>>(
        ei, csr_off, csr_eid, as1, ad1, h2b, b2, out2b);

    // ---------------- final linear ----------------
    {
        dim3 grid(512 / 128, MP / 128);
        gemm3_mfma<<<grid, blk, 0, stream>>>(out2b, wlt, bl, out);
    }
}

// Round 8
// 411.361 us; speedup vs baseline: 5.6683x; 1.1580x over previous
//
#include <hip/hip_runtime.h>
#include <hip/hip_bf16.h>

// ---------------------------------------------------------------------------
// GAT 2-layer forward (PyG GATConv semantics, eval mode).
// R8: gemm1 rebuilt lean: 64x256 blocks, 256 thr, acc[2][8] (<=128 VGPR,
//     4 waves/SIMD), BK=64, A reg-staged to padded LDS, B via global_load_lds
//     with source-XOR swizzle; fused a_s/a_d epilogue. scan_deg -> 3-kernel
//     multi-block scan. Rest unchanged from R7.
// ---------------------------------------------------------------------------

#define N_NODES 50000
#define F_IN    500
#define H1      8
#define E_RAW   600000
#define E_TOT   (E_RAW + N_NODES)
#define NEG_SLOPE 0.2f

#define MP      50048      // N_NODES padded to multiple of 128
#define KP      512        // F_IN padded

typedef __attribute__((ext_vector_type(8))) short bf16x8;
typedef __attribute__((ext_vector_type(4))) float f32x4;
typedef unsigned short ushort_t;

__device__ __forceinline__ int edge_src(const int* ei, int e) {
    return (e < E_RAW) ? ei[e] : e - E_RAW;
}
__device__ __forceinline__ int edge_dst(const int* ei, int e) {
    return (e < E_RAW) ? ei[E_RAW + e] : e - E_RAW;
}

__device__ __forceinline__ unsigned short f32_to_bf16(float f) {
    unsigned int u = __float_as_uint(f);
    u += 0x7fffu + ((u >> 16) & 1u);       // RNE
    return (unsigned short)(u >> 16);
}
__device__ __forceinline__ float bf16_lo(unsigned int u) {
    return __uint_as_float(u << 16);
}
__device__ __forceinline__ float bf16_hi(unsigned int u) {
    return __uint_as_float(u & 0xffff0000u);
}

// ---------------- fills ----------------
__global__ void fill_i32(int* __restrict__ p, int v, long n) {
    long i = blockIdx.x * (long)blockDim.x + threadIdx.x;
    long stride = (long)gridDim.x * blockDim.x;
    for (; i < n; i += stride) p[i] = v;
}

// ---------------- CSR build ----------------
__global__ void count_deg(const int* __restrict__ ei, int* __restrict__ deg) {
    long i = blockIdx.x * (long)blockDim.x + threadIdx.x;
    long stride = (long)gridDim.x * blockDim.x;
    for (; i < E_TOT; i += stride) atomicAdd(&deg[edge_dst(ei, (int)i)], 1);
}

// 3-phase scan over n = 50000 (196 blocks x 256)
__global__ void scan_part(const int* __restrict__ deg, int* __restrict__ part, int n) {
    __shared__ int sm[256];
    int i = blockIdx.x * 256 + threadIdx.x;
    sm[threadIdx.x] = (i < n) ? deg[i] : 0;
    __syncthreads();
    for (int d = 128; d >= 1; d >>= 1) {
        if (threadIdx.x < d) sm[threadIdx.x] += sm[threadIdx.x + d];
        __syncthreads();
    }
    if (threadIdx.x == 0) part[blockIdx.x] = sm[0];
}

__global__ void scan_top(int* __restrict__ part, int nb) {
    __shared__ int sm[256];
    int t = threadIdx.x;
    sm[t] = (t < nb) ? part[t] : 0;
    __syncthreads();
    for (int d = 1; d < 256; d <<= 1) {
        int v = (t >= d) ? sm[t - d] : 0;
        __syncthreads();
        sm[t] += v;
        __syncthreads();
    }
    if (t < nb) part[t] = (t == 0) ? 0 : sm[t - 1];   // exclusive
}

__global__ void scan_final(const int* __restrict__ deg, const int* __restrict__ part,
                           int* __restrict__ off, int n) {
    __shared__ int sm[256];
    int i = blockIdx.x * 256 + threadIdx.x;
    int v = (i < n) ? deg[i] : 0;
    sm[threadIdx.x] = v;
    __syncthreads();
    for (int d = 1; d < 256; d <<= 1) {
        int u = (threadIdx.x >= d) ? sm[threadIdx.x - d] : 0;
        __syncthreads();
        sm[threadIdx.x] += u;
        __syncthreads();
    }
    int excl = sm[threadIdx.x] - v + part[blockIdx.x];
    if (i < n) off[i] = excl;
    if (i == n - 1) off[n] = excl + v;
}

__global__ void scatter_edges(const int* __restrict__ ei, const int* __restrict__ off,
                              int* __restrict__ cnt, int* __restrict__ eid) {
    long i = blockIdx.x * (long)blockDim.x + threadIdx.x;
    long stride = (long)gridDim.x * blockDim.x;
    for (; i < E_TOT; i += stride) {
        int d = edge_dst(ei, (int)i);
        int p = atomicAdd(&cnt[d], 1);
        eid[off[d] + p] = (int)i;
    }
}

// ---------------- bf16 weight conversion kernels ----------------
__global__ void cvt_w1t_bf16(const float* __restrict__ W1, ushort_t* __restrict__ w1t) {
    int idx = blockIdx.x * blockDim.x + threadIdx.x;
    if (idx >= 512 * (KP / 2)) return;
    int n = idx >> 8, k0 = (idx & 255) * 2;
    float v0 = (k0 < F_IN) ? W1[(long)k0 * 512 + n] : 0.f;
    float v1 = (k0 + 1 < F_IN) ? W1[(long)(k0 + 1) * 512 + n] : 0.f;
    ((unsigned int*)w1t)[idx] = (unsigned int)f32_to_bf16(v0) |
                                ((unsigned int)f32_to_bf16(v1) << 16);
}

__global__ void cvt_w2t_bf16(const float* __restrict__ W2, ushort_t* __restrict__ w2t) {
    int idx = blockIdx.x * blockDim.x + threadIdx.x;
    if (idx >= 64 * 256) return;
    int n = idx >> 8, k0 = (idx & 255) * 2;
    float v0 = W2[(long)k0 * 64 + n];
    float v1 = W2[(long)(k0 + 1) * 64 + n];
    ((unsigned int*)w2t)[idx] = (unsigned int)f32_to_bf16(v0) |
                                ((unsigned int)f32_to_bf16(v1) << 16);
}

__global__ void cvt_wlt_bf16(const float* __restrict__ Wl, ushort_t* __restrict__ wlt) {
    int idx = blockIdx.x * blockDim.x + threadIdx.x;
    if (idx >= 512 * 32) return;
    int n = idx >> 5, k0 = (idx & 31) * 2;
    float v0 = (n < F_IN) ? Wl[(long)k0 * F_IN + n] : 0.f;
    float v1 = (n < F_IN) ? Wl[(long)(k0 + 1) * F_IN + n] : 0.f;
    ((unsigned int*)wlt)[idx] = (unsigned int)f32_to_bf16(v0) |
                                ((unsigned int)f32_to_bf16(v1) << 16);
}

// ---------------- GEMM1 (fused): h1b = bf16(x) @ w1t^T; a_s/a_d epilogue ----
// Block: 64 rows x 256 cols, 4 waves (wrow 0..1 x wcol 0..1), BK=64.
// A: f32 x reg-staged -> padded LDS [64][72] (2-way banks, free).
// B: global_load_lds, source-XOR swizzle (slot ^= n&7), matching read XOR.
__global__ __launch_bounds__(256, 4) void gemm1_big(
        const float* __restrict__ X, const ushort_t* __restrict__ Bt,
        const float* __restrict__ att_s, const float* __restrict__ att_d,
        ushort_t* __restrict__ H, float* __restrict__ a_s, float* __restrict__ a_d) {
    __shared__ ushort_t As[64 * 72];     // 9 KB, padded
    __shared__ ushort_t Bs[256 * 64];    // 32 KB, linear (gload_lds dest)
    int tid = threadIdx.x;
    int lane = tid & 63, wid = tid >> 6;
    int wrow = wid >> 1, wcol = wid & 1;
    int lrow = lane & 15, lkb = lane >> 4;
    int brow = blockIdx.y, bcol = blockIdx.x;

    f32x4 acc[2][8];
    const f32x4 zero = {0.f, 0.f, 0.f, 0.f};
    #pragma unroll
    for (int mi = 0; mi < 2; ++mi)
        #pragma unroll
        for (int ni = 0; ni < 8; ++ni) acc[mi][ni] = zero;

    // A staging: thread -> row = tid>>2 (0..63), 16 k-elems at (tid&3)*16
    int arow = tid >> 2;
    int akq = (tid & 3) * 16;
    long arow_g = (long)brow * 64 + arow;
    bool arow_ok = arow_g < N_NODES;
    const float* aG = X + arow_g * F_IN;
    ushort_t* aL = As + arow * 72 + akq;

    for (int k0 = 0; k0 < KP; k0 += 64) {
        // ---- stage B via global_load_lds (pre-swizzled source) ----
        #pragma unroll
        for (int i = 0; i < 8; ++i) {
            int slotL = i * 256 + tid;          // 0..2047 = 256 rows x 8 slots
            int n = slotL >> 3, s = slotL & 7;
            const ushort_t* g = Bt + ((long)(bcol * 256 + n)) * 512 + k0 +
                                ((s ^ (n & 7)) * 8);
            __builtin_amdgcn_global_load_lds(
                (const __attribute__((address_space(1))) void*)g,
                (__attribute__((address_space(3))) void*)(Bs + slotL * 8), 16, 0, 0);
        }
        // ---- stage A (f32 load + in-reg cvt) ----
        float av[16];
        #pragma unroll
        for (int q = 0; q < 4; ++q) {
            int kk = k0 + akq + q * 4;
            float4 v = {0.f, 0.f, 0.f, 0.f};
            if (arow_ok && kk + 4 <= F_IN) v = *(const float4*)(aG + kk);
            av[q * 4 + 0] = v.x; av[q * 4 + 1] = v.y;
            av[q * 4 + 2] = v.z; av[q * 4 + 3] = v.w;
        }
        int4 apk0, apk1;
        #pragma unroll
        for (int q = 0; q < 4; ++q) {
            ((unsigned*)&apk0)[q] = (unsigned)f32_to_bf16(av[2 * q]) |
                                    ((unsigned)f32_to_bf16(av[2 * q + 1]) << 16);
            ((unsigned*)&apk1)[q] = (unsigned)f32_to_bf16(av[8 + 2 * q]) |
                                    ((unsigned)f32_to_bf16(av[9 + 2 * q]) << 16);
        }
        *(int4*)aL = apk0;
        *(int4*)(aL + 8) = apk1;
        __syncthreads();

        // ---- MFMA ----
        #pragma unroll
        for (int ks = 0; ks < 2; ++ks) {
            bf16x8 af[2], bfr[8];
            #pragma unroll
            for (int mi = 0; mi < 2; ++mi) {
                int row = wrow * 32 + mi * 16 + lrow;
                af[mi] = *(const bf16x8*)(As + row * 72 + ks * 32 + lkb * 8);
            }
            #pragma unroll
            for (int ni = 0; ni < 8; ++ni) {
                int n = wcol * 128 + ni * 16 + lrow;
                bfr[ni] = *(const bf16x8*)(Bs + n * 64 +
                                           (((ks * 4 + lkb) ^ (n & 7)) * 8));
            }
            #pragma unroll
            for (int mi = 0; mi < 2; ++mi)
                #pragma unroll
                for (int ni = 0; ni < 8; ++ni)
                    acc[mi][ni] = __builtin_amdgcn_mfma_f32_16x16x32_bf16(
                        af[mi], bfr[ni], acc[mi][ni], 0, 0, 0);
        }
        __syncthreads();
    }

    // ---- epilogue: h1b store + fused attention dots ----
    // C/D layout: col = lrow, row = lkb*4 + reg  [m89]
    int hA = bcol * 4 + wcol * 2, hB = hA + 1;
    float asv[2][4], adv[2][4];
    #pragma unroll
    for (int j = 0; j < 4; ++j) {
        asv[0][j] = att_s[hA * 64 + j * 16 + lrow];
        asv[1][j] = att_s[hB * 64 + j * 16 + lrow];
        adv[0][j] = att_d[hA * 64 + j * 16 + lrow];
        adv[1][j] = att_d[hB * 64 + j * 16 + lrow];
    }

    #pragma unroll
    for (int mi = 0; mi < 2; ++mi) {
        #pragma unroll
        for (int reg = 0; reg < 4; ++reg) {
            long r = (long)brow * 64 + wrow * 32 + mi * 16 + lkb * 4 + reg;
            #pragma unroll
            for (int ni = 0; ni < 8; ++ni) {
                int c = bcol * 256 + wcol * 128 + ni * 16 + lrow;
                H[r * 512 + c] = f32_to_bf16(acc[mi][ni][reg]);
            }
            float sA = 0.f, dA = 0.f, sB = 0.f, dB = 0.f;
            #pragma unroll
            for (int j = 0; j < 4; ++j) {
                sA += acc[mi][j][reg] * asv[0][j];
                dA += acc[mi][j][reg] * adv[0][j];
                sB += acc[mi][j + 4][reg] * asv[1][j];
                dB += acc[mi][j + 4][reg] * adv[1][j];
            }
            #pragma unroll
            for (int mm = 8; mm >= 1; mm >>= 1) {
                sA += __shfl_xor(sA, mm);
                dA += __shfl_xor(dA, mm);
                sB += __shfl_xor(sB, mm);
                dB += __shfl_xor(dB, mm);
            }
            if (lrow == 0 && r < N_NODES) {
                a_s[r * 8 + hA] = sA;
                a_d[r * 8 + hA] = dA;
                a_s[r * 8 + hB] = sB;
                a_d[r * 8 + hB] = dB;
            }
        }
    }
}

// ---------------- GEMM2: h2b[MP][64] = out1b[MP][512] @ w2t[64][512]^T -----
#define LDP 72

__global__ __launch_bounds__(256) void gemm2_mfma(
        const ushort_t* __restrict__ A, const ushort_t* __restrict__ Bt,
        ushort_t* __restrict__ C) {
    __shared__ ushort_t As[128 * LDP];
    __shared__ ushort_t Bs[64 * LDP];
    int tid = threadIdx.x;
    int lane = tid & 63, wid = tid >> 6;
    int wrow = wid >> 1, wcol = wid & 1;
    int brow = blockIdx.x;

    f32x4 acc[4][2];
    const f32x4 zero = {0.f, 0.f, 0.f, 0.f};
    #pragma unroll
    for (int mi = 0; mi < 4; ++mi) { acc[mi][0] = zero; acc[mi][1] = zero; }

    int lrow = lane & 15, lkb = lane >> 4;

    for (int k0 = 0; k0 < 512; k0 += 64) {
        #pragma unroll
        for (int it = 0; it < 4; ++it) {
            int slot = tid + it * 256;
            int row = slot >> 3, seg = slot & 7;
            *(int4*)(As + row * LDP + seg * 8) =
                *(const int4*)(A + ((long)(brow * 128 + row)) * 512 + k0 + seg * 8);
        }
        #pragma unroll
        for (int it = 0; it < 2; ++it) {
            int slot = tid + it * 256;
            int row = slot >> 3, seg = slot & 7;
            *(int4*)(Bs + row * LDP + seg * 8) =
                *(const int4*)(Bt + (long)row * 512 + k0 + seg * 8);
        }
        __syncthreads();
        #pragma unroll
        for (int ks = 0; ks < 2; ++ks) {
            bf16x8 af[4], bfr[2];
            #pragma unroll
            for (int mi = 0; mi < 4; ++mi)
                af[mi] = *(const bf16x8*)(As + (wrow * 64 + mi * 16 + lrow) * LDP +
                                          ks * 32 + lkb * 8);
            #pragma unroll
            for (int ni = 0; ni < 2; ++ni)
                bfr[ni] = *(const bf16x8*)(Bs + (wcol * 32 + ni * 16 + lrow) * LDP +
                                           ks * 32 + lkb * 8);
            #pragma unroll
            for (int mi = 0; mi < 4; ++mi)
                #pragma unroll
                for (int ni = 0; ni < 2; ++ni)
                    acc[mi][ni] = __builtin_amdgcn_mfma_f32_16x16x32_bf16(
                        af[mi], bfr[ni], acc[mi][ni], 0, 0, 0);
        }
        __syncthreads();
    }

    #pragma unroll
    for (int mi = 0; mi < 4; ++mi)
        #pragma unroll
        for (int reg = 0; reg < 4; ++reg) {
            int r = brow * 128 + wrow * 64 + mi * 16 + lkb * 4 + reg;
            #pragma unroll
            for (int ni = 0; ni < 2; ++ni) {
                int c = wcol * 32 + ni * 16 + lrow;
                C[(long)r * 64 + c] = f32_to_bf16(acc[mi][ni][reg]);
            }
        }
}

// ---------------- GEMM3: out[N][500] = out2b[MP][64] @ wlt[512][64]^T + bl --
__global__ __launch_bounds__(256) void gemm3_mfma(
        const ushort_t* __restrict__ A, const ushort_t* __restrict__ Bt,
        const float* __restrict__ bias, float* __restrict__ C) {
    __shared__ ushort_t As[128 * LDP];
    __shared__ ushort_t Bs[128 * LDP];
    int tid = threadIdx.x;
    int lane = tid & 63, wid = tid >> 6;
    int wrow = wid >> 1, wcol = wid & 1;
    int brow = blockIdx.y, bcol = blockIdx.x;

    f32x4 acc[4][4];
    const f32x4 zero = {0.f, 0.f, 0.f, 0.f};
    #pragma unroll
    for (int mi = 0; mi < 4; ++mi)
        #pragma unroll
        for (int ni = 0; ni < 4; ++ni) acc[mi][ni] = zero;

    int lrow = lane & 15, lkb = lane >> 4;

    #pragma unroll
    for (int it = 0; it < 4; ++it) {
        int slot = tid + it * 256;
        int row = slot >> 3, seg = slot & 7;
        *(int4*)(As + row * LDP + seg * 8) =
            *(const int4*)(A + ((long)(brow * 128 + row)) * 64 + seg * 8);
        *(int4*)(Bs + row * LDP + seg * 8) =
            *(const int4*)(Bt + ((long)(bcol * 128 + row)) * 64 + seg * 8);
    }
    __syncthreads();
    #pragma unroll
    for (int ks = 0; ks < 2; ++ks) {
        bf16x8 af[4], bfr[4];
        #pragma unroll
        for (int mi = 0; mi < 4; ++mi)
            af[mi] = *(const bf16x8*)(As + (wrow * 64 + mi * 16 + lrow) * LDP +
                                      ks * 32 + lkb * 8);
        #pragma unroll
        for (int ni = 0; ni < 4; ++ni)
            bfr[ni] = *(const bf16x8*)(Bs + (wcol * 64 + ni * 16 + lrow) * LDP +
                                       ks * 32 + lkb * 8);
        #pragma unroll
        for (int mi = 0; mi < 4; ++mi)
            #pragma unroll
            for (int ni = 0; ni < 4; ++ni)
                acc[mi][ni] = __builtin_amdgcn_mfma_f32_16x16x32_bf16(
                    af[mi], bfr[ni], acc[mi][ni], 0, 0, 0);
    }

    #pragma unroll
    for (int mi = 0; mi < 4; ++mi)
        #pragma unroll
        for (int reg = 0; reg < 4; ++reg) {
            int r = brow * 128 + wrow * 64 + mi * 16 + lkb * 4 + reg;
            if (r >= N_NODES) continue;
            #pragma unroll
            for (int ni = 0; ni < 4; ++ni) {
                int c = bcol * 128 + wcol * 64 + ni * 16 + lrow;
                if (c < F_IN) C[(long)r * F_IN + c] = acc[mi][ni][reg] + bias[c];
            }
        }
}

// ---------------- attention dots L2 (H=1): wave per node ----------------
__global__ void attn_dots1(const ushort_t* __restrict__ hb, const float* __restrict__ att_s,
                           const float* __restrict__ att_d, float* __restrict__ a_s,
                           float* __restrict__ a_d) {
    long wid = (blockIdx.x * (long)blockDim.x + threadIdx.x) >> 6;
    int lane = threadIdx.x & 63;
    if (wid >= N_NODES) return;
    int n = (int)wid;
    float f = __uint_as_float(((unsigned)hb[(long)n * 64 + lane]) << 16);
    float s = f * att_s[lane], d = f * att_d[lane];
    #pragma unroll
    for (int m = 32; m >= 1; m >>= 1) { s += __shfl_xor(s, m); d += __shfl_xor(d, m); }
    if (lane == 0) { a_s[n] = s; a_d[n] = d; }
}

// ---------------- csr_agg8: wave per dst, 8 heads, bf16 gather --------------
__global__ void csr_agg8(const int* __restrict__ ei, const int* __restrict__ off,
                         const int* __restrict__ eid, const float* __restrict__ a_s,
                         const float* __restrict__ a_d, const ushort_t* __restrict__ hb,
                         const float* __restrict__ bias, ushort_t* __restrict__ outb) {
    __shared__ float alds[4 * 64 * 9];       // per-wave [64 edges][9]
    long wid = (blockIdx.x * (long)blockDim.x + threadIdx.x) >> 6;
    int lane = threadIdx.x & 63;
    if (wid >= N_NODES) return;
    int dst = (int)wid;
    float* aw = alds + (threadIdx.x >> 6) * (64 * 9);
    int b = off[dst], e2 = off[dst + 1];
    int deg = e2 - b;
    int myh = lane >> 3;

    float ad[8];
    {
        const float* adp = a_d + (long)dst * 8;
        #pragma unroll
        for (int hh = 0; hh < 8; ++hh) ad[hh] = adp[hh];
    }

    float acc8[8];
    #pragma unroll
    for (int q = 0; q < 8; ++q) acc8[q] = 0.f;

    if (deg <= 64) {
        bool act = lane < deg;
        int src = act ? edge_src(ei, eid[b + lane]) : 0;
        const float* asp = a_s + (long)src * 8;
        float x[8];
        #pragma unroll
        for (int hh = 0; hh < 8; ++hh) {
            float v = act ? (asp[hh] + ad[hh]) : -1e30f;
            x[hh] = v > 0.f ? v : NEG_SLOPE * v;
        }
        #pragma unroll
        for (int hh = 0; hh < 8; ++hh) {
            float cm = x[hh];
            #pragma unroll
            for (int d2 = 32; d2 >= 1; d2 >>= 1) cm = fmaxf(cm, __shfl_xor(cm, d2));
            float ce = act ? __expf(x[hh] - cm) : 0.f;
            float ss = ce;
            #pragma unroll
            for (int d2 = 32; d2 >= 1; d2 >>= 1) ss += __shfl_xor(ss, d2);
            aw[lane * 9 + hh] = ce * (1.f / (ss + 1e-16f));
        }
        asm volatile("s_waitcnt lgkmcnt(0)" ::: "memory");
        for (int j = 0; j < deg; ++j) {
            int sj = __shfl(src, j);
            float aj = aw[j * 9 + myh];
            int4 hv = *(const int4*)(hb + (long)sj * 512 + lane * 8);
            #pragma unroll
            for (int q = 0; q < 4; ++q) {
                unsigned u = ((const unsigned*)&hv)[q];
                acc8[2 * q]     += aj * bf16_lo(u);
                acc8[2 * q + 1] += aj * bf16_hi(u);
            }
        }
    } else {
        float m[8], ssum[8];
        #pragma unroll
        for (int hh = 0; hh < 8; ++hh) { m[hh] = -1e30f; ssum[hh] = 0.f; }

        for (int c = b; c < e2; c += 64) {
            int i = c + lane;
            bool act = i < e2;
            int src = act ? edge_src(ei, eid[i]) : 0;
            float x[8];
            {
                const float* asp = a_s + (long)src * 8;
                #pragma unroll
                for (int hh = 0; hh < 8; ++hh) {
                    float v = act ? (asp[hh] + ad[hh]) : -1e30f;
                    x[hh] = v > 0.f ? v : NEG_SLOPE * v;
                }
            }
            #pragma unroll
            for (int hh = 0; hh < 8; ++hh) {
                float cm = x[hh];
                #pragma unroll
                for (int d2 = 32; d2 >= 1; d2 >>= 1) cm = fmaxf(cm, __shfl_xor(cm, d2));
                float nm = fmaxf(m[hh], cm);
                float ce = act ? __expf(x[hh] - nm) : 0.f;
                #pragma unroll
                for (int d2 = 32; d2 >= 1; d2 >>= 1) ce += __shfl_xor(ce, d2);
                ssum[hh] = ssum[hh] * __expf(m[hh] - nm) + ce;
                m[hh] = nm;
            }
        }
        float inv[8];
        #pragma unroll
        for (int hh = 0; hh < 8; ++hh) inv[hh] = 1.f / (ssum[hh] + 1e-16f);

        for (int c = b; c < e2; c += 64) {
            int i = c + lane;
            bool act = i < e2;
            int src = act ? edge_src(ei, eid[i]) : 0;
            {
                const float* asp = a_s + (long)src * 8;
                #pragma unroll
                for (int hh = 0; hh < 8; ++hh) {
                    float v = act ? (asp[hh] + ad[hh]) : -1e30f;
                    v = v > 0.f ? v : NEG_SLOPE * v;
                    aw[lane * 9 + hh] = act ? __expf(v - m[hh]) * inv[hh] : 0.f;
                }
            }
            asm volatile("s_waitcnt lgkmcnt(0)" ::: "memory");
            int cnt = min(64, e2 - c);
            for (int j = 0; j < cnt; ++j) {
                int sj = __shfl(src, j);
                float aj = aw[j * 9 + myh];
                int4 hv = *(const int4*)(hb + (long)sj * 512 + lane * 8);
                #pragma unroll
                for (int q = 0; q < 4; ++q) {
                    unsigned u = ((const unsigned*)&hv)[q];
                    acc8[2 * q]     += aj * bf16_lo(u);
                    acc8[2 * q + 1] += aj * bf16_hi(u);
                }
            }
            asm volatile("s_waitcnt lgkmcnt(0)" ::: "memory");
        }
    }

    const float* bp = bias + lane * 8;
    int4 st;
    #pragma unroll
    for (int q = 0; q < 8; ++q) {
        float v = acc8[q] + bp[q];
        v = v > 0.f ? v : (__expf(v) - 1.f);
        ((ushort_t*)&st)[q] = f32_to_bf16(v);
    }
    *(int4*)(outb + (long)dst * 512 + lane * 8) = st;
}

// ---------------- csr_agg1: wave per dst, H=1, bf16 gather ------------------
__global__ void csr_agg1(const int* __restrict__ ei, const int* __restrict__ off,
                         const int* __restrict__ eid, const float* __restrict__ a_s,
                         const float* __restrict__ a_d, const ushort_t* __restrict__ hb,
                         const float* __restrict__ bias, ushort_t* __restrict__ outb) {
    long wid = (blockIdx.x * (long)blockDim.x + threadIdx.x) >> 6;
    int lane = threadIdx.x & 63;
    if (wid >= N_NODES) return;
    int dst = (int)wid;
    int b = off[dst], e2 = off[dst + 1];
    float ad = a_d[dst];

    float m = -1e30f, ssum = 0.f;
    for (int c = b; c < e2; c += 64) {
        int i = c + lane;
        bool act = i < e2;
        int src = act ? edge_src(ei, eid[i]) : 0;
        float v = act ? (a_s[src] + ad) : -1e30f;
        float x = v > 0.f ? v : NEG_SLOPE * v;
        float cm = x;
        #pragma unroll
        for (int d2 = 32; d2 >= 1; d2 >>= 1) cm = fmaxf(cm, __shfl_xor(cm, d2));
        float nm = fmaxf(m, cm);
        float ce = act ? __expf(x - nm) : 0.f;
        #pragma unroll
        for (int d2 = 32; d2 >= 1; d2 >>= 1) ce += __shfl_xor(ce, d2);
        ssum = ssum * __expf(m - nm) + ce;
        m = nm;
    }
    float inv = 1.f / (ssum + 1e-16f);

    float acc = 0.f;
    for (int c = b; c < e2; c += 64) {
        int i = c + lane;
        bool act = i < e2;
        int src = act ? edge_src(ei, eid[i]) : 0;
        float alpha = 0.f;
        if (act) {
            float v = a_s[src] + ad;
            v = v > 0.f ? v : NEG_SLOPE * v;
            alpha = __expf(v - m) * inv;
        }
        int cnt = min(64, e2 - c);
        for (int j = 0; j < cnt; ++j) {
            int sj = __shfl(src, j);
            float aj = __shfl(alpha, j);
            float f = __uint_as_float(((unsigned)hb[(long)sj * 64 + lane]) << 16);
            acc += aj * f;
        }
    }
    float v = acc + bias[lane];
    v = v > 0.f ? v : (__expf(v) - 1.f);
    outb[(long)dst * 64 + lane] = f32_to_bf16(v);
}

// ---------------------------------------------------------------------------
extern "C" void kernel_launch(void* const* d_in, const int* in_sizes, int n_in,
                              void* d_out, int out_size, void* d_ws, size_t ws_size,
                              hipStream_t stream) {
    const float* x        = (const float*)d_in[0];
    const int*   ei       = (const int*)d_in[1];
    const float* W1       = (const float*)d_in[2];
    const float* att_src1 = (const float*)d_in[3];
    const float* att_dst1 = (const float*)d_in[4];
    const float* b1       = (const float*)d_in[5];
    const float* W2       = (const float*)d_in[6];
    const float* att_src2 = (const float*)d_in[7];
    const float* att_dst2 = (const float*)d_in[8];
    const float* b2       = (const float*)d_in[9];
    const float* Wl       = (const float*)d_in[10];
    const float* bl       = (const float*)d_in[11];
    float* out = (float*)d_out;

    // workspace layout
    char* p = (char*)d_ws;
    ushort_t* h1b   = (ushort_t*)p; p += (long)MP * 512 * 2;
    ushort_t* out1b = (ushort_t*)p; p += (long)MP * 512 * 2;
    ushort_t* h2b   = (ushort_t*)p; p += (long)MP * 64 * 2;
    ushort_t* out2b = (ushort_t*)p; p += (long)MP * 64 * 2;
    float* as1 = (float*)p; p += (long)N_NODES * 8 * 4;
    float* ad1 = (float*)p; p += (long)N_NODES * 8 * 4;
    ushort_t* w1t = (ushort_t*)p; p += 512 * 512 * 2;
    ushort_t* w2t = (ushort_t*)p; p += 64 * 512 * 2;
    ushort_t* wlt = (ushort_t*)p; p += 512 * 64 * 2;
    int* csr_off = (int*)p; p += (N_NODES + 4) * 4;
    int* csr_cnt = (int*)p; p += N_NODES * 4;
    int* csr_eid = (int*)p; p += (long)E_TOT * 4;
    int* scan_p  = (int*)p; p += 256 * 4;

    const int BT = 256;
    dim3 blk(BT);
    const int NB_SCAN = (N_NODES + 255) / 256;   // 196

    // ---------------- CSR build ----------------
    fill_i32<<<256, blk, 0, stream>>>(csr_cnt, 0, N_NODES);
    count_deg<<<1024, blk, 0, stream>>>(ei, csr_cnt);
    scan_part<<<NB_SCAN, blk, 0, stream>>>(csr_cnt, scan_p, N_NODES);
    scan_top<<<1, blk, 0, stream>>>(scan_p, NB_SCAN);
    scan_final<<<NB_SCAN, blk, 0, stream>>>(csr_cnt, scan_p, csr_off, N_NODES);
    fill_i32<<<256, blk, 0, stream>>>(csr_cnt, 0, N_NODES);
    scatter_edges<<<1024, blk, 0, stream>>>(ei, csr_off, csr_cnt, csr_eid);

    // ---------------- weight conversions + pad-row zero fills ----------------
    cvt_w1t_bf16<<<512, blk, 0, stream>>>(W1, w1t);
    cvt_w2t_bf16<<<64, blk, 0, stream>>>(W2, w2t);
    cvt_wlt_bf16<<<64, blk, 0, stream>>>(Wl, wlt);
    fill_i32<<<12, blk, 0, stream>>>((int*)(out1b + (long)N_NODES * 512), 0,
                                     (MP - N_NODES) * 512 / 2);
    fill_i32<<<2, blk, 0, stream>>>((int*)(out2b + (long)N_NODES * 64), 0,
                                    (MP - N_NODES) * 64 / 2);

    // ---------------- layer 1: fused GEMM + attn dots ----------------
    {
        dim3 grid(2, MP / 64);
        gemm1_big<<<grid, blk, 0, stream>>>(x, w1t, att_src1, att_dst1,
                                            h1b, as1, ad1);
    }
    csr_agg8<<<(N_NODES * 64 + BT - 1) / BT, blk, 0, stream>>>(
        ei, csr_off, csr_eid, as1, ad1, h1b, b1, out1b);

    // ---------------- layer 2 (H=1) ----------------
    gemm2_mfma<<<MP / 128, blk, 0, stream>>>(out1b, w2t, h2b);
    attn_dots1<<<(N_NODES * 64 + BT - 1) / BT, blk, 0, stream>>>(h2b, att_src2, att_dst2,
                                                                 as1, ad1);
    csr_agg1<<<(N_NODES * 64 + BT - 1) / BT, blk, 0, stream>>>(
        ei, csr_off, csr_eid, as1, ad1, h2b, b2, out2b);

    // ---------------- final linear ----------------
    {
        dim3 grid(512 / 128, MP / 128);
        gemm3_mfma<<<grid, blk, 0, stream>>>(out2b, wlt, bl, out);
    }
}

// Round 9
// 371.412 us; speedup vs baseline: 6.2780x; 1.1076x over previous
//
#include <hip/hip_runtime.h>
#include <hip/hip_bf16.h>

// ---------------------------------------------------------------------------
// GAT 2-layer forward (PyG GATConv semantics, eval mode).
// R9: csr_agg gather unrolled x4 (4 outstanding loads/wave), CSR stores src
//     values directly (no eid->ei indirection), merged cvt/fill kernels
//     (18 -> 13 launches). gemm1/gemm2/gemm3 unchanged from R8.
// ---------------------------------------------------------------------------

#define N_NODES 50000
#define F_IN    500
#define H1      8
#define E_RAW   600000
#define E_TOT   (E_RAW + N_NODES)
#define NEG_SLOPE 0.2f

#define MP      50048      // N_NODES padded to multiple of 128
#define KP      512        // F_IN padded

typedef __attribute__((ext_vector_type(8))) short bf16x8;
typedef __attribute__((ext_vector_type(4))) float f32x4;
typedef unsigned short ushort_t;

__device__ __forceinline__ int edge_src(const int* ei, int e) {
    return (e < E_RAW) ? ei[e] : e - E_RAW;
}
__device__ __forceinline__ int edge_dst(const int* ei, int e) {
    return (e < E_RAW) ? ei[E_RAW + e] : e - E_RAW;
}

__device__ __forceinline__ unsigned short f32_to_bf16(float f) {
    unsigned int u = __float_as_uint(f);
    u += 0x7fffu + ((u >> 16) & 1u);       // RNE
    return (unsigned short)(u >> 16);
}
__device__ __forceinline__ float bf16_lo(unsigned int u) {
    return __uint_as_float(u << 16);
}
__device__ __forceinline__ float bf16_hi(unsigned int u) {
    return __uint_as_float(u & 0xffff0000u);
}

// ---------------- merged fill: zero csr_cnt + out1b/out2b pad rows ----------
__global__ void fill_misc(int* __restrict__ cnt, int* __restrict__ pad1,
                          int* __restrict__ pad2) {
    const int N1 = N_NODES;                       // cnt zeros
    const int N2 = (MP - N_NODES) * 512 / 2;      // out1b pad (ints)
    const int N3 = (MP - N_NODES) * 64 / 2;       // out2b pad (ints)
    int i = blockIdx.x * blockDim.x + threadIdx.x;
    int stride = gridDim.x * blockDim.x;
    for (; i < N1 + N2 + N3; i += stride) {
        if (i < N1) cnt[i] = 0;
        else if (i < N1 + N2) pad1[i - N1] = 0;
        else pad2[i - N1 - N2] = 0;
    }
}

// ---------------- CSR build ----------------
__global__ void count_deg(const int* __restrict__ ei, int* __restrict__ deg) {
    long i = blockIdx.x * (long)blockDim.x + threadIdx.x;
    long stride = (long)gridDim.x * blockDim.x;
    for (; i < E_TOT; i += stride) atomicAdd(&deg[edge_dst(ei, (int)i)], 1);
}

// 3-phase scan over n = 50000
__global__ void scan_part(const int* __restrict__ deg, int* __restrict__ part, int n) {
    __shared__ int sm[256];
    int i = blockIdx.x * 256 + threadIdx.x;
    sm[threadIdx.x] = (i < n) ? deg[i] : 0;
    __syncthreads();
    for (int d = 128; d >= 1; d >>= 1) {
        if (threadIdx.x < d) sm[threadIdx.x] += sm[threadIdx.x + d];
        __syncthreads();
    }
    if (threadIdx.x == 0) part[blockIdx.x] = sm[0];
}

__global__ void scan_top(int* __restrict__ part, int nb) {
    __shared__ int sm[256];
    int t = threadIdx.x;
    sm[t] = (t < nb) ? part[t] : 0;
    __syncthreads();
    for (int d = 1; d < 256; d <<= 1) {
        int v = (t >= d) ? sm[t - d] : 0;
        __syncthreads();
        sm[t] += v;
        __syncthreads();
    }
    if (t < nb) part[t] = (t == 0) ? 0 : sm[t - 1];   // exclusive
}

// writes off[] AND pos[] (scatter cursor copy)
__global__ void scan_final(const int* __restrict__ deg, const int* __restrict__ part,
                           int* __restrict__ off, int* __restrict__ pos, int n) {
    __shared__ int sm[256];
    int i = blockIdx.x * 256 + threadIdx.x;
    int v = (i < n) ? deg[i] : 0;
    sm[threadIdx.x] = v;
    __syncthreads();
    for (int d = 1; d < 256; d <<= 1) {
        int u = (threadIdx.x >= d) ? sm[threadIdx.x - d] : 0;
        __syncthreads();
        sm[threadIdx.x] += u;
        __syncthreads();
    }
    int excl = sm[threadIdx.x] - v + part[blockIdx.x];
    if (i < n) { off[i] = excl; pos[i] = excl; }
    if (i == n - 1) off[n] = excl + v;
}

// scatter SRC VALUES into dst-sorted array (no edge-id indirection)
__global__ void scatter_src(const int* __restrict__ ei, int* __restrict__ pos,
                            int* __restrict__ srcs) {
    long i = blockIdx.x * (long)blockDim.x + threadIdx.x;
    long stride = (long)gridDim.x * blockDim.x;
    for (; i < E_TOT; i += stride) {
        int e = (int)i;
        int s, d;
        if (e < E_RAW) { s = ei[e]; d = ei[E_RAW + e]; } else { s = d = e - E_RAW; }
        int p = atomicAdd(&pos[d], 1);
        srcs[p] = s;
    }
}

// ---------------- merged weight conversion ----------------
__global__ void cvt_weights(const float* __restrict__ W1, const float* __restrict__ W2,
                            const float* __restrict__ Wl, ushort_t* __restrict__ w1t,
                            ushort_t* __restrict__ w2t, ushort_t* __restrict__ wlt) {
    const int R1 = 512 * 256;          // w1t pairs
    const int R2 = 64 * 256;           // w2t pairs
    const int R3 = 512 * 32;           // wlt pairs
    int idx = blockIdx.x * blockDim.x + threadIdx.x;
    if (idx < R1) {
        int n = idx >> 8, k0 = (idx & 255) * 2;
        float v0 = (k0 < F_IN) ? W1[(long)k0 * 512 + n] : 0.f;
        float v1 = (k0 + 1 < F_IN) ? W1[(long)(k0 + 1) * 512 + n] : 0.f;
        ((unsigned int*)w1t)[idx] = (unsigned)f32_to_bf16(v0) |
                                    ((unsigned)f32_to_bf16(v1) << 16);
    } else if (idx < R1 + R2) {
        int k = idx - R1;
        int n = k >> 8, k0 = (k & 255) * 2;
        float v0 = W2[(long)k0 * 64 + n];
        float v1 = W2[(long)(k0 + 1) * 64 + n];
        ((unsigned int*)w2t)[k] = (unsigned)f32_to_bf16(v0) |
                                  ((unsigned)f32_to_bf16(v1) << 16);
    } else if (idx < R1 + R2 + R3) {
        int k = idx - R1 - R2;
        int n = k >> 5, k0 = (k & 31) * 2;
        float v0 = (n < F_IN) ? Wl[(long)k0 * F_IN + n] : 0.f;
        float v1 = (n < F_IN) ? Wl[(long)(k0 + 1) * F_IN + n] : 0.f;
        ((unsigned int*)wlt)[k] = (unsigned)f32_to_bf16(v0) |
                                  ((unsigned)f32_to_bf16(v1) << 16);
    }
}

// ---------------- GEMM1 (fused): h1b = bf16(x) @ w1t^T; a_s/a_d epilogue ----
__global__ __launch_bounds__(256, 4) void gemm1_big(
        const float* __restrict__ X, const ushort_t* __restrict__ Bt,
        const float* __restrict__ att_s, const float* __restrict__ att_d,
        ushort_t* __restrict__ H, float* __restrict__ a_s, float* __restrict__ a_d) {
    __shared__ ushort_t As[64 * 72];     // padded
    __shared__ ushort_t Bs[256 * 64];    // linear (gload_lds dest)
    int tid = threadIdx.x;
    int lane = tid & 63, wid = tid >> 6;
    int wrow = wid >> 1, wcol = wid & 1;
    int lrow = lane & 15, lkb = lane >> 4;
    int brow = blockIdx.y, bcol = blockIdx.x;

    f32x4 acc[2][8];
    const f32x4 zero = {0.f, 0.f, 0.f, 0.f};
    #pragma unroll
    for (int mi = 0; mi < 2; ++mi)
        #pragma unroll
        for (int ni = 0; ni < 8; ++ni) acc[mi][ni] = zero;

    int arow = tid >> 2;
    int akq = (tid & 3) * 16;
    long arow_g = (long)brow * 64 + arow;
    bool arow_ok = arow_g < N_NODES;
    const float* aG = X + arow_g * F_IN;
    ushort_t* aL = As + arow * 72 + akq;

    for (int k0 = 0; k0 < KP; k0 += 64) {
        #pragma unroll
        for (int i = 0; i < 8; ++i) {
            int slotL = i * 256 + tid;
            int n = slotL >> 3, s = slotL & 7;
            const ushort_t* g = Bt + ((long)(bcol * 256 + n)) * 512 + k0 +
                                ((s ^ (n & 7)) * 8);
            __builtin_amdgcn_global_load_lds(
                (const __attribute__((address_space(1))) void*)g,
                (__attribute__((address_space(3))) void*)(Bs + slotL * 8), 16, 0, 0);
        }
        float av[16];
        #pragma unroll
        for (int q = 0; q < 4; ++q) {
            int kk = k0 + akq + q * 4;
            float4 v = {0.f, 0.f, 0.f, 0.f};
            if (arow_ok && kk + 4 <= F_IN) v = *(const float4*)(aG + kk);
            av[q * 4 + 0] = v.x; av[q * 4 + 1] = v.y;
            av[q * 4 + 2] = v.z; av[q * 4 + 3] = v.w;
        }
        int4 apk0, apk1;
        #pragma unroll
        for (int q = 0; q < 4; ++q) {
            ((unsigned*)&apk0)[q] = (unsigned)f32_to_bf16(av[2 * q]) |
                                    ((unsigned)f32_to_bf16(av[2 * q + 1]) << 16);
            ((unsigned*)&apk1)[q] = (unsigned)f32_to_bf16(av[8 + 2 * q]) |
                                    ((unsigned)f32_to_bf16(av[9 + 2 * q]) << 16);
        }
        *(int4*)aL = apk0;
        *(int4*)(aL + 8) = apk1;
        __syncthreads();

        #pragma unroll
        for (int ks = 0; ks < 2; ++ks) {
            bf16x8 af[2], bfr[8];
            #pragma unroll
            for (int mi = 0; mi < 2; ++mi) {
                int row = wrow * 32 + mi * 16 + lrow;
                af[mi] = *(const bf16x8*)(As + row * 72 + ks * 32 + lkb * 8);
            }
            #pragma unroll
            for (int ni = 0; ni < 8; ++ni) {
                int n = wcol * 128 + ni * 16 + lrow;
                bfr[ni] = *(const bf16x8*)(Bs + n * 64 +
                                           (((ks * 4 + lkb) ^ (n & 7)) * 8));
            }
            #pragma unroll
            for (int mi = 0; mi < 2; ++mi)
                #pragma unroll
                for (int ni = 0; ni < 8; ++ni)
                    acc[mi][ni] = __builtin_amdgcn_mfma_f32_16x16x32_bf16(
                        af[mi], bfr[ni], acc[mi][ni], 0, 0, 0);
        }
        __syncthreads();
    }

    int hA = bcol * 4 + wcol * 2, hB = hA + 1;
    float asv[2][4], adv[2][4];
    #pragma unroll
    for (int j = 0; j < 4; ++j) {
        asv[0][j] = att_s[hA * 64 + j * 16 + lrow];
        asv[1][j] = att_s[hB * 64 + j * 16 + lrow];
        adv[0][j] = att_d[hA * 64 + j * 16 + lrow];
        adv[1][j] = att_d[hB * 64 + j * 16 + lrow];
    }

    #pragma unroll
    for (int mi = 0; mi < 2; ++mi) {
        #pragma unroll
        for (int reg = 0; reg < 4; ++reg) {
            long r = (long)brow * 64 + wrow * 32 + mi * 16 + lkb * 4 + reg;
            #pragma unroll
            for (int ni = 0; ni < 8; ++ni) {
                int c = bcol * 256 + wcol * 128 + ni * 16 + lrow;
                H[r * 512 + c] = f32_to_bf16(acc[mi][ni][reg]);
            }
            float sA = 0.f, dA = 0.f, sB = 0.f, dB = 0.f;
            #pragma unroll
            for (int j = 0; j < 4; ++j) {
                sA += acc[mi][j][reg] * asv[0][j];
                dA += acc[mi][j][reg] * adv[0][j];
                sB += acc[mi][j + 4][reg] * asv[1][j];
                dB += acc[mi][j + 4][reg] * adv[1][j];
            }
            #pragma unroll
            for (int mm = 8; mm >= 1; mm >>= 1) {
                sA += __shfl_xor(sA, mm);
                dA += __shfl_xor(dA, mm);
                sB += __shfl_xor(sB, mm);
                dB += __shfl_xor(dB, mm);
            }
            if (lrow == 0 && r < N_NODES) {
                a_s[r * 8 + hA] = sA;
                a_d[r * 8 + hA] = dA;
                a_s[r * 8 + hB] = sB;
                a_d[r * 8 + hB] = dB;
            }
        }
    }
}

// ---------------- GEMM2: h2b[MP][64] = out1b[MP][512] @ w2t[64][512]^T -----
#define LDP 72

__global__ __launch_bounds__(256) void gemm2_mfma(
        const ushort_t* __restrict__ A, const ushort_t* __restrict__ Bt,
        ushort_t* __restrict__ C) {
    __shared__ ushort_t As[128 * LDP];
    __shared__ ushort_t Bs[64 * LDP];
    int tid = threadIdx.x;
    int lane = tid & 63, wid = tid >> 6;
    int wrow = wid >> 1, wcol = wid & 1;
    int brow = blockIdx.x;

    f32x4 acc[4][2];
    const f32x4 zero = {0.f, 0.f, 0.f, 0.f};
    #pragma unroll
    for (int mi = 0; mi < 4; ++mi) { acc[mi][0] = zero; acc[mi][1] = zero; }

    int lrow = lane & 15, lkb = lane >> 4;

    for (int k0 = 0; k0 < 512; k0 += 64) {
        #pragma unroll
        for (int it = 0; it < 4; ++it) {
            int slot = tid + it * 256;
            int row = slot >> 3, seg = slot & 7;
            *(int4*)(As + row * LDP + seg * 8) =
                *(const int4*)(A + ((long)(brow * 128 + row)) * 512 + k0 + seg * 8);
        }
        #pragma unroll
        for (int it = 0; it < 2; ++it) {
            int slot = tid + it * 256;
            int row = slot >> 3, seg = slot & 7;
            *(int4*)(Bs + row * LDP + seg * 8) =
                *(const int4*)(Bt + (long)row * 512 + k0 + seg * 8);
        }
        __syncthreads();
        #pragma unroll
        for (int ks = 0; ks < 2; ++ks) {
            bf16x8 af[4], bfr[2];
            #pragma unroll
            for (int mi = 0; mi < 4; ++mi)
                af[mi] = *(const bf16x8*)(As + (wrow * 64 + mi * 16 + lrow) * LDP +
                                          ks * 32 + lkb * 8);
            #pragma unroll
            for (int ni = 0; ni < 2; ++ni)
                bfr[ni] = *(const bf16x8*)(Bs + (wcol * 32 + ni * 16 + lrow) * LDP +
                                           ks * 32 + lkb * 8);
            #pragma unroll
            for (int mi = 0; mi < 4; ++mi)
                #pragma unroll
                for (int ni = 0; ni < 2; ++ni)
                    acc[mi][ni] = __builtin_amdgcn_mfma_f32_16x16x32_bf16(
                        af[mi], bfr[ni], acc[mi][ni], 0, 0, 0);
        }
        __syncthreads();
    }

    #pragma unroll
    for (int mi = 0; mi < 4; ++mi)
        #pragma unroll
        for (int reg = 0; reg < 4; ++reg) {
            int r = brow * 128 + wrow * 64 + mi * 16 + lkb * 4 + reg;
            #pragma unroll
            for (int ni = 0; ni < 2; ++ni) {
                int c = wcol * 32 + ni * 16 + lrow;
                C[(long)r * 64 + c] = f32_to_bf16(acc[mi][ni][reg]);
            }
        }
}

// ---------------- GEMM3: out[N][500] = out2b[MP][64] @ wlt[512][64]^T + bl --
__global__ __launch_bounds__(256) void gemm3_mfma(
        const ushort_t* __restrict__ A, const ushort_t* __restrict__ Bt,
        const float* __restrict__ bias, float* __restrict__ C) {
    __shared__ ushort_t As[128 * LDP];
    __shared__ ushort_t Bs[128 * LDP];
    int tid = threadIdx.x;
    int lane = tid & 63, wid = tid >> 6;
    int wrow = wid >> 1, wcol = wid & 1;
    int brow = blockIdx.y, bcol = blockIdx.x;

    f32x4 acc[4][4];
    const f32x4 zero = {0.f, 0.f, 0.f, 0.f};
    #pragma unroll
    for (int mi = 0; mi < 4; ++mi)
        #pragma unroll
        for (int ni = 0; ni < 4; ++ni) acc[mi][ni] = zero;

    int lrow = lane & 15, lkb = lane >> 4;

    #pragma unroll
    for (int it = 0; it < 4; ++it) {
        int slot = tid + it * 256;
        int row = slot >> 3, seg = slot & 7;
        *(int4*)(As + row * LDP + seg * 8) =
            *(const int4*)(A + ((long)(brow * 128 + row)) * 64 + seg * 8);
        *(int4*)(Bs + row * LDP + seg * 8) =
            *(const int4*)(Bt + ((long)(bcol * 128 + row)) * 64 + seg * 8);
    }
    __syncthreads();
    #pragma unroll
    for (int ks = 0; ks < 2; ++ks) {
        bf16x8 af[4], bfr[4];
        #pragma unroll
        for (int mi = 0; mi < 4; ++mi)
            af[mi] = *(const bf16x8*)(As + (wrow * 64 + mi * 16 + lrow) * LDP +
                                      ks * 32 + lkb * 8);
        #pragma unroll
        for (int ni = 0; ni < 4; ++ni)
            bfr[ni] = *(const bf16x8*)(Bs + (wcol * 64 + ni * 16 + lrow) * LDP +
                                       ks * 32 + lkb * 8);
        #pragma unroll
        for (int mi = 0; mi < 4; ++mi)
            #pragma unroll
            for (int ni = 0; ni < 4; ++ni)
                acc[mi][ni] = __builtin_amdgcn_mfma_f32_16x16x32_bf16(
                    af[mi], bfr[ni], acc[mi][ni], 0, 0, 0);
    }

    #pragma unroll
    for (int mi = 0; mi < 4; ++mi)
        #pragma unroll
        for (int reg = 0; reg < 4; ++reg) {
            int r = brow * 128 + wrow * 64 + mi * 16 + lkb * 4 + reg;
            if (r >= N_NODES) continue;
            #pragma unroll
            for (int ni = 0; ni < 4; ++ni) {
                int c = bcol * 128 + wcol * 64 + ni * 16 + lrow;
                if (c < F_IN) C[(long)r * F_IN + c] = acc[mi][ni][reg] + bias[c];
            }
        }
}

// ---------------- attention dots L2 (H=1): wave per node ----------------
__global__ void attn_dots1(const ushort_t* __restrict__ hb, const float* __restrict__ att_s,
                           const float* __restrict__ att_d, float* __restrict__ a_s,
                           float* __restrict__ a_d) {
    long wid = (blockIdx.x * (long)blockDim.x + threadIdx.x) >> 6;
    int lane = threadIdx.x & 63;
    if (wid >= N_NODES) return;
    int n = (int)wid;
    float f = __uint_as_float(((unsigned)hb[(long)n * 64 + lane]) << 16);
    float s = f * att_s[lane], d = f * att_d[lane];
    #pragma unroll
    for (int m = 32; m >= 1; m >>= 1) { s += __shfl_xor(s, m); d += __shfl_xor(d, m); }
    if (lane == 0) { a_s[n] = s; a_d[n] = d; }
}

// ---------------- csr_agg8: wave per dst, 8 heads, x4-unrolled gather -------
__global__ void csr_agg8(const int* __restrict__ srcs, const int* __restrict__ off,
                         const float* __restrict__ a_s, const float* __restrict__ a_d,
                         const ushort_t* __restrict__ hb, const float* __restrict__ bias,
                         ushort_t* __restrict__ outb) {
    __shared__ float alds[4 * 64 * 9];       // per-wave [64 edges][9]
    long wid = (blockIdx.x * (long)blockDim.x + threadIdx.x) >> 6;
    int lane = threadIdx.x & 63;
    if (wid >= N_NODES) return;
    int dst = (int)wid;
    float* aw = alds + (threadIdx.x >> 6) * (64 * 9);
    int b = off[dst], e2 = off[dst + 1];
    int deg = e2 - b;
    int myh = lane >> 3;

    float ad[8];
    {
        const float* adp = a_d + (long)dst * 8;
        #pragma unroll
        for (int hh = 0; hh < 8; ++hh) ad[hh] = adp[hh];
    }

    float acc8[8];
    #pragma unroll
    for (int q = 0; q < 8; ++q) acc8[q] = 0.f;

    if (deg <= 64) {
        // ---- one-pass fast path ----
        bool act = lane < deg;
        int src = act ? srcs[b + lane] : 0;
        const float* asp = a_s + (long)src * 8;
        float x[8];
        #pragma unroll
        for (int hh = 0; hh < 8; ++hh) {
            float v = act ? (asp[hh] + ad[hh]) : -1e30f;
            x[hh] = v > 0.f ? v : NEG_SLOPE * v;
        }
        #pragma unroll
        for (int hh = 0; hh < 8; ++hh) {
            float cm = x[hh];
            #pragma unroll
            for (int d2 = 32; d2 >= 1; d2 >>= 1) cm = fmaxf(cm, __shfl_xor(cm, d2));
            float ce = act ? __expf(x[hh] - cm) : 0.f;
            float ss = ce;
            #pragma unroll
            for (int d2 = 32; d2 >= 1; d2 >>= 1) ss += __shfl_xor(ss, d2);
            aw[lane * 9 + hh] = ce * (1.f / (ss + 1e-16f));
        }
        asm volatile("s_waitcnt lgkmcnt(0)" ::: "memory");
        int j = 0;
        for (; j + 4 <= deg; j += 4) {
            int s0 = __shfl(src, j),     s1 = __shfl(src, j + 1);
            int s2 = __shfl(src, j + 2), s3 = __shfl(src, j + 3);
            float a0 = aw[(j) * 9 + myh],     a1 = aw[(j + 1) * 9 + myh];
            float a2 = aw[(j + 2) * 9 + myh], a3 = aw[(j + 3) * 9 + myh];
            int4 h0 = *(const int4*)(hb + (long)s0 * 512 + lane * 8);
            int4 h1 = *(const int4*)(hb + (long)s1 * 512 + lane * 8);
            int4 h2 = *(const int4*)(hb + (long)s2 * 512 + lane * 8);
            int4 h3 = *(const int4*)(hb + (long)s3 * 512 + lane * 8);
            #pragma unroll
            for (int q = 0; q < 4; ++q) {
                unsigned u0 = ((const unsigned*)&h0)[q];
                unsigned u1 = ((const unsigned*)&h1)[q];
                unsigned u2 = ((const unsigned*)&h2)[q];
                unsigned u3 = ((const unsigned*)&h3)[q];
                acc8[2 * q]     += a0 * bf16_lo(u0) + a1 * bf16_lo(u1) +
                                   a2 * bf16_lo(u2) + a3 * bf16_lo(u3);
                acc8[2 * q + 1] += a0 * bf16_hi(u0) + a1 * bf16_hi(u1) +
                                   a2 * bf16_hi(u2) + a3 * bf16_hi(u3);
            }
        }
        for (; j < deg; ++j) {
            int sj = __shfl(src, j);
            float aj = aw[j * 9 + myh];
            int4 hv = *(const int4*)(hb + (long)sj * 512 + lane * 8);
            #pragma unroll
            for (int q = 0; q < 4; ++q) {
                unsigned u = ((const unsigned*)&hv)[q];
                acc8[2 * q]     += aj * bf16_lo(u);
                acc8[2 * q + 1] += aj * bf16_hi(u);
            }
        }
    } else {
        // ---- general chunked two-pass path ----
        float m[8], ssum[8];
        #pragma unroll
        for (int hh = 0; hh < 8; ++hh) { m[hh] = -1e30f; ssum[hh] = 0.f; }

        for (int c = b; c < e2; c += 64) {
            int i = c + lane;
            bool act = i < e2;
            int src = act ? srcs[i] : 0;
            float x[8];
            {
                const float* asp = a_s + (long)src * 8;
                #pragma unroll
                for (int hh = 0; hh < 8; ++hh) {
                    float v = act ? (asp[hh] + ad[hh]) : -1e30f;
                    x[hh] = v > 0.f ? v : NEG_SLOPE * v;
                }
            }
            #pragma unroll
            for (int hh = 0; hh < 8; ++hh) {
                float cm = x[hh];
                #pragma unroll
                for (int d2 = 32; d2 >= 1; d2 >>= 1) cm = fmaxf(cm, __shfl_xor(cm, d2));
                float nm = fmaxf(m[hh], cm);
                float ce = act ? __expf(x[hh] - nm) : 0.f;
                #pragma unroll
                for (int d2 = 32; d2 >= 1; d2 >>= 1) ce += __shfl_xor(ce, d2);
                ssum[hh] = ssum[hh] * __expf(m[hh] - nm) + ce;
                m[hh] = nm;
            }
        }
        float inv[8];
        #pragma unroll
        for (int hh = 0; hh < 8; ++hh) inv[hh] = 1.f / (ssum[hh] + 1e-16f);

        for (int c = b; c < e2; c += 64) {
            int i = c + lane;
            bool act = i < e2;
            int src = act ? srcs[i] : 0;
            {
                const float* asp = a_s + (long)src * 8;
                #pragma unroll
                for (int hh = 0; hh < 8; ++hh) {
                    float v = act ? (asp[hh] + ad[hh]) : -1e30f;
                    v = v > 0.f ? v : NEG_SLOPE * v;
                    aw[lane * 9 + hh] = act ? __expf(v - m[hh]) * inv[hh] : 0.f;
                }
            }
            asm volatile("s_waitcnt lgkmcnt(0)" ::: "memory");
            int cnt = min(64, e2 - c);
            for (int j = 0; j < cnt; ++j) {
                int sj = __shfl(src, j);
                float aj = aw[j * 9 + myh];
                int4 hv = *(const int4*)(hb + (long)sj * 512 + lane * 8);
                #pragma unroll
                for (int q = 0; q < 4; ++q) {
                    unsigned u = ((const unsigned*)&hv)[q];
                    acc8[2 * q]     += aj * bf16_lo(u);
                    acc8[2 * q + 1] += aj * bf16_hi(u);
                }
            }
            asm volatile("s_waitcnt lgkmcnt(0)" ::: "memory");
        }
    }

    const float* bp = bias + lane * 8;
    int4 st;
    #pragma unroll
    for (int q = 0; q < 8; ++q) {
        float v = acc8[q] + bp[q];
        v = v > 0.f ? v : (__expf(v) - 1.f);
        ((ushort_t*)&st)[q] = f32_to_bf16(v);
    }
    *(int4*)(outb + (long)dst * 512 + lane * 8) = st;
}

// ---------------- csr_agg1: wave per dst, H=1, x4-unrolled gather -----------
__global__ void csr_agg1(const int* __restrict__ srcs, const int* __restrict__ off,
                         const float* __restrict__ a_s, const float* __restrict__ a_d,
                         const ushort_t* __restrict__ hb, const float* __restrict__ bias,
                         ushort_t* __restrict__ outb) {
    long wid = (blockIdx.x * (long)blockDim.x + threadIdx.x) >> 6;
    int lane = threadIdx.x & 63;
    if (wid >= N_NODES) return;
    int dst = (int)wid;
    int b = off[dst], e2 = off[dst + 1];
    int deg = e2 - b;
    float ad = a_d[dst];
    float acc = 0.f;

    if (deg <= 64) {
        bool act = lane < deg;
        int src = act ? srcs[b + lane] : 0;
        float v = act ? (a_s[src] + ad) : -1e30f;
        float xx = v > 0.f ? v : NEG_SLOPE * v;
        float cm = xx;
        #pragma unroll
        for (int d2 = 32; d2 >= 1; d2 >>= 1) cm = fmaxf(cm, __shfl_xor(cm, d2));
        float alpha = act ? __expf(xx - cm) : 0.f;
        float ss = alpha;
        #pragma unroll
        for (int d2 = 32; d2 >= 1; d2 >>= 1) ss += __shfl_xor(ss, d2);
        alpha *= 1.f / (ss + 1e-16f);

        int j = 0;
        for (; j + 4 <= deg; j += 4) {
            int s0 = __shfl(src, j),     s1 = __shfl(src, j + 1);
            int s2 = __shfl(src, j + 2), s3 = __shfl(src, j + 3);
            float a0 = __shfl(alpha, j),     a1 = __shfl(alpha, j + 1);
            float a2 = __shfl(alpha, j + 2), a3 = __shfl(alpha, j + 3);
            float f0 = __uint_as_float(((unsigned)hb[(long)s0 * 64 + lane]) << 16);
            float f1 = __uint_as_float(((unsigned)hb[(long)s1 * 64 + lane]) << 16);
            float f2 = __uint_as_float(((unsigned)hb[(long)s2 * 64 + lane]) << 16);
            float f3 = __uint_as_float(((unsigned)hb[(long)s3 * 64 + lane]) << 16);
            acc += a0 * f0 + a1 * f1 + a2 * f2 + a3 * f3;
        }
        for (; j < deg; ++j) {
            int sj = __shfl(src, j);
            float aj = __shfl(alpha, j);
            acc += aj * __uint_as_float(((unsigned)hb[(long)sj * 64 + lane]) << 16);
        }
    } else {
        float m = -1e30f, ssum = 0.f;
        for (int c = b; c < e2; c += 64) {
            int i = c + lane;
            bool act = i < e2;
            int src = act ? srcs[i] : 0;
            float v = act ? (a_s[src] + ad) : -1e30f;
            float xx = v > 0.f ? v : NEG_SLOPE * v;
            float cm = xx;
            #pragma unroll
            for (int d2 = 32; d2 >= 1; d2 >>= 1) cm = fmaxf(cm, __shfl_xor(cm, d2));
            float nm = fmaxf(m, cm);
            float ce = act ? __expf(xx - nm) : 0.f;
            #pragma unroll
            for (int d2 = 32; d2 >= 1; d2 >>= 1) ce += __shfl_xor(ce, d2);
            ssum = ssum * __expf(m - nm) + ce;
            m = nm;
        }
        float inv = 1.f / (ssum + 1e-16f);
        for (int c = b; c < e2; c += 64) {
            int i = c + lane;
            bool act = i < e2;
            int src = act ? srcs[i] : 0;
            float alpha = 0.f;
            if (act) {
                float v = a_s[src] + ad;
                v = v > 0.f ? v : NEG_SLOPE * v;
                alpha = __expf(v - m) * inv;
            }
            int cnt = min(64, e2 - c);
            for (int j = 0; j < cnt; ++j) {
                int sj = __shfl(src, j);
                float aj = __shfl(alpha, j);
                acc += aj * __uint_as_float(((unsigned)hb[(long)sj * 64 + lane]) << 16);
            }
        }
    }
    float v = acc + bias[lane];
    v = v > 0.f ? v : (__expf(v) - 1.f);
    outb[(long)dst * 64 + lane] = f32_to_bf16(v);
}

// ---------------------------------------------------------------------------
extern "C" void kernel_launch(void* const* d_in, const int* in_sizes, int n_in,
                              void* d_out, int out_size, void* d_ws, size_t ws_size,
                              hipStream_t stream) {
    const float* x        = (const float*)d_in[0];
    const int*   ei       = (const int*)d_in[1];
    const float* W1       = (const float*)d_in[2];
    const float* att_src1 = (const float*)d_in[3];
    const float* att_dst1 = (const float*)d_in[4];
    const float* b1       = (const float*)d_in[5];
    const float* W2       = (const float*)d_in[6];
    const float* att_src2 = (const float*)d_in[7];
    const float* att_dst2 = (const float*)d_in[8];
    const float* b2       = (const float*)d_in[9];
    const float* Wl       = (const float*)d_in[10];
    const float* bl       = (const float*)d_in[11];
    float* out = (float*)d_out;

    // workspace layout
    char* p = (char*)d_ws;
    ushort_t* h1b   = (ushort_t*)p; p += (long)MP * 512 * 2;
    ushort_t* out1b = (ushort_t*)p; p += (long)MP * 512 * 2;
    ushort_t* h2b   = (ushort_t*)p; p += (long)MP * 64 * 2;
    ushort_t* out2b = (ushort_t*)p; p += (long)MP * 64 * 2;
    float* as1 = (float*)p; p += (long)N_NODES * 8 * 4;
    float* ad1 = (float*)p; p += (long)N_NODES * 8 * 4;
    ushort_t* w1t = (ushort_t*)p; p += 512 * 512 * 2;
    ushort_t* w2t = (ushort_t*)p; p += 64 * 512 * 2;
    ushort_t* wlt = (ushort_t*)p; p += 512 * 64 * 2;
    int* csr_off = (int*)p; p += (N_NODES + 4) * 4;
    int* csr_cnt = (int*)p; p += N_NODES * 4;
    int* csr_pos = (int*)p; p += N_NODES * 4;
    int* csr_src = (int*)p; p += (long)E_TOT * 4;
    int* scan_p  = (int*)p; p += 256 * 4;

    const int BT = 256;
    dim3 blk(BT);
    const int NB_SCAN = (N_NODES + 255) / 256;   // 196

    // ---------------- CSR build + fills ----------------
    fill_misc<<<256, blk, 0, stream>>>(csr_cnt, (int*)(out1b + (long)N_NODES * 512),
                                       (int*)(out2b + (long)N_NODES * 64));
    count_deg<<<1024, blk, 0, stream>>>(ei, csr_cnt);
    scan_part<<<NB_SCAN, blk, 0, stream>>>(csr_cnt, scan_p, N_NODES);
    scan_top<<<1, blk, 0, stream>>>(scan_p, NB_SCAN);
    scan_final<<<NB_SCAN, blk, 0, stream>>>(csr_cnt, scan_p, csr_off, csr_pos, N_NODES);
    scatter_src<<<1024, blk, 0, stream>>>(ei, csr_pos, csr_src);

    // ---------------- weight conversions ----------------
    cvt_weights<<<640, blk, 0, stream>>>(W1, W2, Wl, w1t, w2t, wlt);

    // ---------------- layer 1: fused GEMM + attn dots ----------------
    {
        dim3 grid(2, MP / 64);
        gemm1_big<<<grid, blk, 0, stream>>>(x, w1t, att_src1, att_dst1,
                                            h1b, as1, ad1);
    }
    csr_agg8<<<(N_NODES * 64 + BT - 1) / BT, blk, 0, stream>>>(
        csr_src, csr_off, as1, ad1, h1b, b1, out1b);

    // ---------------- layer 2 (H=1) ----------------
    gemm2_mfma<<<MP / 128, blk, 0, stream>>>(out1b, w2t, h2b);
    attn_dots1<<<(N_NODES * 64 + BT - 1) / BT, blk, 0, stream>>>(h2b, att_src2, att_dst2,
                                                                 as1, ad1);
    csr_agg1<<<(N_NODES * 64 + BT - 1) / BT, blk, 0, stream>>>(
        csr_src, csr_off, as1, ad1, h2b, b2, out2b);

    // ---------------- final linear ----------------
    {
        dim3 grid(512 / 128, MP / 128);
        gemm3_mfma<<<grid, blk, 0, stream>>>(out2b, wlt, bl, out);
    }
}

// Round 10
// 368.273 us; speedup vs baseline: 6.3315x; 1.0085x over previous
//
#include <hip/hip_runtime.h>
#include <hip/hip_bf16.h>

// ---------------------------------------------------------------------------
// GAT 2-layer forward (PyG GATConv semantics, eval mode).
// R10: csr_agg8 softmax-lite (single shared-max reduce across 8 heads);
//      gemm1 1-D grid with pair swizzle (both column-blocks of a row panel
//      land on the same XCD -> A-panel L2 reuse). Rest unchanged from R9.
// ---------------------------------------------------------------------------

#define N_NODES 50000
#define F_IN    500
#define H1      8
#define E_RAW   600000
#define E_TOT   (E_RAW + N_NODES)
#define NEG_SLOPE 0.2f

#define MP      50048      // N_NODES padded to multiple of 128
#define KP      512        // F_IN padded

typedef __attribute__((ext_vector_type(8))) short bf16x8;
typedef __attribute__((ext_vector_type(4))) float f32x4;
typedef unsigned short ushort_t;

__device__ __forceinline__ int edge_dst(const int* ei, int e) {
    return (e < E_RAW) ? ei[E_RAW + e] : e - E_RAW;
}

__device__ __forceinline__ unsigned short f32_to_bf16(float f) {
    unsigned int u = __float_as_uint(f);
    u += 0x7fffu + ((u >> 16) & 1u);       // RNE
    return (unsigned short)(u >> 16);
}
__device__ __forceinline__ float bf16_lo(unsigned int u) {
    return __uint_as_float(u << 16);
}
__device__ __forceinline__ float bf16_hi(unsigned int u) {
    return __uint_as_float(u & 0xffff0000u);
}

// ---------------- merged fill: zero csr_cnt + out1b/out2b pad rows ----------
__global__ void fill_misc(int* __restrict__ cnt, int* __restrict__ pad1,
                          int* __restrict__ pad2) {
    const int N1 = N_NODES;
    const int N2 = (MP - N_NODES) * 512 / 2;
    const int N3 = (MP - N_NODES) * 64 / 2;
    int i = blockIdx.x * blockDim.x + threadIdx.x;
    int stride = gridDim.x * blockDim.x;
    for (; i < N1 + N2 + N3; i += stride) {
        if (i < N1) cnt[i] = 0;
        else if (i < N1 + N2) pad1[i - N1] = 0;
        else pad2[i - N1 - N2] = 0;
    }
}

// ---------------- CSR build ----------------
__global__ void count_deg(const int* __restrict__ ei, int* __restrict__ deg) {
    long i = blockIdx.x * (long)blockDim.x + threadIdx.x;
    long stride = (long)gridDim.x * blockDim.x;
    for (; i < E_TOT; i += stride) atomicAdd(&deg[edge_dst(ei, (int)i)], 1);
}

__global__ void scan_part(const int* __restrict__ deg, int* __restrict__ part, int n) {
    __shared__ int sm[256];
    int i = blockIdx.x * 256 + threadIdx.x;
    sm[threadIdx.x] = (i < n) ? deg[i] : 0;
    __syncthreads();
    for (int d = 128; d >= 1; d >>= 1) {
        if (threadIdx.x < d) sm[threadIdx.x] += sm[threadIdx.x + d];
        __syncthreads();
    }
    if (threadIdx.x == 0) part[blockIdx.x] = sm[0];
}

__global__ void scan_top(int* __restrict__ part, int nb) {
    __shared__ int sm[256];
    int t = threadIdx.x;
    sm[t] = (t < nb) ? part[t] : 0;
    __syncthreads();
    for (int d = 1; d < 256; d <<= 1) {
        int v = (t >= d) ? sm[t - d] : 0;
        __syncthreads();
        sm[t] += v;
        __syncthreads();
    }
    if (t < nb) part[t] = (t == 0) ? 0 : sm[t - 1];   // exclusive
}

__global__ void scan_final(const int* __restrict__ deg, const int* __restrict__ part,
                           int* __restrict__ off, int* __restrict__ pos, int n) {
    __shared__ int sm[256];
    int i = blockIdx.x * 256 + threadIdx.x;
    int v = (i < n) ? deg[i] : 0;
    sm[threadIdx.x] = v;
    __syncthreads();
    for (int d = 1; d < 256; d <<= 1) {
        int u = (threadIdx.x >= d) ? sm[threadIdx.x - d] : 0;
        __syncthreads();
        sm[threadIdx.x] += u;
        __syncthreads();
    }
    int excl = sm[threadIdx.x] - v + part[blockIdx.x];
    if (i < n) { off[i] = excl; pos[i] = excl; }
    if (i == n - 1) off[n] = excl + v;
}

__global__ void scatter_src(const int* __restrict__ ei, int* __restrict__ pos,
                            int* __restrict__ srcs) {
    long i = blockIdx.x * (long)blockDim.x + threadIdx.x;
    long stride = (long)gridDim.x * blockDim.x;
    for (; i < E_TOT; i += stride) {
        int e = (int)i;
        int s, d;
        if (e < E_RAW) { s = ei[e]; d = ei[E_RAW + e]; } else { s = d = e - E_RAW; }
        int p = atomicAdd(&pos[d], 1);
        srcs[p] = s;
    }
}

// ---------------- merged weight conversion ----------------
__global__ void cvt_weights(const float* __restrict__ W1, const float* __restrict__ W2,
                            const float* __restrict__ Wl, ushort_t* __restrict__ w1t,
                            ushort_t* __restrict__ w2t, ushort_t* __restrict__ wlt) {
    const int R1 = 512 * 256;
    const int R2 = 64 * 256;
    const int R3 = 512 * 32;
    int idx = blockIdx.x * blockDim.x + threadIdx.x;
    if (idx < R1) {
        int n = idx >> 8, k0 = (idx & 255) * 2;
        float v0 = (k0 < F_IN) ? W1[(long)k0 * 512 + n] : 0.f;
        float v1 = (k0 + 1 < F_IN) ? W1[(long)(k0 + 1) * 512 + n] : 0.f;
        ((unsigned int*)w1t)[idx] = (unsigned)f32_to_bf16(v0) |
                                    ((unsigned)f32_to_bf16(v1) << 16);
    } else if (idx < R1 + R2) {
        int k = idx - R1;
        int n = k >> 8, k0 = (k & 255) * 2;
        float v0 = W2[(long)k0 * 64 + n];
        float v1 = W2[(long)(k0 + 1) * 64 + n];
        ((unsigned int*)w2t)[k] = (unsigned)f32_to_bf16(v0) |
                                  ((unsigned)f32_to_bf16(v1) << 16);
    } else if (idx < R1 + R2 + R3) {
        int k = idx - R1 - R2;
        int n = k >> 5, k0 = (k & 31) * 2;
        float v0 = (n < F_IN) ? Wl[(long)k0 * F_IN + n] : 0.f;
        float v1 = (n < F_IN) ? Wl[(long)(k0 + 1) * F_IN + n] : 0.f;
        ((unsigned int*)wlt)[k] = (unsigned)f32_to_bf16(v0) |
                                  ((unsigned)f32_to_bf16(v1) << 16);
    }
}

// ---------------- GEMM1 (fused): h1b = bf16(x) @ w1t^T; a_s/a_d epilogue ----
// 1-D grid of 1564 with pair swizzle: blocks (bcol=0,1) of the same brow are
// 8 dispatch slots apart -> same XCD -> A-panel read hits L2 the second time.
__global__ __launch_bounds__(256, 4) void gemm1_big(
        const float* __restrict__ X, const ushort_t* __restrict__ Bt,
        const float* __restrict__ att_s, const float* __restrict__ att_d,
        ushort_t* __restrict__ H, float* __restrict__ a_s, float* __restrict__ a_d) {
    __shared__ ushort_t As[64 * 72];
    __shared__ ushort_t Bs[256 * 64];
    int tid = threadIdx.x;
    int lane = tid & 63, wid = tid >> 6;
    int wrow = wid >> 1, wcol = wid & 1;
    int lrow = lane & 15, lkb = lane >> 4;

    // pair swizzle: 97 groups of 16 cover rows 0..775; 12-block tail.
    int bid = blockIdx.x;
    int brow, bcol;
    if (bid < 1552) {
        int g = bid >> 4, r = bid & 15;
        brow = g * 8 + (r & 7);
        bcol = r >> 3;
    } else {
        int t = bid - 1552;
        brow = 776 + (t >> 1);
        bcol = t & 1;
    }

    f32x4 acc[2][8];
    const f32x4 zero = {0.f, 0.f, 0.f, 0.f};
    #pragma unroll
    for (int mi = 0; mi < 2; ++mi)
        #pragma unroll
        for (int ni = 0; ni < 8; ++ni) acc[mi][ni] = zero;

    int arow = tid >> 2;
    int akq = (tid & 3) * 16;
    long arow_g = (long)brow * 64 + arow;
    bool arow_ok = arow_g < N_NODES;
    const float* aG = X + arow_g * F_IN;
    ushort_t* aL = As + arow * 72 + akq;

    for (int k0 = 0; k0 < KP; k0 += 64) {
        #pragma unroll
        for (int i = 0; i < 8; ++i) {
            int slotL = i * 256 + tid;
            int n = slotL >> 3, s = slotL & 7;
            const ushort_t* g = Bt + ((long)(bcol * 256 + n)) * 512 + k0 +
                                ((s ^ (n & 7)) * 8);
            __builtin_amdgcn_global_load_lds(
                (const __attribute__((address_space(1))) void*)g,
                (__attribute__((address_space(3))) void*)(Bs + slotL * 8), 16, 0, 0);
        }
        float av[16];
        #pragma unroll
        for (int q = 0; q < 4; ++q) {
            int kk = k0 + akq + q * 4;
            float4 v = {0.f, 0.f, 0.f, 0.f};
            if (arow_ok && kk + 4 <= F_IN) v = *(const float4*)(aG + kk);
            av[q * 4 + 0] = v.x; av[q * 4 + 1] = v.y;
            av[q * 4 + 2] = v.z; av[q * 4 + 3] = v.w;
        }
        int4 apk0, apk1;
        #pragma unroll
        for (int q = 0; q < 4; ++q) {
            ((unsigned*)&apk0)[q] = (unsigned)f32_to_bf16(av[2 * q]) |
                                    ((unsigned)f32_to_bf16(av[2 * q + 1]) << 16);
            ((unsigned*)&apk1)[q] = (unsigned)f32_to_bf16(av[8 + 2 * q]) |
                                    ((unsigned)f32_to_bf16(av[9 + 2 * q]) << 16);
        }
        *(int4*)aL = apk0;
        *(int4*)(aL + 8) = apk1;
        __syncthreads();

        #pragma unroll
        for (int ks = 0; ks < 2; ++ks) {
            bf16x8 af[2], bfr[8];
            #pragma unroll
            for (int mi = 0; mi < 2; ++mi) {
                int row = wrow * 32 + mi * 16 + lrow;
                af[mi] = *(const bf16x8*)(As + row * 72 + ks * 32 + lkb * 8);
            }
            #pragma unroll
            for (int ni = 0; ni < 8; ++ni) {
                int n = wcol * 128 + ni * 16 + lrow;
                bfr[ni] = *(const bf16x8*)(Bs + n * 64 +
                                           (((ks * 4 + lkb) ^ (n & 7)) * 8));
            }
            #pragma unroll
            for (int mi = 0; mi < 2; ++mi)
                #pragma unroll
                for (int ni = 0; ni < 8; ++ni)
                    acc[mi][ni] = __builtin_amdgcn_mfma_f32_16x16x32_bf16(
                        af[mi], bfr[ni], acc[mi][ni], 0, 0, 0);
        }
        __syncthreads();
    }

    int hA = bcol * 4 + wcol * 2, hB = hA + 1;
    float asv[2][4], adv[2][4];
    #pragma unroll
    for (int j = 0; j < 4; ++j) {
        asv[0][j] = att_s[hA * 64 + j * 16 + lrow];
        asv[1][j] = att_s[hB * 64 + j * 16 + lrow];
        adv[0][j] = att_d[hA * 64 + j * 16 + lrow];
        adv[1][j] = att_d[hB * 64 + j * 16 + lrow];
    }

    #pragma unroll
    for (int mi = 0; mi < 2; ++mi) {
        #pragma unroll
        for (int reg = 0; reg < 4; ++reg) {
            long r = (long)brow * 64 + wrow * 32 + mi * 16 + lkb * 4 + reg;
            #pragma unroll
            for (int ni = 0; ni < 8; ++ni) {
                int c = bcol * 256 + wcol * 128 + ni * 16 + lrow;
                H[r * 512 + c] = f32_to_bf16(acc[mi][ni][reg]);
            }
            float sA = 0.f, dA = 0.f, sB = 0.f, dB = 0.f;
            #pragma unroll
            for (int j = 0; j < 4; ++j) {
                sA += acc[mi][j][reg] * asv[0][j];
                dA += acc[mi][j][reg] * adv[0][j];
                sB += acc[mi][j + 4][reg] * asv[1][j];
                dB += acc[mi][j + 4][reg] * adv[1][j];
            }
            #pragma unroll
            for (int mm = 8; mm >= 1; mm >>= 1) {
                sA += __shfl_xor(sA, mm);
                dA += __shfl_xor(dA, mm);
                sB += __shfl_xor(sB, mm);
                dB += __shfl_xor(dB, mm);
            }
            if (lrow == 0 && r < N_NODES) {
                a_s[r * 8 + hA] = sA;
                a_d[r * 8 + hA] = dA;
                a_s[r * 8 + hB] = sB;
                a_d[r * 8 + hB] = dB;
            }
        }
    }
}

// ---------------- GEMM2: h2b[MP][64] = out1b[MP][512] @ w2t[64][512]^T -----
#define LDP 72

__global__ __launch_bounds__(256) void gemm2_mfma(
        const ushort_t* __restrict__ A, const ushort_t* __restrict__ Bt,
        ushort_t* __restrict__ C) {
    __shared__ ushort_t As[128 * LDP];
    __shared__ ushort_t Bs[64 * LDP];
    int tid = threadIdx.x;
    int lane = tid & 63, wid = tid >> 6;
    int wrow = wid >> 1, wcol = wid & 1;
    int brow = blockIdx.x;

    f32x4 acc[4][2];
    const f32x4 zero = {0.f, 0.f, 0.f, 0.f};
    #pragma unroll
    for (int mi = 0; mi < 4; ++mi) { acc[mi][0] = zero; acc[mi][1] = zero; }

    int lrow = lane & 15, lkb = lane >> 4;

    for (int k0 = 0; k0 < 512; k0 += 64) {
        #pragma unroll
        for (int it = 0; it < 4; ++it) {
            int slot = tid + it * 256;
            int row = slot >> 3, seg = slot & 7;
            *(int4*)(As + row * LDP + seg * 8) =
                *(const int4*)(A + ((long)(brow * 128 + row)) * 512 + k0 + seg * 8);
        }
        #pragma unroll
        for (int it = 0; it < 2; ++it) {
            int slot = tid + it * 256;
            int row = slot >> 3, seg = slot & 7;
            *(int4*)(Bs + row * LDP + seg * 8) =
                *(const int4*)(Bt + (long)row * 512 + k0 + seg * 8);
        }
        __syncthreads();
        #pragma unroll
        for (int ks = 0; ks < 2; ++ks) {
            bf16x8 af[4], bfr[2];
            #pragma unroll
            for (int mi = 0; mi < 4; ++mi)
                af[mi] = *(const bf16x8*)(As + (wrow * 64 + mi * 16 + lrow) * LDP +
                                          ks * 32 + lkb * 8);
            #pragma unroll
            for (int ni = 0; ni < 2; ++ni)
                bfr[ni] = *(const bf16x8*)(Bs + (wcol * 32 + ni * 16 + lrow) * LDP +
                                           ks * 32 + lkb * 8);
            #pragma unroll
            for (int mi = 0; mi < 4; ++mi)
                #pragma unroll
                for (int ni = 0; ni < 2; ++ni)
                    acc[mi][ni] = __builtin_amdgcn_mfma_f32_16x16x32_bf16(
                        af[mi], bfr[ni], acc[mi][ni], 0, 0, 0);
        }
        __syncthreads();
    }

    #pragma unroll
    for (int mi = 0; mi < 4; ++mi)
        #pragma unroll
        for (int reg = 0; reg < 4; ++reg) {
            int r = brow * 128 + wrow * 64 + mi * 16 + lkb * 4 + reg;
            #pragma unroll
            for (int ni = 0; ni < 2; ++ni) {
                int c = wcol * 32 + ni * 16 + lrow;
                C[(long)r * 64 + c] = f32_to_bf16(acc[mi][ni][reg]);
            }
        }
}

// ---------------- GEMM3: out[N][500] = out2b[MP][64] @ wlt[512][64]^T + bl --
__global__ __launch_bounds__(256) void gemm3_mfma(
        const ushort_t* __restrict__ A, const ushort_t* __restrict__ Bt,
        const float* __restrict__ bias, float* __restrict__ C) {
    __shared__ ushort_t As[128 * LDP];
    __shared__ ushort_t Bs[128 * LDP];
    int tid = threadIdx.x;
    int lane = tid & 63, wid = tid >> 6;
    int wrow = wid >> 1, wcol = wid & 1;
    int brow = blockIdx.y, bcol = blockIdx.x;

    f32x4 acc[4][4];
    const f32x4 zero = {0.f, 0.f, 0.f, 0.f};
    #pragma unroll
    for (int mi = 0; mi < 4; ++mi)
        #pragma unroll
        for (int ni = 0; ni < 4; ++ni) acc[mi][ni] = zero;

    int lrow = lane & 15, lkb = lane >> 4;

    #pragma unroll
    for (int it = 0; it < 4; ++it) {
        int slot = tid + it * 256;
        int row = slot >> 3, seg = slot & 7;
        *(int4*)(As + row * LDP + seg * 8) =
            *(const int4*)(A + ((long)(brow * 128 + row)) * 64 + seg * 8);
        *(int4*)(Bs + row * LDP + seg * 8) =
            *(const int4*)(Bt + ((long)(bcol * 128 + row)) * 64 + seg * 8);
    }
    __syncthreads();
    #pragma unroll
    for (int ks = 0; ks < 2; ++ks) {
        bf16x8 af[4], bfr[4];
        #pragma unroll
        for (int mi = 0; mi < 4; ++mi)
            af[mi] = *(const bf16x8*)(As + (wrow * 64 + mi * 16 + lrow) * LDP +
                                      ks * 32 + lkb * 8);
        #pragma unroll
        for (int ni = 0; ni < 4; ++ni)
            bfr[ni] = *(const bf16x8*)(Bs + (wcol * 64 + ni * 16 + lrow) * LDP +
                                       ks * 32 + lkb * 8);
        #pragma unroll
        for (int mi = 0; mi < 4; ++mi)
            #pragma unroll
            for (int ni = 0; ni < 4; ++ni)
                acc[mi][ni] = __builtin_amdgcn_mfma_f32_16x16x32_bf16(
                    af[mi], bfr[ni], acc[mi][ni], 0, 0, 0);
    }

    #pragma unroll
    for (int mi = 0; mi < 4; ++mi)
        #pragma unroll
        for (int reg = 0; reg < 4; ++reg) {
            int r = brow * 128 + wrow * 64 + mi * 16 + lkb * 4 + reg;
            if (r >= N_NODES) continue;
            #pragma unroll
            for (int ni = 0; ni < 4; ++ni) {
                int c = bcol * 128 + wcol * 64 + ni * 16 + lrow;
                if (c < F_IN) C[(long)r * F_IN + c] = acc[mi][ni][reg] + bias[c];
            }
        }
}

// ---------------- attention dots L2 (H=1): wave per node ----------------
__global__ void attn_dots1(const ushort_t* __restrict__ hb, const float* __restrict__ att_s,
                           const float* __restrict__ att_d, float* __restrict__ a_s,
                           float* __restrict__ a_d) {
    long wid = (blockIdx.x * (long)blockDim.x + threadIdx.x) >> 6;
    int lane = threadIdx.x & 63;
    if (wid >= N_NODES) return;
    int n = (int)wid;
    float f = __uint_as_float(((unsigned)hb[(long)n * 64 + lane]) << 16);
    float s = f * att_s[lane], d = f * att_d[lane];
    #pragma unroll
    for (int m = 32; m >= 1; m >>= 1) { s += __shfl_xor(s, m); d += __shfl_xor(d, m); }
    if (lane == 0) { a_s[n] = s; a_d[n] = d; }
}

// ---------------- csr_agg8: wave per dst, 8 heads, softmax-lite gather ------
__global__ void csr_agg8(const int* __restrict__ srcs, const int* __restrict__ off,
                         const float* __restrict__ a_s, const float* __restrict__ a_d,
                         const ushort_t* __restrict__ hb, const float* __restrict__ bias,
                         ushort_t* __restrict__ outb) {
    __shared__ float alds[4 * 64 * 9];       // per-wave [64 edges][9]
    long wid = (blockIdx.x * (long)blockDim.x + threadIdx.x) >> 6;
    int lane = threadIdx.x & 63;
    if (wid >= N_NODES) return;
    int dst = (int)wid;
    float* aw = alds + (threadIdx.x >> 6) * (64 * 9);
    int b = off[dst], e2 = off[dst + 1];
    int deg = e2 - b;
    int myh = lane >> 3;

    float ad[8];
    {
        const float* adp = a_d + (long)dst * 8;
        #pragma unroll
        for (int hh = 0; hh < 8; ++hh) ad[hh] = adp[hh];
    }

    float acc8[8];
    #pragma unroll
    for (int q = 0; q < 8; ++q) acc8[q] = 0.f;

    if (deg <= 64) {
        // ---- one-pass fast path, shared max across heads (exact: per-head
        // constant cancels in softmax; scores are O(1) so no underflow) ----
        bool act = lane < deg;
        int src = act ? srcs[b + lane] : 0;
        const float* asp = a_s + (long)src * 8;
        float x[8];
        #pragma unroll
        for (int hh = 0; hh < 8; ++hh) {
            float v = act ? (asp[hh] + ad[hh]) : -1e30f;
            x[hh] = v > 0.f ? v : NEG_SLOPE * v;
        }
        float xmax = x[0];
        #pragma unroll
        for (int hh = 1; hh < 8; ++hh) xmax = fmaxf(xmax, x[hh]);
        #pragma unroll
        for (int d2 = 32; d2 >= 1; d2 >>= 1) xmax = fmaxf(xmax, __shfl_xor(xmax, d2));
        #pragma unroll
        for (int hh = 0; hh < 8; ++hh) {
            float ce = act ? __expf(x[hh] - xmax) : 0.f;
            float ss = ce;
            #pragma unroll
            for (int d2 = 32; d2 >= 1; d2 >>= 1) ss += __shfl_xor(ss, d2);
            aw[lane * 9 + hh] = ce * (1.f / (ss + 1e-16f));
        }
        asm volatile("s_waitcnt lgkmcnt(0)" ::: "memory");
        int j = 0;
        for (; j + 4 <= deg; j += 4) {
            int s0 = __shfl(src, j),     s1 = __shfl(src, j + 1);
            int s2 = __shfl(src, j + 2), s3 = __shfl(src, j + 3);
            float a0 = aw[(j) * 9 + myh],     a1 = aw[(j + 1) * 9 + myh];
            float a2 = aw[(j + 2) * 9 + myh], a3 = aw[(j + 3) * 9 + myh];
            int4 h0 = *(const int4*)(hb + (long)s0 * 512 + lane * 8);
            int4 h1 = *(const int4*)(hb + (long)s1 * 512 + lane * 8);
            int4 h2 = *(const int4*)(hb + (long)s2 * 512 + lane * 8);
            int4 h3 = *(const int4*)(hb + (long)s3 * 512 + lane * 8);
            #pragma unroll
            for (int q = 0; q < 4; ++q) {
                unsigned u0 = ((const unsigned*)&h0)[q];
                unsigned u1 = ((const unsigned*)&h1)[q];
                unsigned u2 = ((const unsigned*)&h2)[q];
                unsigned u3 = ((const unsigned*)&h3)[q];
                acc8[2 * q]     += a0 * bf16_lo(u0) + a1 * bf16_lo(u1) +
                                   a2 * bf16_lo(u2) + a3 * bf16_lo(u3);
                acc8[2 * q + 1] += a0 * bf16_hi(u0) + a1 * bf16_hi(u1) +
                                   a2 * bf16_hi(u2) + a3 * bf16_hi(u3);
            }
        }
        for (; j < deg; ++j) {
            int sj = __shfl(src, j);
            float aj = aw[j * 9 + myh];
            int4 hv = *(const int4*)(hb + (long)sj * 512 + lane * 8);
            #pragma unroll
            for (int q = 0; q < 4; ++q) {
                unsigned u = ((const unsigned*)&hv)[q];
                acc8[2 * q]     += aj * bf16_lo(u);
                acc8[2 * q + 1] += aj * bf16_hi(u);
            }
        }
    } else {
        // ---- general chunked two-pass path (per-head online softmax) ----
        float m[8], ssum[8];
        #pragma unroll
        for (int hh = 0; hh < 8; ++hh) { m[hh] = -1e30f; ssum[hh] = 0.f; }

        for (int c = b; c < e2; c += 64) {
            int i = c + lane;
            bool act = i < e2;
            int src = act ? srcs[i] : 0;
            float x[8];
            {
                const float* asp = a_s + (long)src * 8;
                #pragma unroll
                for (int hh = 0; hh < 8; ++hh) {
                    float v = act ? (asp[hh] + ad[hh]) : -1e30f;
                    x[hh] = v > 0.f ? v : NEG_SLOPE * v;
                }
            }
            #pragma unroll
            for (int hh = 0; hh < 8; ++hh) {
                float cm = x[hh];
                #pragma unroll
                for (int d2 = 32; d2 >= 1; d2 >>= 1) cm = fmaxf(cm, __shfl_xor(cm, d2));
                float nm = fmaxf(m[hh], cm);
                float ce = act ? __expf(x[hh] - nm) : 0.f;
                #pragma unroll
                for (int d2 = 32; d2 >= 1; d2 >>= 1) ce += __shfl_xor(ce, d2);
                ssum[hh] = ssum[hh] * __expf(m[hh] - nm) + ce;
                m[hh] = nm;
            }
        }
        float inv[8];
        #pragma unroll
        for (int hh = 0; hh < 8; ++hh) inv[hh] = 1.f / (ssum[hh] + 1e-16f);

        for (int c = b; c < e2; c += 64) {
            int i = c + lane;
            bool act = i < e2;
            int src = act ? srcs[i] : 0;
            {
                const float* asp = a_s + (long)src * 8;
                #pragma unroll
                for (int hh = 0; hh < 8; ++hh) {
                    float v = act ? (asp[hh] + ad[hh]) : -1e30f;
                    v = v > 0.f ? v : NEG_SLOPE * v;
                    aw[lane * 9 + hh] = act ? __expf(v - m[hh]) * inv[hh] : 0.f;
                }
            }
            asm volatile("s_waitcnt lgkmcnt(0)" ::: "memory");
            int cnt = min(64, e2 - c);
            for (int j = 0; j < cnt; ++j) {
                int sj = __shfl(src, j);
                float aj = aw[j * 9 + myh];
                int4 hv = *(const int4*)(hb + (long)sj * 512 + lane * 8);
                #pragma unroll
                for (int q = 0; q < 4; ++q) {
                    unsigned u = ((const unsigned*)&hv)[q];
                    acc8[2 * q]     += aj * bf16_lo(u);
                    acc8[2 * q + 1] += aj * bf16_hi(u);
                }
            }
            asm volatile("s_waitcnt lgkmcnt(0)" ::: "memory");
        }
    }

    const float* bp = bias + lane * 8;
    int4 st;
    #pragma unroll
    for (int q = 0; q < 8; ++q) {
        float v = acc8[q] + bp[q];
        v = v > 0.f ? v : (__expf(v) - 1.f);
        ((ushort_t*)&st)[q] = f32_to_bf16(v);
    }
    *(int4*)(outb + (long)dst * 512 + lane * 8) = st;
}

// ---------------- csr_agg1: wave per dst, H=1, x4-unrolled gather -----------
__global__ void csr_agg1(const int* __restrict__ srcs, const int* __restrict__ off,
                         const float* __restrict__ a_s, const float* __restrict__ a_d,
                         const ushort_t* __restrict__ hb, const float* __restrict__ bias,
                         ushort_t* __restrict__ outb) {
    long wid = (blockIdx.x * (long)blockDim.x + threadIdx.x) >> 6;
    int lane = threadIdx.x & 63;
    if (wid >= N_NODES) return;
    int dst = (int)wid;
    int b = off[dst], e2 = off[dst + 1];
    int deg = e2 - b;
    float ad = a_d[dst];
    float acc = 0.f;

    if (deg <= 64) {
        bool act = lane < deg;
        int src = act ? srcs[b + lane] : 0;
        float v = act ? (a_s[src] + ad) : -1e30f;
        float xx = v > 0.f ? v : NEG_SLOPE * v;
        float cm = xx;
        #pragma unroll
        for (int d2 = 32; d2 >= 1; d2 >>= 1) cm = fmaxf(cm, __shfl_xor(cm, d2));
        float alpha = act ? __expf(xx - cm) : 0.f;
        float ss = alpha;
        #pragma unroll
        for (int d2 = 32; d2 >= 1; d2 >>= 1) ss += __shfl_xor(ss, d2);
        alpha *= 1.f / (ss + 1e-16f);

        int j = 0;
        for (; j + 4 <= deg; j += 4) {
            int s0 = __shfl(src, j),     s1 = __shfl(src, j + 1);
            int s2 = __shfl(src, j + 2), s3 = __shfl(src, j + 3);
            float a0 = __shfl(alpha, j),     a1 = __shfl(alpha, j + 1);
            float a2 = __shfl(alpha, j + 2), a3 = __shfl(alpha, j + 3);
            float f0 = __uint_as_float(((unsigned)hb[(long)s0 * 64 + lane]) << 16);
            float f1 = __uint_as_float(((unsigned)hb[(long)s1 * 64 + lane]) << 16);
            float f2 = __uint_as_float(((unsigned)hb[(long)s2 * 64 + lane]) << 16);
            float f3 = __uint_as_float(((unsigned)hb[(long)s3 * 64 + lane]) << 16);
            acc += a0 * f0 + a1 * f1 + a2 * f2 + a3 * f3;
        }
        for (; j < deg; ++j) {
            int sj = __shfl(src, j);
            float aj = __shfl(alpha, j);
            acc += aj * __uint_as_float(((unsigned)hb[(long)sj * 64 + lane]) << 16);
        }
    } else {
        float m = -1e30f, ssum = 0.f;
        for (int c = b; c < e2; c += 64) {
            int i = c + lane;
            bool act = i < e2;
            int src = act ? srcs[i] : 0;
            float v = act ? (a_s[src] + ad) : -1e30f;
            float xx = v > 0.f ? v : NEG_SLOPE * v;
            float cm = xx;
            #pragma unroll
            for (int d2 = 32; d2 >= 1; d2 >>= 1) cm = fmaxf(cm, __shfl_xor(cm, d2));
            float nm = fmaxf(m, cm);
            float ce = act ? __expf(xx - nm) : 0.f;
            #pragma unroll
            for (int d2 = 32; d2 >= 1; d2 >>= 1) ce += __shfl_xor(ce, d2);
            ssum = ssum * __expf(m - nm) + ce;
            m = nm;
        }
        float inv = 1.f / (ssum + 1e-16f);
        for (int c = b; c < e2; c += 64) {
            int i = c + lane;
            bool act = i < e2;
            int src = act ? srcs[i] : 0;
            float alpha = 0.f;
            if (act) {
                float v = a_s[src] + ad;
                v = v > 0.f ? v : NEG_SLOPE * v;
                alpha = __expf(v - m) * inv;
            }
            int cnt = min(64, e2 - c);
            for (int j = 0; j < cnt; ++j) {
                int sj = __shfl(src, j);
                float aj = __shfl(alpha, j);
                acc += aj * __uint_as_float(((unsigned)hb[(long)sj * 64 + lane]) << 16);
            }
        }
    }
    float v = acc + bias[lane];
    v = v > 0.f ? v : (__expf(v) - 1.f);
    outb[(long)dst * 64 + lane] = f32_to_bf16(v);
}

// ---------------------------------------------------------------------------
extern "C" void kernel_launch(void* const* d_in, const int* in_sizes, int n_in,
                              void* d_out, int out_size, void* d_ws, size_t ws_size,
                              hipStream_t stream) {
    const float* x        = (const float*)d_in[0];
    const int*   ei       = (const int*)d_in[1];
    const float* W1       = (const float*)d_in[2];
    const float* att_src1 = (const float*)d_in[3];
    const float* att_dst1 = (const float*)d_in[4];
    const float* b1       = (const float*)d_in[5];
    const float* W2       = (const float*)d_in[6];
    const float* att_src2 = (const float*)d_in[7];
    const float* att_dst2 = (const float*)d_in[8];
    const float* b2       = (const float*)d_in[9];
    const float* Wl       = (const float*)d_in[10];
    const float* bl       = (const float*)d_in[11];
    float* out = (float*)d_out;

    // workspace layout
    char* p = (char*)d_ws;
    ushort_t* h1b   = (ushort_t*)p; p += (long)MP * 512 * 2;
    ushort_t* out1b = (ushort_t*)p; p += (long)MP * 512 * 2;
    ushort_t* h2b   = (ushort_t*)p; p += (long)MP * 64 * 2;
    ushort_t* out2b = (ushort_t*)p; p += (long)MP * 64 * 2;
    float* as1 = (float*)p; p += (long)N_NODES * 8 * 4;
    float* ad1 = (float*)p; p += (long)N_NODES * 8 * 4;
    ushort_t* w1t = (ushort_t*)p; p += 512 * 512 * 2;
    ushort_t* w2t = (ushort_t*)p; p += 64 * 512 * 2;
    ushort_t* wlt = (ushort_t*)p; p += 512 * 64 * 2;
    int* csr_off = (int*)p; p += (N_NODES + 4) * 4;
    int* csr_cnt = (int*)p; p += N_NODES * 4;
    int* csr_pos = (int*)p; p += N_NODES * 4;
    int* csr_src = (int*)p; p += (long)E_TOT * 4;
    int* scan_p  = (int*)p; p += 256 * 4;

    const int BT = 256;
    dim3 blk(BT);
    const int NB_SCAN = (N_NODES + 255) / 256;   // 196

    // ---------------- CSR build + fills ----------------
    fill_misc<<<256, blk, 0, stream>>>(csr_cnt, (int*)(out1b + (long)N_NODES * 512),
                                       (int*)(out2b + (long)N_NODES * 64));
    count_deg<<<1024, blk, 0, stream>>>(ei, csr_cnt);
    scan_part<<<NB_SCAN, blk, 0, stream>>>(csr_cnt, scan_p, N_NODES);
    scan_top<<<1, blk, 0, stream>>>(scan_p, NB_SCAN);
    scan_final<<<NB_SCAN, blk, 0, stream>>>(csr_cnt, scan_p, csr_off, csr_pos, N_NODES);
    scatter_src<<<1024, blk, 0, stream>>>(ei, csr_pos, csr_src);

    // ---------------- weight conversions ----------------
    cvt_weights<<<640, blk, 0, stream>>>(W1, W2, Wl, w1t, w2t, wlt);

    // ---------------- layer 1: fused GEMM + attn dots ----------------
    gemm1_big<<<2 * (MP / 64), blk, 0, stream>>>(x, w1t, att_src1, att_dst1,
                                                 h1b, as1, ad1);
    csr_agg8<<<(N_NODES * 64 + BT - 1) / BT, blk, 0, stream>>>(
        csr_src, csr_off, as1, ad1, h1b, b1, out1b);

    // ---------------- layer 2 (H=1) ----------------
    gemm2_mfma<<<MP / 128, blk, 0, stream>>>(out1b, w2t, h2b);
    attn_dots1<<<(N_NODES * 64 + BT - 1) / BT, blk, 0, stream>>>(h2b, att_src2, att_dst2,
                                                                 as1, ad1);
    csr_agg1<<<(N_NODES * 64 + BT - 1) / BT, blk, 0, stream>>>(
        csr_src, csr_off, as1, ad1, h2b, b2, out2b);

    // ---------------- final linear ----------------
    {
        dim3 grid(512 / 128, MP / 128);
        gemm3_mfma<<<grid, blk, 0, stream>>>(out2b, wlt, bl, out);
    }
}